// Round 2
// baseline (3448.782 us; speedup 1.0000x reference)
//
#include <hip/hip_runtime.h>
#include <math.h>

#define S_ 4
#define L_ 2048
#define D_ 1024
#define H_ 16
#define DH_ 64
#define TTOT_ 8192
#define WCL_ 384
#define KMAX_ 16
#define MAXCL_ (S_*KMAX_)
#define MAXLEN_ (WCL_+1)   // 385
#define LSCAP_ 4096
#define NELEM_ ((size_t)TTOT_*(size_t)D_)

// ---------------------------------------------------------------------------
// GEMM: C[M,N] = A[M,K] * B[N,K]^T   (both row-major, contraction over 2nd idx)
// 64x64 tile, 256 threads, 4x4 micro-tile, K-chunk 16.
// ---------------------------------------------------------------------------
__global__ __launch_bounds__(256)
void gemm_nt(const float* __restrict__ A, const float* __restrict__ B,
             float* __restrict__ C, int M, int N, int Kd) {
  __shared__ float As[16][68];
  __shared__ float Bs[16][68];
  const int tx = threadIdx.x & 15, ty = threadIdx.x >> 4;
  const int m0 = blockIdx.x * 64, n0 = blockIdx.y * 64;
  const int lr = threadIdx.x >> 2, lc = threadIdx.x & 3;
  float acc[4][4] = {};
  for (int k0 = 0; k0 < Kd; k0 += 16) {
    __syncthreads();
    float4 a4 = *(const float4*)(A + (size_t)(m0 + lr) * Kd + k0 + lc * 4);
    float4 b4 = *(const float4*)(B + (size_t)(n0 + lr) * Kd + k0 + lc * 4);
    As[lc*4+0][lr] = a4.x; As[lc*4+1][lr] = a4.y; As[lc*4+2][lr] = a4.z; As[lc*4+3][lr] = a4.w;
    Bs[lc*4+0][lr] = b4.x; Bs[lc*4+1][lr] = b4.y; Bs[lc*4+2][lr] = b4.z; Bs[lc*4+3][lr] = b4.w;
    __syncthreads();
#pragma unroll
    for (int kk = 0; kk < 16; kk++) {
      float4 av = *(const float4*)&As[kk][ty * 4];
      float4 bv = *(const float4*)&Bs[kk][tx * 4];
      float aa[4] = {av.x, av.y, av.z, av.w};
      float bb[4] = {bv.x, bv.y, bv.z, bv.w};
#pragma unroll
      for (int i = 0; i < 4; i++)
#pragma unroll
        for (int j = 0; j < 4; j++) acc[i][j] += aa[i] * bb[j];
    }
  }
#pragma unroll
  for (int i = 0; i < 4; i++)
#pragma unroll
    for (int j = 0; j < 4; j++)
      C[(size_t)(m0 + ty * 4 + i) * N + (n0 + tx * 4 + j)] = acc[i][j];
}

// ---------------------------------------------------------------------------
// Routing features: r = 0.5*(l2n(mean_h qh) + l2n(mean_h kh)), one wave/token.
// ---------------------------------------------------------------------------
__global__ __launch_bounds__(256)
void feats_kernel(const float* __restrict__ Q, const float* __restrict__ K,
                  float* __restrict__ FE) {
  int t = blockIdx.x * 4 + (threadIdx.x >> 6);
  int lane = threadIdx.x & 63;
  if (t >= TTOT_) return;
  float qm = 0.f, km = 0.f;
#pragma unroll
  for (int h = 0; h < H_; h++) {
    qm += Q[(size_t)t * D_ + h * DH_ + lane];
    km += K[(size_t)t * D_ + h * DH_ + lane];
  }
  qm *= (1.0f / 16.0f);
  km *= (1.0f / 16.0f);
  float q2 = qm * qm, k2 = km * km;
#pragma unroll
  for (int m = 1; m < 64; m <<= 1) {
    q2 += __shfl_xor(q2, m, 64);
    k2 += __shfl_xor(k2, m, 64);
  }
  float r = 0.5f * (qm / (sqrtf(q2) + 1e-6f) + km / (sqrtf(k2) + 1e-6f));
  FE[(size_t)t * DH_ + lane] = r;
}

// ---------------------------------------------------------------------------
// Routing: 1 block per sequence, replicates _route_np exactly.
// ---------------------------------------------------------------------------
__device__ __forceinline__ float dot64(const float* __restrict__ f,
                                       const float* __restrict__ c) {
  float s = 0.f;
#pragma unroll
  for (int c4 = 0; c4 < 16; c4++) {
    float4 fv = *(const float4*)(f + c4 * 4);
    float4 cv = *(const float4*)(c + c4 * 4);
    s += fv.x * cv.x; s += fv.y * cv.y; s += fv.z * cv.z; s += fv.w * cv.w;
  }
  return s;
}

__global__ __launch_bounds__(1024)
void routing_kernel(const float* __restrict__ FE, const int* __restrict__ seqlens,
                    const int* __restrict__ gidx, int* __restrict__ cT,
                    int* __restrict__ cL, int* __restrict__ tC) {
  __shared__ float cent[KMAX_][64];
  __shared__ float csum[KMAX_][64];
  __shared__ int cnt1[KMAX_];
  __shared__ int cnt2[KMAX_];
  __shared__ int starts[KMAX_ + 1];
  __shared__ unsigned char assign[LSCAP_];
  __shared__ unsigned long long keys[LSCAP_];

  const int s = blockIdx.x, tid = threadIdx.x;
  int a = 0;
  for (int t = 0; t < s; t++) a += seqlens[t];
  int Ls = seqlens[s];
  if (Ls > LSCAP_) Ls = LSCAP_;
  for (int cs = tid; cs < KMAX_; cs += 1024) cL[s * KMAX_ + cs] = 0;
  if (Ls <= 0) return;

  int wloc = Ls < WCL_ ? Ls : WCL_;
  if (wloc < 1) wloc = 1;
  int k = (Ls + wloc - 1) / wloc;
  if (k < 1) k = 1;
  if (k > KMAX_) k = KMAX_;

  // centroid init: feats at round(linspace(0, Ls-1, k))  (double, half-even)
  if (tid < k * 64) {
    int j = tid >> 6, d = tid & 63;
    double step = (k > 1) ? (double)(Ls - 1) / (double)(k - 1) : 0.0;
    long ii = (long)rint(step * (double)j);
    if (ii < 0) ii = 0;
    if (ii > Ls - 1) ii = Ls - 1;
    cent[j][d] = FE[(size_t)(a + ii) * DH_ + d];
  }
  if (tid < KMAX_) cnt1[tid] = 0;
  __syncthreads();

  // ---- one k-means iteration (ROUTING_ITERS = 1) ----
  for (int i = tid; i < Ls; i += 1024) {
    const float* f = FE + (size_t)(a + i) * DH_;
    float best = -1e30f; int bj = 0;
    for (int j = 0; j < k; j++) {
      float sd = dot64(f, &cent[j][0]);
      if (sd > best) { best = sd; bj = j; }      // first-max tie-break
    }
    assign[i] = (unsigned char)bj;
  }
  __syncthreads();
  for (int i = tid; i < Ls; i += 1024) atomicAdd(&cnt1[assign[i]], 1);
  __syncthreads();
  // deterministic per-dim sequential scatter-sum (matches np.add.at order)
  if (tid < 64) {
    int d = tid;
    for (int j = 0; j < k; j++) csum[j][d] = 0.f;
    for (int i = 0; i < Ls; i++)
      csum[assign[i]][d] += FE[(size_t)(a + i) * DH_ + d];
  }
  __syncthreads();
  if (tid < k * 64) {
    int j = tid >> 6, d = tid & 63;
    float v = csum[j][d] / fmaxf((float)cnt1[j], 1.0f);
    float sq = v * v;
#pragma unroll
    for (int m = 1; m < 64; m <<= 1) sq += __shfl_xor(sq, m, 64);
    cent[j][d] = v / (sqrtf(sq) + 1e-6f);
  }
  __syncthreads();

  // ---- final assign + own + composite sort keys ----
  int NP2 = 1;
  while (NP2 < Ls) NP2 <<= 1;
  for (int i = tid; i < NP2; i += 1024) {
    unsigned long long key;
    if (i < Ls) {
      const float* f = FE + (size_t)(a + i) * DH_;
      float best = -1e30f; int bj = 0;
      for (int j = 0; j < k; j++) {
        float sd = dot64(f, &cent[j][0]);
        if (sd > best) { best = sd; bj = j; }
      }
      assign[i] = (unsigned char)bj;
      unsigned int u = __float_as_uint(best);
      unsigned int ord = (u & 0x80000000u) ? ~u : (u | 0x80000000u); // asc map
      unsigned int dsc = ~ord;                                      // descending own
      key = ((unsigned long long)bj << 45) |
            ((unsigned long long)dsc << 13) | (unsigned long long)i;
    } else {
      key = ~0ull;
    }
    keys[i] = key;
  }
  if (tid < KMAX_) cnt2[tid] = 0;
  __syncthreads();
  for (int i = tid; i < Ls; i += 1024) atomicAdd(&cnt2[assign[i]], 1);
  __syncthreads();

  // ---- bitonic sort ascending: (cid asc, own desc, idx asc) ----
  for (int len2 = 2; len2 <= NP2; len2 <<= 1) {
    for (int st = len2 >> 1; st > 0; st >>= 1) {
      for (int i = tid; i < NP2; i += 1024) {
        int j = i ^ st;
        if (j > i) {
          unsigned long long x = keys[i], y = keys[j];
          bool asc = ((i & len2) == 0);
          if ((x > y) == asc) { keys[i] = y; keys[j] = x; }
        }
      }
      __syncthreads();
    }
  }
  if (tid == 0) {
    starts[0] = 0;
    for (int j = 0; j < k; j++) starts[j + 1] = starts[j] + cnt2[j];
  }
  __syncthreads();

  // ---- emit clusters: top-min(count,wloc) per cluster + global token ----
  const int g = gidx[s];
  int cOut = 0;
  for (int j = 0; j < k; j++) {
    int cj = cnt2[j];
    if (cj <= 0) continue;
    int keep = cj < wloc ? cj : wloc;
    int slot = s * KMAX_ + cOut;
    for (int p = tid; p < keep; p += 1024) {
      int token = a + (int)(keys[starts[j] + p] & 0x1FFFull);
      cT[slot * MAXLEN_ + p] = token;
      atomicAdd(&tC[token], 1);
    }
    if (tid == 0) {
      cT[slot * MAXLEN_ + keep] = g;
      atomicAdd(&tC[g], 1);
      cL[slot] = keep + 1;
    }
    cOut++;
  }
}

// ---------------------------------------------------------------------------
// Per-(cluster, head, q-chunk) flash attention. 512 thr = 8 waves, each wave
// owns 8 q-rows of a 64-row chunk; K/V staged in 64-key swizzled LDS tiles.
// ---------------------------------------------------------------------------
__global__ __launch_bounds__(512)
void attn_kernel(const float* __restrict__ Q, const float* __restrict__ K,
                 const float* __restrict__ V, const int* __restrict__ cT,
                 const int* __restrict__ cL, float* __restrict__ OH) {
  const int c = blockIdx.x, h = blockIdx.y;
  const int len = cL[c];
  const int q0 = blockIdx.z * 64;
  if (len <= 0 || q0 >= len) return;

  __shared__ int toks[MAXLEN_];
  __shared__ float qs[64][64];       // q chunk, linear (reads are broadcasts)
  __shared__ float Ks[64][64];       // swizzled
  __shared__ float Vs[64][64];       // swizzled
  __shared__ float ps[8][4][64];     // per-wave p staging (half-row batches)

  const int tid = threadIdx.x, wave = tid >> 6, lane = tid & 63;
  for (int i = tid; i < len; i += 512) toks[i] = cT[c * MAXLEN_ + i];
  __syncthreads();

  // stage q chunk: 64 rows x 16 float4
  for (int e = tid; e < 1024; e += 512) {
    int rr = e >> 4, c4 = e & 15;
    int row = q0 + rr;
    float4 v4 = make_float4(0.f, 0.f, 0.f, 0.f);
    if (row < len) v4 = *(const float4*)(Q + (size_t)toks[row] * D_ + h * DH_ + c4 * 4);
    *(float4*)&qs[rr][c4 * 4] = v4;
  }

  const int r0 = wave * 8;
  float acc[8] = {0.f,0.f,0.f,0.f,0.f,0.f,0.f,0.f};
  float mm[8], ll[8];
#pragma unroll
  for (int r = 0; r < 8; r++) { mm[r] = -INFINITY; ll[r] = 0.f; }

  const int ntile = (len + 63) >> 6;
  for (int mt = 0; mt < ntile; mt++) {
    __syncthreads();  // qs/Ks/Vs producers <-> consumers
    for (int e = tid; e < 2048; e += 512) {
      int mat = e >> 10;
      int idx = e & 1023;
      int rr = idx >> 4, c4 = idx & 15;
      int mg = mt * 64 + rr;
      float4 v4 = make_float4(0.f, 0.f, 0.f, 0.f);
      if (mg < len) {
        const float* src = (mat ? V : K) + (size_t)toks[mg] * D_ + h * DH_ + c4 * 4;
        v4 = *(const float4*)src;
      }
      int sc = (c4 ^ (rr & 15)) * 4;
      float* dst = mat ? &Vs[rr][sc] : &Ks[rr][sc];
      *(float4*)dst = v4;
    }
    __syncthreads();

    // ---- QK^T: lane <-> key, 8 rows per wave ----
    const int key = mt * 64 + lane;
    const bool kvalid = key < len;
    float d[8] = {0.f,0.f,0.f,0.f,0.f,0.f,0.f,0.f};
#pragma unroll
    for (int c4 = 0; c4 < 16; c4++) {
      float4 kv = *(const float4*)&Ks[lane][((c4 ^ (lane & 15)) << 2)];
#pragma unroll
      for (int r = 0; r < 8; r++) {
        float4 q4 = *(const float4*)&qs[r0 + r][c4 * 4];
        d[r] += q4.x * kv.x + q4.y * kv.y + q4.z * kv.z + q4.w * kv.w;
      }
    }

    // ---- online softmax + PV in two half-row batches of 4 ----
#pragma unroll
    for (int half = 0; half < 2; half++) {
#pragma unroll
      for (int rr = 0; rr < 4; rr++) {
        int r = half * 4 + rr;
        float s = kvalid ? d[r] * 0.125f : -INFINITY;
        float t = s;
#pragma unroll
        for (int m = 1; m < 64; m <<= 1) t = fmaxf(t, __shfl_xor(t, m, 64));
        float n = fmaxf(mm[r], t);
        float cor = expf(mm[r] - n);
        float p = expf(s - n);
        float sum = p;
#pragma unroll
        for (int m = 1; m < 64; m <<= 1) sum += __shfl_xor(sum, m, 64);
        ll[r] = ll[r] * cor + sum;
        acc[r] *= cor;
        mm[r] = n;
        ps[wave][rr][lane] = p;
      }
      __asm__ volatile("" ::: "memory");  // keep ps writes before reads
#pragma unroll
      for (int mq = 0; mq < 16; mq++) {
        float vv[4];
#pragma unroll
        for (int u = 0; u < 4; u++) {
          int ml = mq * 4 + u;
          vv[u] = Vs[ml][(((lane >> 2) ^ (ml & 15)) << 2) + (lane & 3)];
        }
#pragma unroll
        for (int rr = 0; rr < 4; rr++) {
          float4 pv = *(const float4*)&ps[wave][rr][mq * 4];
          acc[half * 4 + rr] += pv.x * vv[0] + pv.y * vv[1] + pv.z * vv[2] + pv.w * vv[3];
        }
      }
    }
  }

#pragma unroll
  for (int r = 0; r < 8; r++) {
    int row = q0 + r0 + r;
    if (row < len)
      atomicAdd(&OH[(size_t)toks[row] * D_ + h * DH_ + lane], acc[r] / ll[r]);
  }
}

// ---------------------------------------------------------------------------
// out_h /= clip(cnt, 1)
// ---------------------------------------------------------------------------
__global__ __launch_bounds__(256)
void norm_oh(float* __restrict__ OH, const int* __restrict__ cnt) {
  size_t i = (size_t)blockIdx.x * 256 + threadIdx.x;  // float4 index
  size_t n4 = NELEM_ / 4;
  if (i >= n4) return;
  int row = (int)((i * 4) >> 10);
  int cc = cnt[row];
  float s = 1.0f / (float)(cc > 1 ? cc : 1);
  float4* p = (float4*)OH + i;
  float4 v = *p;
  v.x *= s; v.y *= s; v.z *= s; v.w *= s;
  *p = v;
}

// ---------------------------------------------------------------------------
extern "C" void kernel_launch(void* const* d_in, const int* in_sizes, int n_in,
                              void* d_out, int out_size, void* d_ws, size_t ws_size,
                              hipStream_t stream) {
  (void)in_sizes; (void)n_in; (void)out_size; (void)ws_size;
  const float* q_in = (const float*)d_in[0];
  const float* k_in = (const float*)d_in[1];
  const float* v_in = (const float*)d_in[2];
  const int* seqlens = (const int*)d_in[3];
  const int* gidx    = (const int*)d_in[4];
  const float* Wq = (const float*)d_in[5];
  const float* Wk = (const float*)d_in[6];
  const float* Wv = (const float*)d_in[7];
  const float* Wo = (const float*)d_in[8];
  float* out = (float*)d_out;

  float* Q  = (float*)d_ws;
  float* K  = Q + NELEM_;
  float* V  = K + NELEM_;
  float* OH = V + NELEM_;
  float* FE = OH + NELEM_;
  int* cT = (int*)(FE + (size_t)TTOT_ * DH_);
  int* cL = cT + MAXCL_ * MAXLEN_;
  int* tC = cL + MAXCL_;

  hipMemsetAsync(OH, 0, NELEM_ * sizeof(float), stream);
  hipMemsetAsync(tC, 0, TTOT_ * sizeof(int), stream);

  dim3 gg(TTOT_ / 64, D_ / 64);
  gemm_nt<<<gg, 256, 0, stream>>>(q_in, Wq, Q, TTOT_, D_, D_);
  gemm_nt<<<gg, 256, 0, stream>>>(k_in, Wk, K, TTOT_, D_, D_);
  gemm_nt<<<gg, 256, 0, stream>>>(v_in, Wv, V, TTOT_, D_, D_);
  feats_kernel<<<TTOT_ / 4, 256, 0, stream>>>(Q, K, FE);
  routing_kernel<<<S_, 1024, 0, stream>>>(FE, seqlens, gidx, cT, cL, tC);
  attn_kernel<<<dim3(MAXCL_, H_, (MAXLEN_ + 63) / 64), 512, 0, stream>>>(Q, K, V, cT, cL, OH);
  norm_oh<<<(unsigned)((NELEM_ / 4 + 255) / 256), 256, 0, stream>>>(OH, tC);
  gemm_nt<<<gg, 256, 0, stream>>>(OH, Wo, out, TTOT_, D_, D_);
}

// Round 3
// 1716.554 us; speedup vs baseline: 2.0091x; 2.0091x over previous
//
#include <hip/hip_runtime.h>
#include <math.h>

#define S_ 4
#define L_ 2048
#define D_ 1024
#define H_ 16
#define DH_ 64
#define TTOT_ 8192
#define WCL_ 384
#define KMAX_ 16
#define MAXCL_ (S_*KMAX_)
#define MAXLEN_ (WCL_+1)   // 385
#define LSCAP_ 4096
#define NELEM_ ((size_t)TTOT_*(size_t)D_)

typedef __attribute__((ext_vector_type(8))) short bf16x8;
typedef __attribute__((ext_vector_type(4))) float f32x4;

// bf16 split helpers (RNE)
__device__ __forceinline__ unsigned short bfh(float x) {
  unsigned u = __float_as_uint(x);
  return (unsigned short)((u + 0x7FFFu + ((u >> 16) & 1u)) >> 16);
}
__device__ __forceinline__ float bff(unsigned short h) {
  return __uint_as_float(((unsigned)h) << 16);
}
__device__ __forceinline__ unsigned pk2(unsigned short a, unsigned short b) {
  return (unsigned)a | ((unsigned)b << 16);
}
// XOR swizzle on ushort index within [row][64] tiles (16B-chunk granularity)
#define SWZ(r, c) (((r) << 6) + ((c) ^ (((r) & 7) << 3)))

// ---------------------------------------------------------------------------
// GEMM: C[M,N] = A[M,K] * B[N,K]^T  (f32 vector, unchanged this round)
// ---------------------------------------------------------------------------
__global__ __launch_bounds__(256)
void gemm_nt(const float* __restrict__ A, const float* __restrict__ B,
             float* __restrict__ C, int M, int N, int Kd) {
  __shared__ float As[16][68];
  __shared__ float Bs[16][68];
  const int tx = threadIdx.x & 15, ty = threadIdx.x >> 4;
  const int m0 = blockIdx.x * 64, n0 = blockIdx.y * 64;
  const int lr = threadIdx.x >> 2, lc = threadIdx.x & 3;
  float acc[4][4] = {};
  for (int k0 = 0; k0 < Kd; k0 += 16) {
    __syncthreads();
    float4 a4 = *(const float4*)(A + (size_t)(m0 + lr) * Kd + k0 + lc * 4);
    float4 b4 = *(const float4*)(B + (size_t)(n0 + lr) * Kd + k0 + lc * 4);
    As[lc*4+0][lr] = a4.x; As[lc*4+1][lr] = a4.y; As[lc*4+2][lr] = a4.z; As[lc*4+3][lr] = a4.w;
    Bs[lc*4+0][lr] = b4.x; Bs[lc*4+1][lr] = b4.y; Bs[lc*4+2][lr] = b4.z; Bs[lc*4+3][lr] = b4.w;
    __syncthreads();
#pragma unroll
    for (int kk = 0; kk < 16; kk++) {
      float4 av = *(const float4*)&As[kk][ty * 4];
      float4 bv = *(const float4*)&Bs[kk][tx * 4];
      float aa[4] = {av.x, av.y, av.z, av.w};
      float bb[4] = {bv.x, bv.y, bv.z, bv.w};
#pragma unroll
      for (int i = 0; i < 4; i++)
#pragma unroll
        for (int j = 0; j < 4; j++) acc[i][j] += aa[i] * bb[j];
    }
  }
#pragma unroll
  for (int i = 0; i < 4; i++)
#pragma unroll
    for (int j = 0; j < 4; j++)
      C[(size_t)(m0 + ty * 4 + i) * N + (n0 + tx * 4 + j)] = acc[i][j];
}

// ---------------------------------------------------------------------------
// Routing features
// ---------------------------------------------------------------------------
__global__ __launch_bounds__(256)
void feats_kernel(const float* __restrict__ Q, const float* __restrict__ K,
                  float* __restrict__ FE) {
  int t = blockIdx.x * 4 + (threadIdx.x >> 6);
  int lane = threadIdx.x & 63;
  if (t >= TTOT_) return;
  float qm = 0.f, km = 0.f;
#pragma unroll
  for (int h = 0; h < H_; h++) {
    qm += Q[(size_t)t * D_ + h * DH_ + lane];
    km += K[(size_t)t * D_ + h * DH_ + lane];
  }
  qm *= (1.0f / 16.0f);
  km *= (1.0f / 16.0f);
  float q2 = qm * qm, k2 = km * km;
#pragma unroll
  for (int m = 1; m < 64; m <<= 1) {
    q2 += __shfl_xor(q2, m, 64);
    k2 += __shfl_xor(k2, m, 64);
  }
  float r = 0.5f * (qm / (sqrtf(q2) + 1e-6f) + km / (sqrtf(k2) + 1e-6f));
  FE[(size_t)t * DH_ + lane] = r;
}

// ---------------------------------------------------------------------------
// Routing (exact replica of _route_np) — unchanged
// ---------------------------------------------------------------------------
__device__ __forceinline__ float dot64(const float* __restrict__ f,
                                       const float* __restrict__ c) {
  float s = 0.f;
#pragma unroll
  for (int c4 = 0; c4 < 16; c4++) {
    float4 fv = *(const float4*)(f + c4 * 4);
    float4 cv = *(const float4*)(c + c4 * 4);
    s += fv.x * cv.x; s += fv.y * cv.y; s += fv.z * cv.z; s += fv.w * cv.w;
  }
  return s;
}

__global__ __launch_bounds__(1024)
void routing_kernel(const float* __restrict__ FE, const int* __restrict__ seqlens,
                    const int* __restrict__ gidx, int* __restrict__ cT,
                    int* __restrict__ cL, int* __restrict__ tC) {
  __shared__ float cent[KMAX_][64];
  __shared__ float csum[KMAX_][64];
  __shared__ int cnt1[KMAX_];
  __shared__ int cnt2[KMAX_];
  __shared__ int starts[KMAX_ + 1];
  __shared__ unsigned char assign[LSCAP_];
  __shared__ unsigned long long keys[LSCAP_];

  const int s = blockIdx.x, tid = threadIdx.x;
  int a = 0;
  for (int t = 0; t < s; t++) a += seqlens[t];
  int Ls = seqlens[s];
  if (Ls > LSCAP_) Ls = LSCAP_;
  for (int cs = tid; cs < KMAX_; cs += 1024) cL[s * KMAX_ + cs] = 0;
  if (Ls <= 0) return;

  int wloc = Ls < WCL_ ? Ls : WCL_;
  if (wloc < 1) wloc = 1;
  int k = (Ls + wloc - 1) / wloc;
  if (k < 1) k = 1;
  if (k > KMAX_) k = KMAX_;

  if (tid < k * 64) {
    int j = tid >> 6, d = tid & 63;
    double step = (k > 1) ? (double)(Ls - 1) / (double)(k - 1) : 0.0;
    long ii = (long)rint(step * (double)j);
    if (ii < 0) ii = 0;
    if (ii > Ls - 1) ii = Ls - 1;
    cent[j][d] = FE[(size_t)(a + ii) * DH_ + d];
  }
  if (tid < KMAX_) cnt1[tid] = 0;
  __syncthreads();

  for (int i = tid; i < Ls; i += 1024) {
    const float* f = FE + (size_t)(a + i) * DH_;
    float best = -1e30f; int bj = 0;
    for (int j = 0; j < k; j++) {
      float sd = dot64(f, &cent[j][0]);
      if (sd > best) { best = sd; bj = j; }
    }
    assign[i] = (unsigned char)bj;
  }
  __syncthreads();
  for (int i = tid; i < Ls; i += 1024) atomicAdd(&cnt1[assign[i]], 1);
  __syncthreads();
  if (tid < 64) {
    int d = tid;
    for (int j = 0; j < k; j++) csum[j][d] = 0.f;
    for (int i = 0; i < Ls; i++)
      csum[assign[i]][d] += FE[(size_t)(a + i) * DH_ + d];
  }
  __syncthreads();
  if (tid < k * 64) {
    int j = tid >> 6, d = tid & 63;
    float v = csum[j][d] / fmaxf((float)cnt1[j], 1.0f);
    float sq = v * v;
#pragma unroll
    for (int m = 1; m < 64; m <<= 1) sq += __shfl_xor(sq, m, 64);
    cent[j][d] = v / (sqrtf(sq) + 1e-6f);
  }
  __syncthreads();

  int NP2 = 1;
  while (NP2 < Ls) NP2 <<= 1;
  for (int i = tid; i < NP2; i += 1024) {
    unsigned long long key;
    if (i < Ls) {
      const float* f = FE + (size_t)(a + i) * DH_;
      float best = -1e30f; int bj = 0;
      for (int j = 0; j < k; j++) {
        float sd = dot64(f, &cent[j][0]);
        if (sd > best) { best = sd; bj = j; }
      }
      assign[i] = (unsigned char)bj;
      unsigned int u = __float_as_uint(best);
      unsigned int ord = (u & 0x80000000u) ? ~u : (u | 0x80000000u);
      unsigned int dsc = ~ord;
      key = ((unsigned long long)bj << 45) |
            ((unsigned long long)dsc << 13) | (unsigned long long)i;
    } else {
      key = ~0ull;
    }
    keys[i] = key;
  }
  if (tid < KMAX_) cnt2[tid] = 0;
  __syncthreads();
  for (int i = tid; i < Ls; i += 1024) atomicAdd(&cnt2[assign[i]], 1);
  __syncthreads();

  for (int len2 = 2; len2 <= NP2; len2 <<= 1) {
    for (int st = len2 >> 1; st > 0; st >>= 1) {
      for (int i = tid; i < NP2; i += 1024) {
        int j = i ^ st;
        if (j > i) {
          unsigned long long x = keys[i], y = keys[j];
          bool asc = ((i & len2) == 0);
          if ((x > y) == asc) { keys[i] = y; keys[j] = x; }
        }
      }
      __syncthreads();
    }
  }
  if (tid == 0) {
    starts[0] = 0;
    for (int j = 0; j < k; j++) starts[j + 1] = starts[j] + cnt2[j];
  }
  __syncthreads();

  const int g = gidx[s];
  int cOut = 0;
  for (int j = 0; j < k; j++) {
    int cj = cnt2[j];
    if (cj <= 0) continue;
    int keep = cj < wloc ? cj : wloc;
    int slot = s * KMAX_ + cOut;
    for (int p = tid; p < keep; p += 1024) {
      int token = a + (int)(keys[starts[j] + p] & 0x1FFFull);
      cT[slot * MAXLEN_ + p] = token;
      atomicAdd(&tC[token], 1);
    }
    if (tid == 0) {
      cT[slot * MAXLEN_ + keep] = g;
      atomicAdd(&tC[g], 1);
      cL[slot] = keep + 1;
    }
    cOut++;
  }
}

// ---------------------------------------------------------------------------
// MFMA flash attention. Block = (cluster, head, 64-row q-chunk), 256 thr =
// 4 waves, each wave owns 16 q-rows. Split-bf16 (hi+lo) MFMA for QK^T and PV.
// LDS: Q[64][64] + K[64][64] (natural) + V^T[64][64] + per-wave P[16][64],
// all bf16 hi/lo, XOR-swizzled. mfma_f32_16x16x32_bf16 throughout.
// ---------------------------------------------------------------------------
__global__ __launch_bounds__(256)
void attn_kernel(const float* __restrict__ Q, const float* __restrict__ K,
                 const float* __restrict__ V, const int* __restrict__ cT,
                 const int* __restrict__ cL, float* __restrict__ OH) {
  const int c = blockIdx.x, h = blockIdx.y;
  const int len = cL[c];
  const int q0 = blockIdx.z * 64;
  if (len <= 0 || q0 >= len) return;

  __shared__ int toks[MAXLEN_];
  __shared__ __align__(16) unsigned short Qh[4096], Ql[4096];   // [qrow][dim]
  __shared__ __align__(16) unsigned short Kh[4096], Kl[4096];   // [key][dim]
  __shared__ __align__(16) unsigned short Vh[4096], Vl[4096];   // [dim][key] (transposed)
  __shared__ __align__(16) unsigned short Ph[4][1024], Pl[4][1024]; // per-wave [qrow16][key64]

  const int tid = threadIdx.x, wave = tid >> 6, lane = tid & 63;
  const int lm = lane & 15, lg = lane >> 4;

  for (int i = tid; i < len; i += 256) toks[i] = cT[c * MAXLEN_ + i];
  __syncthreads();

  // ---- stage Q chunk (once): rows q0..q0+63, bf16 hi/lo, swizzled ----
  for (int e = tid; e < 1024; e += 256) {
    int rr = e >> 4, c4 = e & 15;
    int row = q0 + rr;
    float4 v4 = make_float4(0.f, 0.f, 0.f, 0.f);
    if (row < len)
      v4 = *(const float4*)(Q + (size_t)toks[row] * D_ + h * DH_ + c4 * 4);
    unsigned short h0 = bfh(v4.x), h1 = bfh(v4.y), h2 = bfh(v4.z), h3 = bfh(v4.w);
    *(uint2*)&Qh[SWZ(rr, c4 * 4)] = make_uint2(pk2(h0, h1), pk2(h2, h3));
    *(uint2*)&Ql[SWZ(rr, c4 * 4)] =
        make_uint2(pk2(bfh(v4.x - bff(h0)), bfh(v4.y - bff(h1))),
                   pk2(bfh(v4.z - bff(h2)), bfh(v4.w - bff(h3))));
  }
  __syncthreads();

  // ---- per-wave Q fragments (invariant over K-tiles): A[m=lm][k blocked] ----
  bf16x8 qAh[2], qAl[2];
#pragma unroll
  for (int s = 0; s < 2; s++) {
    qAh[s] = *(const bf16x8*)&Qh[SWZ(wave * 16 + lm, s * 32 + lg * 8)];
    qAl[s] = *(const bf16x8*)&Ql[SWZ(wave * 16 + lm, s * 32 + lg * 8)];
  }

  f32x4 accO[4];
#pragma unroll
  for (int t = 0; t < 4; t++) accO[t] = (f32x4){0.f, 0.f, 0.f, 0.f};
  float mm[4] = {-INFINITY, -INFINITY, -INFINITY, -INFINITY};
  float ll[4] = {0.f, 0.f, 0.f, 0.f};

  const int ntile = (len + 63) >> 6;
  for (int mt = 0; mt < ntile; mt++) {
    __syncthreads();  // protect K/V LDS reuse
    // ---- stage K tile (natural [key][dim]) ----
    for (int e = tid; e < 1024; e += 256) {
      int rr = e >> 4, c4 = e & 15;
      int mg = mt * 64 + rr;
      float4 v4 = make_float4(0.f, 0.f, 0.f, 0.f);
      if (mg < len)
        v4 = *(const float4*)(K + (size_t)toks[mg] * D_ + h * DH_ + c4 * 4);
      unsigned short h0 = bfh(v4.x), h1 = bfh(v4.y), h2 = bfh(v4.z), h3 = bfh(v4.w);
      *(uint2*)&Kh[SWZ(rr, c4 * 4)] = make_uint2(pk2(h0, h1), pk2(h2, h3));
      *(uint2*)&Kl[SWZ(rr, c4 * 4)] =
          make_uint2(pk2(bfh(v4.x - bff(h0)), bfh(v4.y - bff(h1))),
                     pk2(bfh(v4.z - bff(h2)), bfh(v4.w - bff(h3))));
    }
    // ---- stage V tile transposed ([dim][key]) ----
    {
      int dg = tid & 15, kg = tid >> 4;
      int d0 = dg * 4;
      float4 a0 = make_float4(0,0,0,0), a1 = a0, a2 = a0, a3 = a0;
      int m0k = mt * 64 + kg * 4;
      if (m0k + 0 < len) a0 = *(const float4*)(V + (size_t)toks[m0k + 0] * D_ + h * DH_ + d0);
      if (m0k + 1 < len) a1 = *(const float4*)(V + (size_t)toks[m0k + 1] * D_ + h * DH_ + d0);
      if (m0k + 2 < len) a2 = *(const float4*)(V + (size_t)toks[m0k + 2] * D_ + h * DH_ + d0);
      if (m0k + 3 < len) a3 = *(const float4*)(V + (size_t)toks[m0k + 3] * D_ + h * DH_ + d0);
#define VROW(dd, e0, e1, e2, e3)                                               \
      {                                                                        \
        unsigned short h0 = bfh(e0), h1 = bfh(e1), h2 = bfh(e2), h3 = bfh(e3); \
        *(uint2*)&Vh[SWZ(d0 + dd, kg * 4)] = make_uint2(pk2(h0, h1), pk2(h2, h3)); \
        *(uint2*)&Vl[SWZ(d0 + dd, kg * 4)] =                                   \
            make_uint2(pk2(bfh(e0 - bff(h0)), bfh(e1 - bff(h1))),              \
                       pk2(bfh(e2 - bff(h2)), bfh(e3 - bff(h3))));             \
      }
      VROW(0, a0.x, a1.x, a2.x, a3.x)
      VROW(1, a0.y, a1.y, a2.y, a3.y)
      VROW(2, a0.z, a1.z, a2.z, a3.z)
      VROW(3, a0.w, a1.w, a2.w, a3.w)
#undef VROW
    }
    __syncthreads();

    // ---- QK^T: 4 key-tiles x 2 k-slabs x 3 split terms ----
    f32x4 sA[4];
#pragma unroll
    for (int t = 0; t < 4; t++) sA[t] = (f32x4){0.f, 0.f, 0.f, 0.f};
#pragma unroll
    for (int t = 0; t < 4; t++) {
#pragma unroll
      for (int s = 0; s < 2; s++) {
        bf16x8 kb = *(const bf16x8*)&Kh[SWZ(t * 16 + lm, s * 32 + lg * 8)];
        bf16x8 kl = *(const bf16x8*)&Kl[SWZ(t * 16 + lm, s * 32 + lg * 8)];
        sA[t] = __builtin_amdgcn_mfma_f32_16x16x32_bf16(qAh[s], kb, sA[t], 0, 0, 0);
        sA[t] = __builtin_amdgcn_mfma_f32_16x16x32_bf16(qAl[s], kb, sA[t], 0, 0, 0);
        sA[t] = __builtin_amdgcn_mfma_f32_16x16x32_bf16(qAh[s], kl, sA[t], 0, 0, 0);
      }
    }

    // ---- mask + online softmax (rows live in (lg, reg)) ----
    float sc[4][4];
#pragma unroll
    for (int t = 0; t < 4; t++) {
      bool kvalid = (mt * 64 + t * 16 + lm) < len;
#pragma unroll
      for (int r = 0; r < 4; r++)
        sc[t][r] = kvalid ? sA[t][r] * 0.125f : -1e9f;
    }
    float mx[4], nn[4], cor[4], sum[4];
#pragma unroll
    for (int r = 0; r < 4; r++) {
      mx[r] = fmaxf(fmaxf(sc[0][r], sc[1][r]), fmaxf(sc[2][r], sc[3][r]));
      mx[r] = fmaxf(mx[r], __shfl_xor(mx[r], 1, 64));
      mx[r] = fmaxf(mx[r], __shfl_xor(mx[r], 2, 64));
      mx[r] = fmaxf(mx[r], __shfl_xor(mx[r], 4, 64));
      mx[r] = fmaxf(mx[r], __shfl_xor(mx[r], 8, 64));
      nn[r] = fmaxf(mm[r], mx[r]);
      cor[r] = expf(mm[r] - nn[r]);
      mm[r] = nn[r];
    }
    float pp[4][4];
#pragma unroll
    for (int t = 0; t < 4; t++)
#pragma unroll
      for (int r = 0; r < 4; r++) pp[t][r] = expf(sc[t][r] - nn[r]);
#pragma unroll
    for (int r = 0; r < 4; r++) {
      sum[r] = (pp[0][r] + pp[1][r]) + (pp[2][r] + pp[3][r]);
      sum[r] += __shfl_xor(sum[r], 1, 64);
      sum[r] += __shfl_xor(sum[r], 2, 64);
      sum[r] += __shfl_xor(sum[r], 4, 64);
      sum[r] += __shfl_xor(sum[r], 8, 64);
      ll[r] = ll[r] * cor[r] + sum[r];
    }
#pragma unroll
    for (int t = 0; t < 4; t++) {
#pragma unroll
      for (int r = 0; r < 4; r++) {
        accO[t][r] *= cor[r];
        int row = lg * 4 + r, col = t * 16 + lm;
        unsigned short hp = bfh(pp[t][r]);
        Ph[wave][SWZ(row, col)] = hp;
        Pl[wave][SWZ(row, col)] = bfh(pp[t][r] - bff(hp));
      }
    }

    // ---- PV: A = P[qrow][key], B = V^T[dim][key] reads, 3 split terms ----
    bf16x8 pAh[2], pAl[2];
#pragma unroll
    for (int s = 0; s < 2; s++) {
      pAh[s] = *(const bf16x8*)&Ph[wave][SWZ(lm, s * 32 + lg * 8)];
      pAl[s] = *(const bf16x8*)&Pl[wave][SWZ(lm, s * 32 + lg * 8)];
    }
#pragma unroll
    for (int t = 0; t < 4; t++) {
#pragma unroll
      for (int s = 0; s < 2; s++) {
        bf16x8 vb = *(const bf16x8*)&Vh[SWZ(t * 16 + lm, s * 32 + lg * 8)];
        bf16x8 vl = *(const bf16x8*)&Vl[SWZ(t * 16 + lm, s * 32 + lg * 8)];
        accO[t] = __builtin_amdgcn_mfma_f32_16x16x32_bf16(pAh[s], vb, accO[t], 0, 0, 0);
        accO[t] = __builtin_amdgcn_mfma_f32_16x16x32_bf16(pAl[s], vb, accO[t], 0, 0, 0);
        accO[t] = __builtin_amdgcn_mfma_f32_16x16x32_bf16(pAh[s], vl, accO[t], 0, 0, 0);
      }
    }
  }

  // ---- epilogue: normalize, scatter-add ----
#pragma unroll
  for (int t = 0; t < 4; t++) {
#pragma unroll
    for (int r = 0; r < 4; r++) {
      int row = q0 + wave * 16 + lg * 4 + r;
      if (row < len)
        atomicAdd(&OH[(size_t)toks[row] * D_ + h * DH_ + t * 16 + lm],
                  accO[t][r] / ll[r]);
    }
  }
}

// ---------------------------------------------------------------------------
// out_h /= clip(cnt, 1)
// ---------------------------------------------------------------------------
__global__ __launch_bounds__(256)
void norm_oh(float* __restrict__ OH, const int* __restrict__ cnt) {
  size_t i = (size_t)blockIdx.x * 256 + threadIdx.x;
  size_t n4 = NELEM_ / 4;
  if (i >= n4) return;
  int row = (int)((i * 4) >> 10);
  int cc = cnt[row];
  float s = 1.0f / (float)(cc > 1 ? cc : 1);
  float4* p = (float4*)OH + i;
  float4 v = *p;
  v.x *= s; v.y *= s; v.z *= s; v.w *= s;
  *p = v;
}

// ---------------------------------------------------------------------------
extern "C" void kernel_launch(void* const* d_in, const int* in_sizes, int n_in,
                              void* d_out, int out_size, void* d_ws, size_t ws_size,
                              hipStream_t stream) {
  (void)in_sizes; (void)n_in; (void)out_size; (void)ws_size;
  const float* q_in = (const float*)d_in[0];
  const float* k_in = (const float*)d_in[1];
  const float* v_in = (const float*)d_in[2];
  const int* seqlens = (const int*)d_in[3];
  const int* gidx    = (const int*)d_in[4];
  const float* Wq = (const float*)d_in[5];
  const float* Wk = (const float*)d_in[6];
  const float* Wv = (const float*)d_in[7];
  const float* Wo = (const float*)d_in[8];
  float* out = (float*)d_out;

  float* Q  = (float*)d_ws;
  float* K  = Q + NELEM_;
  float* V  = K + NELEM_;
  float* OH = V + NELEM_;
  float* FE = OH + NELEM_;
  int* cT = (int*)(FE + (size_t)TTOT_ * DH_);
  int* cL = cT + MAXCL_ * MAXLEN_;
  int* tC = cL + MAXCL_;

  hipMemsetAsync(OH, 0, NELEM_ * sizeof(float), stream);
  hipMemsetAsync(tC, 0, TTOT_ * sizeof(int), stream);

  dim3 gg(TTOT_ / 64, D_ / 64);
  gemm_nt<<<gg, 256, 0, stream>>>(q_in, Wq, Q, TTOT_, D_, D_);
  gemm_nt<<<gg, 256, 0, stream>>>(k_in, Wk, K, TTOT_, D_, D_);
  gemm_nt<<<gg, 256, 0, stream>>>(v_in, Wv, V, TTOT_, D_, D_);
  feats_kernel<<<TTOT_ / 4, 256, 0, stream>>>(Q, K, FE);
  routing_kernel<<<S_, 1024, 0, stream>>>(FE, seqlens, gidx, cT, cL, tC);
  attn_kernel<<<dim3(MAXCL_, H_, (MAXLEN_ + 63) / 64), 256, 0, stream>>>(Q, K, V, cT, cL, OH);
  norm_oh<<<(unsigned)((NELEM_ / 4 + 255) / 256), 256, 0, stream>>>(OH, tC);
  gemm_nt<<<gg, 256, 0, stream>>>(OH, Wo, out, TTOT_, D_, D_);
}

// Round 4
// 1109.535 us; speedup vs baseline: 3.1083x; 1.5471x over previous
//
#include <hip/hip_runtime.h>
#include <math.h>

#define S_ 4
#define L_ 2048
#define D_ 1024
#define H_ 16
#define DH_ 64
#define TTOT_ 8192
#define WCL_ 384
#define KMAX_ 16
#define MAXCL_ (S_*KMAX_)
#define MAXLEN_ (WCL_+1)   // 385
#define LSCAP_ 4096
#define NELEM_ ((size_t)TTOT_*(size_t)D_)

typedef __attribute__((ext_vector_type(8))) short bf16x8;
typedef __attribute__((ext_vector_type(4))) float f32x4;

// bf16 split helpers (RNE)
__device__ __forceinline__ unsigned short bfh(float x) {
  unsigned u = __float_as_uint(x);
  return (unsigned short)((u + 0x7FFFu + ((u >> 16) & 1u)) >> 16);
}
__device__ __forceinline__ float bff(unsigned short h) {
  return __uint_as_float(((unsigned)h) << 16);
}
__device__ __forceinline__ unsigned pk2(unsigned short a, unsigned short b) {
  return (unsigned)a | ((unsigned)b << 16);
}
// XOR swizzle on ushort index within [row][64] tiles (16B-chunk granularity)
#define SWZ(r, c) (((r) << 6) + ((c) ^ (((r) & 7) << 3)))

__device__ __forceinline__ void glds16(const void* g, void* l) {
  __builtin_amdgcn_global_load_lds(
      (const __attribute__((address_space(1))) unsigned int*)g,
      (__attribute__((address_space(3))) unsigned int*)l, 16, 0, 0);
}

// ---------------------------------------------------------------------------
// f32 GEMM (kept for the small, routing-exact feats GEMMs): C=A[M,K]*B[N,K]^T
// ---------------------------------------------------------------------------
__global__ __launch_bounds__(256)
void gemm_nt(const float* __restrict__ A, const float* __restrict__ B,
             float* __restrict__ C, int M, int N, int Kd) {
  __shared__ float As[16][68];
  __shared__ float Bs[16][68];
  const int tx = threadIdx.x & 15, ty = threadIdx.x >> 4;
  const int m0 = blockIdx.x * 64, n0 = blockIdx.y * 64;
  const int lr = threadIdx.x >> 2, lc = threadIdx.x & 3;
  float acc[4][4] = {};
  for (int k0 = 0; k0 < Kd; k0 += 16) {
    __syncthreads();
    float4 a4 = *(const float4*)(A + (size_t)(m0 + lr) * Kd + k0 + lc * 4);
    float4 b4 = *(const float4*)(B + (size_t)(n0 + lr) * Kd + k0 + lc * 4);
    As[lc*4+0][lr] = a4.x; As[lc*4+1][lr] = a4.y; As[lc*4+2][lr] = a4.z; As[lc*4+3][lr] = a4.w;
    Bs[lc*4+0][lr] = b4.x; Bs[lc*4+1][lr] = b4.y; Bs[lc*4+2][lr] = b4.z; Bs[lc*4+3][lr] = b4.w;
    __syncthreads();
#pragma unroll
    for (int kk = 0; kk < 16; kk++) {
      float4 av = *(const float4*)&As[kk][ty * 4];
      float4 bv = *(const float4*)&Bs[kk][tx * 4];
      float aa[4] = {av.x, av.y, av.z, av.w};
      float bb[4] = {bv.x, bv.y, bv.z, bv.w};
#pragma unroll
      for (int i = 0; i < 4; i++)
#pragma unroll
        for (int j = 0; j < 4; j++) acc[i][j] += aa[i] * bb[j];
    }
  }
#pragma unroll
  for (int i = 0; i < 4; i++)
#pragma unroll
    for (int j = 0; j < 4; j++)
      C[(size_t)(m0 + ty * 4 + i) * N + (n0 + tx * 4 + j)] = acc[i][j];
}

// ---------------------------------------------------------------------------
// Split-bf16 MFMA GEMM: C[M,N] = A[M,K]*B[N,K]^T, A/B pre-split into hi/lo
// bf16 arrays. 128x128 tile, BK=64, 256 thr (4 waves), global_load_lds
// staging with pre-swizzled source, swizzled ds_read_b128, 3-term split.
// ---------------------------------------------------------------------------
__global__ __launch_bounds__(256)
void gemm_bf16s(const unsigned short* __restrict__ Ah, const unsigned short* __restrict__ Al,
                const unsigned short* __restrict__ Bh, const unsigned short* __restrict__ Bl,
                float* __restrict__ C, int M, int N, int Kd) {
  __shared__ __align__(16) unsigned short LA[2][128 * 64];
  __shared__ __align__(16) unsigned short LB[2][128 * 64];

  const int tid = threadIdx.x, wave = tid >> 6, lane = tid & 63;
  const int lm = lane & 15, lg = lane >> 4;
  const int m0 = blockIdx.x * 128, n0 = blockIdx.y * 128;
  const int wr = wave >> 1, wc = wave & 1;
  const int lrow = lane >> 3;              // 0..7 (row within 8-row slab)
  const int lchk = (lane & 7) ^ lrow;      // pre-swizzled source chunk

  f32x4 acc[4][4];
#pragma unroll
  for (int i = 0; i < 4; i++)
#pragma unroll
    for (int j = 0; j < 4; j++) acc[i][j] = (f32x4){0.f, 0.f, 0.f, 0.f};

  for (int k0 = 0; k0 < Kd; k0 += 64) {
    __syncthreads();
#pragma unroll
    for (int i = 0; i < 4; i++) {
      const int r = wave * 32 + i * 8;
      const size_t ga = (size_t)(m0 + r + lrow) * Kd + k0 + lchk * 8;
      const size_t gb = (size_t)(n0 + r + lrow) * Kd + k0 + lchk * 8;
      glds16(&Ah[ga], &LA[0][r * 64]);
      glds16(&Al[ga], &LA[1][r * 64]);
      glds16(&Bh[gb], &LB[0][r * 64]);
      glds16(&Bl[gb], &LB[1][r * 64]);
    }
    __syncthreads();
#pragma unroll
    for (int s = 0; s < 2; s++) {
      bf16x8 ah[4], al[4], bh[4], bl[4];
#pragma unroll
      for (int i = 0; i < 4; i++) {
        const int ra = wr * 64 + i * 16 + lm;
        const int ca = ((s * 4 + lg) ^ (ra & 7)) * 8;
        ah[i] = *(const bf16x8*)&LA[0][ra * 64 + ca];
        al[i] = *(const bf16x8*)&LA[1][ra * 64 + ca];
        const int rb = wc * 64 + i * 16 + lm;
        const int cb = ((s * 4 + lg) ^ (rb & 7)) * 8;
        bh[i] = *(const bf16x8*)&LB[0][rb * 64 + cb];
        bl[i] = *(const bf16x8*)&LB[1][rb * 64 + cb];
      }
#pragma unroll
      for (int i = 0; i < 4; i++)
#pragma unroll
        for (int j = 0; j < 4; j++) {
          acc[i][j] = __builtin_amdgcn_mfma_f32_16x16x32_bf16(ah[i], bh[j], acc[i][j], 0, 0, 0);
          acc[i][j] = __builtin_amdgcn_mfma_f32_16x16x32_bf16(al[i], bh[j], acc[i][j], 0, 0, 0);
          acc[i][j] = __builtin_amdgcn_mfma_f32_16x16x32_bf16(ah[i], bl[j], acc[i][j], 0, 0, 0);
        }
    }
  }
#pragma unroll
  for (int i = 0; i < 4; i++)
#pragma unroll
    for (int j = 0; j < 4; j++) {
      const int rowb = m0 + wr * 64 + i * 16 + lg * 4;
      const int col = n0 + wc * 64 + j * 16 + lm;
#pragma unroll
      for (int r = 0; r < 4; r++)
        C[(size_t)(rowb + r) * N + col] = acc[i][j][r];
    }
}

// ---------------------------------------------------------------------------
// f32 -> (hi,lo) bf16 split, vectorized
// ---------------------------------------------------------------------------
__global__ __launch_bounds__(256)
void conv_split(const float* __restrict__ src, unsigned short* __restrict__ dh,
                unsigned short* __restrict__ dl, int n4) {
  int i = blockIdx.x * 256 + threadIdx.x;
  if (i >= n4) return;
  float4 v = ((const float4*)src)[i];
  unsigned short h0 = bfh(v.x), h1 = bfh(v.y), h2 = bfh(v.z), h3 = bfh(v.w);
  *(uint2*)&dh[(size_t)i * 4] = make_uint2(pk2(h0, h1), pk2(h2, h3));
  *(uint2*)&dl[(size_t)i * 4] =
      make_uint2(pk2(bfh(v.x - bff(h0)), bfh(v.y - bff(h1))),
                 pk2(bfh(v.z - bff(h2)), bfh(v.w - bff(h3))));
}

// ---------------------------------------------------------------------------
// Wm[d][k] = (1/16) sum_h W[h*64+d][k]   (64 x 1024 output)
// ---------------------------------------------------------------------------
__global__ __launch_bounds__(256)
void wmean(const float* __restrict__ W, float* __restrict__ Wm) {
  int i = blockIdx.x * 256 + threadIdx.x;
  if (i >= 64 * 1024) return;
  int d = i >> 10, kk = i & 1023;
  float s = 0.f;
#pragma unroll
  for (int h = 0; h < 16; h++) s += W[(size_t)(h * 64 + d) * 1024 + kk];
  Wm[i] = s * (1.0f / 16.0f);
}

// ---------------------------------------------------------------------------
// FE[t] = 0.5*(l2n(FQ[t]) + l2n(FK[t]))   (one wave per token)
// ---------------------------------------------------------------------------
__global__ __launch_bounds__(256)
void l2comb(const float* __restrict__ FQ, const float* __restrict__ FK,
            float* __restrict__ FE) {
  int t = blockIdx.x * 4 + (threadIdx.x >> 6);
  int lane = threadIdx.x & 63;
  if (t >= TTOT_) return;
  float q = FQ[(size_t)t * 64 + lane], k = FK[(size_t)t * 64 + lane];
  float q2 = q * q, k2 = k * k;
#pragma unroll
  for (int m = 1; m < 64; m <<= 1) {
    q2 += __shfl_xor(q2, m, 64);
    k2 += __shfl_xor(k2, m, 64);
  }
  FE[(size_t)t * 64 + lane] =
      0.5f * (q / (sqrtf(q2) + 1e-6f) + k / (sqrtf(k2) + 1e-6f));
}

// ---------------------------------------------------------------------------
// Routing (exact replica of _route_np) — unchanged
// ---------------------------------------------------------------------------
__device__ __forceinline__ float dot64(const float* __restrict__ f,
                                       const float* __restrict__ c) {
  float s = 0.f;
#pragma unroll
  for (int c4 = 0; c4 < 16; c4++) {
    float4 fv = *(const float4*)(f + c4 * 4);
    float4 cv = *(const float4*)(c + c4 * 4);
    s += fv.x * cv.x; s += fv.y * cv.y; s += fv.z * cv.z; s += fv.w * cv.w;
  }
  return s;
}

__global__ __launch_bounds__(1024)
void routing_kernel(const float* __restrict__ FE, const int* __restrict__ seqlens,
                    const int* __restrict__ gidx, int* __restrict__ cT,
                    int* __restrict__ cL, int* __restrict__ tC) {
  __shared__ float cent[KMAX_][64];
  __shared__ float csum[KMAX_][64];
  __shared__ int cnt1[KMAX_];
  __shared__ int cnt2[KMAX_];
  __shared__ int starts[KMAX_ + 1];
  __shared__ unsigned char assign[LSCAP_];
  __shared__ unsigned long long keys[LSCAP_];

  const int s = blockIdx.x, tid = threadIdx.x;
  int a = 0;
  for (int t = 0; t < s; t++) a += seqlens[t];
  int Ls = seqlens[s];
  if (Ls > LSCAP_) Ls = LSCAP_;
  for (int cs = tid; cs < KMAX_; cs += 1024) cL[s * KMAX_ + cs] = 0;
  if (Ls <= 0) return;

  int wloc = Ls < WCL_ ? Ls : WCL_;
  if (wloc < 1) wloc = 1;
  int k = (Ls + wloc - 1) / wloc;
  if (k < 1) k = 1;
  if (k > KMAX_) k = KMAX_;

  if (tid < k * 64) {
    int j = tid >> 6, d = tid & 63;
    double step = (k > 1) ? (double)(Ls - 1) / (double)(k - 1) : 0.0;
    long ii = (long)rint(step * (double)j);
    if (ii < 0) ii = 0;
    if (ii > Ls - 1) ii = Ls - 1;
    cent[j][d] = FE[(size_t)(a + ii) * DH_ + d];
  }
  if (tid < KMAX_) cnt1[tid] = 0;
  __syncthreads();

  for (int i = tid; i < Ls; i += 1024) {
    const float* f = FE + (size_t)(a + i) * DH_;
    float best = -1e30f; int bj = 0;
    for (int j = 0; j < k; j++) {
      float sd = dot64(f, &cent[j][0]);
      if (sd > best) { best = sd; bj = j; }
    }
    assign[i] = (unsigned char)bj;
  }
  __syncthreads();
  for (int i = tid; i < Ls; i += 1024) atomicAdd(&cnt1[assign[i]], 1);
  __syncthreads();
  if (tid < 64) {
    int d = tid;
    for (int j = 0; j < k; j++) csum[j][d] = 0.f;
    for (int i = 0; i < Ls; i++)
      csum[assign[i]][d] += FE[(size_t)(a + i) * DH_ + d];
  }
  __syncthreads();
  if (tid < k * 64) {
    int j = tid >> 6, d = tid & 63;
    float v = csum[j][d] / fmaxf((float)cnt1[j], 1.0f);
    float sq = v * v;
#pragma unroll
    for (int m = 1; m < 64; m <<= 1) sq += __shfl_xor(sq, m, 64);
    cent[j][d] = v / (sqrtf(sq) + 1e-6f);
  }
  __syncthreads();

  int NP2 = 1;
  while (NP2 < Ls) NP2 <<= 1;
  for (int i = tid; i < NP2; i += 1024) {
    unsigned long long key;
    if (i < Ls) {
      const float* f = FE + (size_t)(a + i) * DH_;
      float best = -1e30f; int bj = 0;
      for (int j = 0; j < k; j++) {
        float sd = dot64(f, &cent[j][0]);
        if (sd > best) { best = sd; bj = j; }
      }
      assign[i] = (unsigned char)bj;
      unsigned int u = __float_as_uint(best);
      unsigned int ord = (u & 0x80000000u) ? ~u : (u | 0x80000000u);
      unsigned int dsc = ~ord;
      key = ((unsigned long long)bj << 45) |
            ((unsigned long long)dsc << 13) | (unsigned long long)i;
    } else {
      key = ~0ull;
    }
    keys[i] = key;
  }
  if (tid < KMAX_) cnt2[tid] = 0;
  __syncthreads();
  for (int i = tid; i < Ls; i += 1024) atomicAdd(&cnt2[assign[i]], 1);
  __syncthreads();

  for (int len2 = 2; len2 <= NP2; len2 <<= 1) {
    for (int st = len2 >> 1; st > 0; st >>= 1) {
      for (int i = tid; i < NP2; i += 1024) {
        int j = i ^ st;
        if (j > i) {
          unsigned long long x = keys[i], y = keys[j];
          bool asc = ((i & len2) == 0);
          if ((x > y) == asc) { keys[i] = y; keys[j] = x; }
        }
      }
      __syncthreads();
    }
  }
  if (tid == 0) {
    starts[0] = 0;
    for (int j = 0; j < k; j++) starts[j + 1] = starts[j] + cnt2[j];
  }
  __syncthreads();

  const int g = gidx[s];
  int cOut = 0;
  for (int j = 0; j < k; j++) {
    int cj = cnt2[j];
    if (cj <= 0) continue;
    int keep = cj < wloc ? cj : wloc;
    int slot = s * KMAX_ + cOut;
    for (int p = tid; p < keep; p += 1024) {
      int token = a + (int)(keys[starts[j] + p] & 0x1FFFull);
      cT[slot * MAXLEN_ + p] = token;
      atomicAdd(&tC[token], 1);
    }
    if (tid == 0) {
      cT[slot * MAXLEN_ + keep] = g;
      atomicAdd(&tC[g], 1);
      cL[slot] = keep + 1;
    }
    cOut++;
  }
}

// ---------------------------------------------------------------------------
// MFMA flash attention (unchanged from R3)
// ---------------------------------------------------------------------------
__global__ __launch_bounds__(256)
void attn_kernel(const float* __restrict__ Q, const float* __restrict__ K,
                 const float* __restrict__ V, const int* __restrict__ cT,
                 const int* __restrict__ cL, float* __restrict__ OH) {
  const int c = blockIdx.x, h = blockIdx.y;
  const int len = cL[c];
  const int q0 = blockIdx.z * 64;
  if (len <= 0 || q0 >= len) return;

  __shared__ int toks[MAXLEN_];
  __shared__ __align__(16) unsigned short Qh[4096], Ql[4096];   // [qrow][dim]
  __shared__ __align__(16) unsigned short Kh[4096], Kl[4096];   // [key][dim]
  __shared__ __align__(16) unsigned short Vh[4096], Vl[4096];   // [dim][key]
  __shared__ __align__(16) unsigned short Ph[4][1024], Pl[4][1024];

  const int tid = threadIdx.x, wave = tid >> 6, lane = tid & 63;
  const int lm = lane & 15, lg = lane >> 4;

  for (int i = tid; i < len; i += 256) toks[i] = cT[c * MAXLEN_ + i];
  __syncthreads();

  for (int e = tid; e < 1024; e += 256) {
    int rr = e >> 4, c4 = e & 15;
    int row = q0 + rr;
    float4 v4 = make_float4(0.f, 0.f, 0.f, 0.f);
    if (row < len)
      v4 = *(const float4*)(Q + (size_t)toks[row] * D_ + h * DH_ + c4 * 4);
    unsigned short h0 = bfh(v4.x), h1 = bfh(v4.y), h2 = bfh(v4.z), h3 = bfh(v4.w);
    *(uint2*)&Qh[SWZ(rr, c4 * 4)] = make_uint2(pk2(h0, h1), pk2(h2, h3));
    *(uint2*)&Ql[SWZ(rr, c4 * 4)] =
        make_uint2(pk2(bfh(v4.x - bff(h0)), bfh(v4.y - bff(h1))),
                   pk2(bfh(v4.z - bff(h2)), bfh(v4.w - bff(h3))));
  }
  __syncthreads();

  bf16x8 qAh[2], qAl[2];
#pragma unroll
  for (int s = 0; s < 2; s++) {
    qAh[s] = *(const bf16x8*)&Qh[SWZ(wave * 16 + lm, s * 32 + lg * 8)];
    qAl[s] = *(const bf16x8*)&Ql[SWZ(wave * 16 + lm, s * 32 + lg * 8)];
  }

  f32x4 accO[4];
#pragma unroll
  for (int t = 0; t < 4; t++) accO[t] = (f32x4){0.f, 0.f, 0.f, 0.f};
  float mm[4] = {-INFINITY, -INFINITY, -INFINITY, -INFINITY};
  float ll[4] = {0.f, 0.f, 0.f, 0.f};

  const int ntile = (len + 63) >> 6;
  for (int mt = 0; mt < ntile; mt++) {
    __syncthreads();
    for (int e = tid; e < 1024; e += 256) {
      int rr = e >> 4, c4 = e & 15;
      int mg = mt * 64 + rr;
      float4 v4 = make_float4(0.f, 0.f, 0.f, 0.f);
      if (mg < len)
        v4 = *(const float4*)(K + (size_t)toks[mg] * D_ + h * DH_ + c4 * 4);
      unsigned short h0 = bfh(v4.x), h1 = bfh(v4.y), h2 = bfh(v4.z), h3 = bfh(v4.w);
      *(uint2*)&Kh[SWZ(rr, c4 * 4)] = make_uint2(pk2(h0, h1), pk2(h2, h3));
      *(uint2*)&Kl[SWZ(rr, c4 * 4)] =
          make_uint2(pk2(bfh(v4.x - bff(h0)), bfh(v4.y - bff(h1))),
                     pk2(bfh(v4.z - bff(h2)), bfh(v4.w - bff(h3))));
    }
    {
      int dg = tid & 15, kg = tid >> 4;
      int d0 = dg * 4;
      float4 a0 = make_float4(0,0,0,0), a1 = a0, a2 = a0, a3 = a0;
      int m0k = mt * 64 + kg * 4;
      if (m0k + 0 < len) a0 = *(const float4*)(V + (size_t)toks[m0k + 0] * D_ + h * DH_ + d0);
      if (m0k + 1 < len) a1 = *(const float4*)(V + (size_t)toks[m0k + 1] * D_ + h * DH_ + d0);
      if (m0k + 2 < len) a2 = *(const float4*)(V + (size_t)toks[m0k + 2] * D_ + h * DH_ + d0);
      if (m0k + 3 < len) a3 = *(const float4*)(V + (size_t)toks[m0k + 3] * D_ + h * DH_ + d0);
#define VROW(dd, e0, e1, e2, e3)                                               \
      {                                                                        \
        unsigned short h0 = bfh(e0), h1 = bfh(e1), h2 = bfh(e2), h3 = bfh(e3); \
        *(uint2*)&Vh[SWZ(d0 + dd, kg * 4)] = make_uint2(pk2(h0, h1), pk2(h2, h3)); \
        *(uint2*)&Vl[SWZ(d0 + dd, kg * 4)] =                                   \
            make_uint2(pk2(bfh(e0 - bff(h0)), bfh(e1 - bff(h1))),              \
                       pk2(bfh(e2 - bff(h2)), bfh(e3 - bff(h3))));             \
      }
      VROW(0, a0.x, a1.x, a2.x, a3.x)
      VROW(1, a0.y, a1.y, a2.y, a3.y)
      VROW(2, a0.z, a1.z, a2.z, a3.z)
      VROW(3, a0.w, a1.w, a2.w, a3.w)
#undef VROW
    }
    __syncthreads();

    f32x4 sA[4];
#pragma unroll
    for (int t = 0; t < 4; t++) sA[t] = (f32x4){0.f, 0.f, 0.f, 0.f};
#pragma unroll
    for (int t = 0; t < 4; t++) {
#pragma unroll
      for (int s = 0; s < 2; s++) {
        bf16x8 kb = *(const bf16x8*)&Kh[SWZ(t * 16 + lm, s * 32 + lg * 8)];
        bf16x8 kl = *(const bf16x8*)&Kl[SWZ(t * 16 + lm, s * 32 + lg * 8)];
        sA[t] = __builtin_amdgcn_mfma_f32_16x16x32_bf16(qAh[s], kb, sA[t], 0, 0, 0);
        sA[t] = __builtin_amdgcn_mfma_f32_16x16x32_bf16(qAl[s], kb, sA[t], 0, 0, 0);
        sA[t] = __builtin_amdgcn_mfma_f32_16x16x32_bf16(qAh[s], kl, sA[t], 0, 0, 0);
      }
    }

    float sc[4][4];
#pragma unroll
    for (int t = 0; t < 4; t++) {
      bool kvalid = (mt * 64 + t * 16 + lm) < len;
#pragma unroll
      for (int r = 0; r < 4; r++)
        sc[t][r] = kvalid ? sA[t][r] * 0.125f : -1e9f;
    }
    float mx[4], nn[4], cor[4], sum[4];
#pragma unroll
    for (int r = 0; r < 4; r++) {
      mx[r] = fmaxf(fmaxf(sc[0][r], sc[1][r]), fmaxf(sc[2][r], sc[3][r]));
      mx[r] = fmaxf(mx[r], __shfl_xor(mx[r], 1, 64));
      mx[r] = fmaxf(mx[r], __shfl_xor(mx[r], 2, 64));
      mx[r] = fmaxf(mx[r], __shfl_xor(mx[r], 4, 64));
      mx[r] = fmaxf(mx[r], __shfl_xor(mx[r], 8, 64));
      nn[r] = fmaxf(mm[r], mx[r]);
      cor[r] = expf(mm[r] - nn[r]);
      mm[r] = nn[r];
    }
    float pp[4][4];
#pragma unroll
    for (int t = 0; t < 4; t++)
#pragma unroll
      for (int r = 0; r < 4; r++) pp[t][r] = expf(sc[t][r] - nn[r]);
#pragma unroll
    for (int r = 0; r < 4; r++) {
      sum[r] = (pp[0][r] + pp[1][r]) + (pp[2][r] + pp[3][r]);
      sum[r] += __shfl_xor(sum[r], 1, 64);
      sum[r] += __shfl_xor(sum[r], 2, 64);
      sum[r] += __shfl_xor(sum[r], 4, 64);
      sum[r] += __shfl_xor(sum[r], 8, 64);
      ll[r] = ll[r] * cor[r] + sum[r];
    }
#pragma unroll
    for (int t = 0; t < 4; t++) {
#pragma unroll
      for (int r = 0; r < 4; r++) {
        accO[t][r] *= cor[r];
        int row = lg * 4 + r, col = t * 16 + lm;
        unsigned short hp = bfh(pp[t][r]);
        Ph[wave][SWZ(row, col)] = hp;
        Pl[wave][SWZ(row, col)] = bfh(pp[t][r] - bff(hp));
      }
    }

    bf16x8 pAh[2], pAl[2];
#pragma unroll
    for (int s = 0; s < 2; s++) {
      pAh[s] = *(const bf16x8*)&Ph[wave][SWZ(lm, s * 32 + lg * 8)];
      pAl[s] = *(const bf16x8*)&Pl[wave][SWZ(lm, s * 32 + lg * 8)];
    }
#pragma unroll
    for (int t = 0; t < 4; t++) {
#pragma unroll
      for (int s = 0; s < 2; s++) {
        bf16x8 vb = *(const bf16x8*)&Vh[SWZ(t * 16 + lm, s * 32 + lg * 8)];
        bf16x8 vl = *(const bf16x8*)&Vl[SWZ(t * 16 + lm, s * 32 + lg * 8)];
        accO[t] = __builtin_amdgcn_mfma_f32_16x16x32_bf16(pAh[s], vb, accO[t], 0, 0, 0);
        accO[t] = __builtin_amdgcn_mfma_f32_16x16x32_bf16(pAl[s], vb, accO[t], 0, 0, 0);
        accO[t] = __builtin_amdgcn_mfma_f32_16x16x32_bf16(pAh[s], vl, accO[t], 0, 0, 0);
      }
    }
  }

#pragma unroll
  for (int t = 0; t < 4; t++) {
#pragma unroll
    for (int r = 0; r < 4; r++) {
      int row = q0 + wave * 16 + lg * 4 + r;
      if (row < len)
        atomicAdd(&OH[(size_t)toks[row] * D_ + h * DH_ + t * 16 + lm],
                  accO[t][r] / ll[r]);
    }
  }
}

// ---------------------------------------------------------------------------
// out_h /= clip(cnt,1), then split to bf16 hi/lo for the output GEMM
// ---------------------------------------------------------------------------
__global__ __launch_bounds__(256)
void norm_split(const float* __restrict__ OH, const int* __restrict__ cnt,
                unsigned short* __restrict__ oh, unsigned short* __restrict__ ol) {
  size_t i = (size_t)blockIdx.x * 256 + threadIdx.x;
  size_t n4 = NELEM_ / 4;
  if (i >= n4) return;
  int row = (int)((i * 4) >> 10);
  int cc = cnt[row];
  float s = 1.0f / (float)(cc > 1 ? cc : 1);
  float4 v = ((const float4*)OH)[i];
  v.x *= s; v.y *= s; v.z *= s; v.w *= s;
  unsigned short h0 = bfh(v.x), h1 = bfh(v.y), h2 = bfh(v.z), h3 = bfh(v.w);
  *(uint2*)&oh[i * 4] = make_uint2(pk2(h0, h1), pk2(h2, h3));
  *(uint2*)&ol[i * 4] =
      make_uint2(pk2(bfh(v.x - bff(h0)), bfh(v.y - bff(h1))),
                 pk2(bfh(v.z - bff(h2)), bfh(v.w - bff(h3))));
}

// ---------------------------------------------------------------------------
extern "C" void kernel_launch(void* const* d_in, const int* in_sizes, int n_in,
                              void* d_out, int out_size, void* d_ws, size_t ws_size,
                              hipStream_t stream) {
  (void)in_sizes; (void)n_in; (void)out_size; (void)ws_size;
  const float* q_in = (const float*)d_in[0];
  const float* k_in = (const float*)d_in[1];
  const float* v_in = (const float*)d_in[2];
  const int* seqlens = (const int*)d_in[3];
  const int* gidx    = (const int*)d_in[4];
  const float* Wq = (const float*)d_in[5];
  const float* Wk = (const float*)d_in[6];
  const float* Wv = (const float*)d_in[7];
  const float* Wo = (const float*)d_in[8];
  float* out = (float*)d_out;

  float* Q  = (float*)d_ws;            // 8.4M f32  (later: OH splits)
  float* K  = Q + NELEM_;
  float* V  = K + NELEM_;
  float* OH = V + NELEM_;              // 8.4M f32  (earlier: input splits)
  float* WS = OH + NELEM_;             // 1M f32 slots = 2x 1M ushorts (W splits)
  float* FE = WS + (1 << 20);
  float* FQ = FE + (size_t)TTOT_ * DH_;
  float* FK = FQ + (size_t)TTOT_ * DH_;
  float* Wqm = FK + (size_t)TTOT_ * DH_;
  float* Wkm = Wqm + 64 * 1024;
  int* cT = (int*)(Wkm + 64 * 1024);
  int* cL = cT + MAXCL_ * MAXLEN_;
  int* tC = cL + MAXCL_;

  unsigned short* SPh = (unsigned short*)OH;        // input hi (aliases OH)
  unsigned short* SPl = SPh + NELEM_;               // input lo
  unsigned short* WSh = (unsigned short*)WS;        // weight hi
  unsigned short* WSl = WSh + (1 << 20);            // weight lo
  unsigned short* OHh = (unsigned short*)Q;         // OH hi (aliases Q)
  unsigned short* OHl = OHh + NELEM_;               // OH lo

  hipMemsetAsync(tC, 0, TTOT_ * sizeof(int), stream);

  // ---- routing features (exact f32 path, decoupled from bf16 GEMMs) ----
  wmean<<<256, 256, 0, stream>>>(Wq, Wqm);
  wmean<<<256, 256, 0, stream>>>(Wk, Wkm);
  gemm_nt<<<dim3(TTOT_ / 64, 1), 256, 0, stream>>>(q_in, Wqm, FQ, TTOT_, 64, 1024);
  gemm_nt<<<dim3(TTOT_ / 64, 1), 256, 0, stream>>>(k_in, Wkm, FK, TTOT_, 64, 1024);
  l2comb<<<TTOT_ / 4, 256, 0, stream>>>(FQ, FK, FE);
  routing_kernel<<<S_, 1024, 0, stream>>>(FE, seqlens, gidx, cT, cL, tC);

  // ---- Q/K/V projections: split-bf16 MFMA GEMMs ----
  const int n4in = (int)(NELEM_ / 4);
  const int n4w = (1024 * 1024) / 4;
  dim3 gg(TTOT_ / 128, D_ / 128);

  conv_split<<<(n4w + 255) / 256, 256, 0, stream>>>(Wq, WSh, WSl, n4w);
  conv_split<<<(n4in + 255) / 256, 256, 0, stream>>>(q_in, SPh, SPl, n4in);
  gemm_bf16s<<<gg, 256, 0, stream>>>(SPh, SPl, WSh, WSl, Q, TTOT_, D_, D_);

  conv_split<<<(n4w + 255) / 256, 256, 0, stream>>>(Wk, WSh, WSl, n4w);
  conv_split<<<(n4in + 255) / 256, 256, 0, stream>>>(k_in, SPh, SPl, n4in);
  gemm_bf16s<<<gg, 256, 0, stream>>>(SPh, SPl, WSh, WSl, K, TTOT_, D_, D_);

  conv_split<<<(n4w + 255) / 256, 256, 0, stream>>>(Wv, WSh, WSl, n4w);
  conv_split<<<(n4in + 255) / 256, 256, 0, stream>>>(v_in, SPh, SPl, n4in);
  gemm_bf16s<<<gg, 256, 0, stream>>>(SPh, SPl, WSh, WSl, V, TTOT_, D_, D_);

  // ---- attention (OH aliases the now-dead input-split slab) ----
  hipMemsetAsync(OH, 0, NELEM_ * sizeof(float), stream);
  attn_kernel<<<dim3(MAXCL_, H_, (MAXLEN_ + 63) / 64), 256, 0, stream>>>(Q, K, V, cT, cL, OH);

  // ---- normalize + split (into dead Q slab), output GEMM ----
  norm_split<<<(unsigned)((NELEM_ / 4 + 255) / 256), 256, 0, stream>>>(OH, tC, OHh, OHl);
  conv_split<<<(n4w + 255) / 256, 256, 0, stream>>>(Wo, WSh, WSl, n4w);
  gemm_bf16s<<<gg, 256, 0, stream>>>(OHh, OHl, WSh, WSl, out, TTOT_, D_, D_);
}

// Round 5
// 829.277 us; speedup vs baseline: 4.1588x; 1.3380x over previous
//
#include <hip/hip_runtime.h>
#include <math.h>

#define S_ 4
#define L_ 2048
#define D_ 1024
#define H_ 16
#define DH_ 64
#define TTOT_ 8192
#define WCL_ 384
#define KMAX_ 16
#define MAXCL_ (S_*KMAX_)
#define MAXLEN_ (WCL_+1)   // 385
#define LSCAP_ 4096
#define NELEM_ ((size_t)TTOT_*(size_t)D_)

typedef __attribute__((ext_vector_type(8))) short bf16x8;
typedef __attribute__((ext_vector_type(4))) float f32x4;
typedef __attribute__((ext_vector_type(4))) unsigned short u16x4;

// bf16 split helpers (RNE)
__device__ __forceinline__ unsigned short bfh(float x) {
  unsigned u = __float_as_uint(x);
  return (unsigned short)((u + 0x7FFFu + ((u >> 16) & 1u)) >> 16);
}
__device__ __forceinline__ float bff(unsigned short h) {
  return __uint_as_float(((unsigned)h) << 16);
}
__device__ __forceinline__ unsigned pk2(unsigned short a, unsigned short b) {
  return (unsigned)a | ((unsigned)b << 16);
}
// XOR swizzle on ushort index within [row][64] tiles (16B-chunk granularity)
#define SWZ(r, c) (((r) << 6) + ((c) ^ (((r) & 7) << 3)))

__device__ __forceinline__ void glds16(const void* g, void* l) {
  __builtin_amdgcn_global_load_lds(
      (const __attribute__((address_space(1))) unsigned int*)g,
      (__attribute__((address_space(3))) unsigned int*)l, 16, 0, 0);
}

// ---------------------------------------------------------------------------
// f32 GEMM (kept for the small, routing-exact feats GEMMs): C=A[M,K]*B[N,K]^T
// ---------------------------------------------------------------------------
__global__ __launch_bounds__(256)
void gemm_nt(const float* __restrict__ A, const float* __restrict__ B,
             float* __restrict__ C, int M, int N, int Kd) {
  __shared__ float As[16][68];
  __shared__ float Bs[16][68];
  const int tx = threadIdx.x & 15, ty = threadIdx.x >> 4;
  const int m0 = blockIdx.x * 64, n0 = blockIdx.y * 64;
  const int lr = threadIdx.x >> 2, lc = threadIdx.x & 3;
  float acc[4][4] = {};
  for (int k0 = 0; k0 < Kd; k0 += 16) {
    __syncthreads();
    float4 a4 = *(const float4*)(A + (size_t)(m0 + lr) * Kd + k0 + lc * 4);
    float4 b4 = *(const float4*)(B + (size_t)(n0 + lr) * Kd + k0 + lc * 4);
    As[lc*4+0][lr] = a4.x; As[lc*4+1][lr] = a4.y; As[lc*4+2][lr] = a4.z; As[lc*4+3][lr] = a4.w;
    Bs[lc*4+0][lr] = b4.x; Bs[lc*4+1][lr] = b4.y; Bs[lc*4+2][lr] = b4.z; Bs[lc*4+3][lr] = b4.w;
    __syncthreads();
#pragma unroll
    for (int kk = 0; kk < 16; kk++) {
      float4 av = *(const float4*)&As[kk][ty * 4];
      float4 bv = *(const float4*)&Bs[kk][tx * 4];
      float aa[4] = {av.x, av.y, av.z, av.w};
      float bb[4] = {bv.x, bv.y, bv.z, bv.w};
#pragma unroll
      for (int i = 0; i < 4; i++)
#pragma unroll
        for (int j = 0; j < 4; j++) acc[i][j] += aa[i] * bb[j];
    }
  }
#pragma unroll
  for (int i = 0; i < 4; i++)
#pragma unroll
    for (int j = 0; j < 4; j++)
      C[(size_t)(m0 + ty * 4 + i) * N + (n0 + tx * 4 + j)] = acc[i][j];
}

// ---------------------------------------------------------------------------
// Split-bf16 MFMA GEMM core: 128x128 tile, BK=64, 4 waves, glds staging.
// Two epilogues: f32 C (final) and split hi/lo C (projections).
// ---------------------------------------------------------------------------
#define GEMM_BODY                                                              \
  __shared__ __align__(16) unsigned short LA[2][128 * 64];                     \
  __shared__ __align__(16) unsigned short LB[2][128 * 64];                     \
  const int tid = threadIdx.x, wave = tid >> 6, lane = tid & 63;               \
  const int lm = lane & 15, lg = lane >> 4;                                    \
  const int m0 = blockIdx.x * 128, n0 = blockIdx.y * 128;                      \
  const int wr = wave >> 1, wc = wave & 1;                                     \
  const int lrow = lane >> 3;                                                  \
  const int lchk = (lane & 7) ^ lrow;                                          \
  f32x4 acc[4][4];                                                             \
  _Pragma("unroll") for (int i = 0; i < 4; i++)                                \
      _Pragma("unroll") for (int j = 0; j < 4; j++)                            \
          acc[i][j] = (f32x4){0.f, 0.f, 0.f, 0.f};                             \
  for (int k0 = 0; k0 < Kd; k0 += 64) {                                        \
    __syncthreads();                                                           \
    _Pragma("unroll") for (int i = 0; i < 4; i++) {                            \
      const int r = wave * 32 + i * 8;                                         \
      const size_t ga = (size_t)(m0 + r + lrow) * Kd + k0 + lchk * 8;          \
      const size_t gb = (size_t)(n0 + r + lrow) * Kd + k0 + lchk * 8;          \
      glds16(&Ah[ga], &LA[0][r * 64]);                                         \
      glds16(&Al[ga], &LA[1][r * 64]);                                         \
      glds16(&Bh[gb], &LB[0][r * 64]);                                         \
      glds16(&Bl[gb], &LB[1][r * 64]);                                         \
    }                                                                          \
    __syncthreads();                                                           \
    _Pragma("unroll") for (int s = 0; s < 2; s++) {                            \
      bf16x8 ah[4], al[4], bh[4], bl[4];                                       \
      _Pragma("unroll") for (int i = 0; i < 4; i++) {                          \
        const int ra = wr * 64 + i * 16 + lm;                                  \
        const int ca = ((s * 4 + lg) ^ (ra & 7)) * 8;                          \
        ah[i] = *(const bf16x8*)&LA[0][ra * 64 + ca];                          \
        al[i] = *(const bf16x8*)&LA[1][ra * 64 + ca];                          \
        const int rb = wc * 64 + i * 16 + lm;                                  \
        const int cb = ((s * 4 + lg) ^ (rb & 7)) * 8;                          \
        bh[i] = *(const bf16x8*)&LB[0][rb * 64 + cb];                          \
        bl[i] = *(const bf16x8*)&LB[1][rb * 64 + cb];                          \
      }                                                                        \
      _Pragma("unroll") for (int i = 0; i < 4; i++)                            \
          _Pragma("unroll") for (int j = 0; j < 4; j++) {                      \
        acc[i][j] = __builtin_amdgcn_mfma_f32_16x16x32_bf16(ah[i], bh[j], acc[i][j], 0, 0, 0); \
        acc[i][j] = __builtin_amdgcn_mfma_f32_16x16x32_bf16(al[i], bh[j], acc[i][j], 0, 0, 0); \
        acc[i][j] = __builtin_amdgcn_mfma_f32_16x16x32_bf16(ah[i], bl[j], acc[i][j], 0, 0, 0); \
      }                                                                        \
    }                                                                          \
  }

__global__ __launch_bounds__(256)
void gemm_bf16s(const unsigned short* __restrict__ Ah, const unsigned short* __restrict__ Al,
                const unsigned short* __restrict__ Bh, const unsigned short* __restrict__ Bl,
                float* __restrict__ C, int M, int N, int Kd) {
  GEMM_BODY
#pragma unroll
  for (int i = 0; i < 4; i++)
#pragma unroll
    for (int j = 0; j < 4; j++) {
      const int rowb = m0 + wr * 64 + i * 16 + lg * 4;
      const int col = n0 + wc * 64 + j * 16 + lm;
#pragma unroll
      for (int r = 0; r < 4; r++)
        C[(size_t)(rowb + r) * N + col] = acc[i][j][r];
    }
}

__global__ __launch_bounds__(256)
void gemm_bf16s_sp(const unsigned short* __restrict__ Ah, const unsigned short* __restrict__ Al,
                   const unsigned short* __restrict__ Bh, const unsigned short* __restrict__ Bl,
                   unsigned short* __restrict__ Ch, unsigned short* __restrict__ Cl,
                   int M, int N, int Kd) {
  GEMM_BODY
#pragma unroll
  for (int i = 0; i < 4; i++)
#pragma unroll
    for (int j = 0; j < 4; j++) {
      const int rowb = m0 + wr * 64 + i * 16 + lg * 4;
      const int col = n0 + wc * 64 + j * 16 + lm;
#pragma unroll
      for (int r = 0; r < 4; r++) {
        float v = acc[i][j][r];
        unsigned short hh = bfh(v);
        Ch[(size_t)(rowb + r) * N + col] = hh;
        Cl[(size_t)(rowb + r) * N + col] = bfh(v - bff(hh));
      }
    }
}

// ---------------------------------------------------------------------------
// f32 -> (hi,lo) bf16 split, vectorized
// ---------------------------------------------------------------------------
__global__ __launch_bounds__(256)
void conv_split(const float* __restrict__ src, unsigned short* __restrict__ dh,
                unsigned short* __restrict__ dl, int n4) {
  int i = blockIdx.x * 256 + threadIdx.x;
  if (i >= n4) return;
  float4 v = ((const float4*)src)[i];
  unsigned short h0 = bfh(v.x), h1 = bfh(v.y), h2 = bfh(v.z), h3 = bfh(v.w);
  *(uint2*)&dh[(size_t)i * 4] = make_uint2(pk2(h0, h1), pk2(h2, h3));
  *(uint2*)&dl[(size_t)i * 4] =
      make_uint2(pk2(bfh(v.x - bff(h0)), bfh(v.y - bff(h1))),
                 pk2(bfh(v.z - bff(h2)), bfh(v.w - bff(h3))));
}

// ---------------------------------------------------------------------------
// Wm[d][k] = (1/16) sum_h W[h*64+d][k]   (64 x 1024 output)
// ---------------------------------------------------------------------------
__global__ __launch_bounds__(256)
void wmean(const float* __restrict__ W, float* __restrict__ Wm) {
  int i = blockIdx.x * 256 + threadIdx.x;
  if (i >= 64 * 1024) return;
  int d = i >> 10, kk = i & 1023;
  float s = 0.f;
#pragma unroll
  for (int h = 0; h < 16; h++) s += W[(size_t)(h * 64 + d) * 1024 + kk];
  Wm[i] = s * (1.0f / 16.0f);
}

// ---------------------------------------------------------------------------
// FE[t] = 0.5*(l2n(FQ[t]) + l2n(FK[t]))   (one wave per token)
// ---------------------------------------------------------------------------
__global__ __launch_bounds__(256)
void l2comb(const float* __restrict__ FQ, const float* __restrict__ FK,
            float* __restrict__ FE) {
  int t = blockIdx.x * 4 + (threadIdx.x >> 6);
  int lane = threadIdx.x & 63;
  if (t >= TTOT_) return;
  float q = FQ[(size_t)t * 64 + lane], k = FK[(size_t)t * 64 + lane];
  float q2 = q * q, k2 = k * k;
#pragma unroll
  for (int m = 1; m < 64; m <<= 1) {
    q2 += __shfl_xor(q2, m, 64);
    k2 += __shfl_xor(k2, m, 64);
  }
  FE[(size_t)t * 64 + lane] =
      0.5f * (q / (sqrtf(q2) + 1e-6f) + k / (sqrtf(k2) + 1e-6f));
}

// ---------------------------------------------------------------------------
// Routing (exact replica of _route_np) — unchanged
// ---------------------------------------------------------------------------
__device__ __forceinline__ float dot64(const float* __restrict__ f,
                                       const float* __restrict__ c) {
  float s = 0.f;
#pragma unroll
  for (int c4 = 0; c4 < 16; c4++) {
    float4 fv = *(const float4*)(f + c4 * 4);
    float4 cv = *(const float4*)(c + c4 * 4);
    s += fv.x * cv.x; s += fv.y * cv.y; s += fv.z * cv.z; s += fv.w * cv.w;
  }
  return s;
}

__global__ __launch_bounds__(1024)
void routing_kernel(const float* __restrict__ FE, const int* __restrict__ seqlens,
                    const int* __restrict__ gidx, int* __restrict__ cT,
                    int* __restrict__ cL, int* __restrict__ tC) {
  __shared__ float cent[KMAX_][64];
  __shared__ float csum[KMAX_][64];
  __shared__ int cnt1[KMAX_];
  __shared__ int cnt2[KMAX_];
  __shared__ int starts[KMAX_ + 1];
  __shared__ unsigned char assign[LSCAP_];
  __shared__ unsigned long long keys[LSCAP_];

  const int s = blockIdx.x, tid = threadIdx.x;
  int a = 0;
  for (int t = 0; t < s; t++) a += seqlens[t];
  int Ls = seqlens[s];
  if (Ls > LSCAP_) Ls = LSCAP_;
  for (int cs = tid; cs < KMAX_; cs += 1024) cL[s * KMAX_ + cs] = 0;
  if (Ls <= 0) return;

  int wloc = Ls < WCL_ ? Ls : WCL_;
  if (wloc < 1) wloc = 1;
  int k = (Ls + wloc - 1) / wloc;
  if (k < 1) k = 1;
  if (k > KMAX_) k = KMAX_;

  if (tid < k * 64) {
    int j = tid >> 6, d = tid & 63;
    double step = (k > 1) ? (double)(Ls - 1) / (double)(k - 1) : 0.0;
    long ii = (long)rint(step * (double)j);
    if (ii < 0) ii = 0;
    if (ii > Ls - 1) ii = Ls - 1;
    cent[j][d] = FE[(size_t)(a + ii) * DH_ + d];
  }
  if (tid < KMAX_) cnt1[tid] = 0;
  __syncthreads();

  for (int i = tid; i < Ls; i += 1024) {
    const float* f = FE + (size_t)(a + i) * DH_;
    float best = -1e30f; int bj = 0;
    for (int j = 0; j < k; j++) {
      float sd = dot64(f, &cent[j][0]);
      if (sd > best) { best = sd; bj = j; }
    }
    assign[i] = (unsigned char)bj;
  }
  __syncthreads();
  for (int i = tid; i < Ls; i += 1024) atomicAdd(&cnt1[assign[i]], 1);
  __syncthreads();
  if (tid < 64) {
    int d = tid;
    for (int j = 0; j < k; j++) csum[j][d] = 0.f;
    for (int i = 0; i < Ls; i++)
      csum[assign[i]][d] += FE[(size_t)(a + i) * DH_ + d];
  }
  __syncthreads();
  if (tid < k * 64) {
    int j = tid >> 6, d = tid & 63;
    float v = csum[j][d] / fmaxf((float)cnt1[j], 1.0f);
    float sq = v * v;
#pragma unroll
    for (int m = 1; m < 64; m <<= 1) sq += __shfl_xor(sq, m, 64);
    cent[j][d] = v / (sqrtf(sq) + 1e-6f);
  }
  __syncthreads();

  int NP2 = 1;
  while (NP2 < Ls) NP2 <<= 1;
  for (int i = tid; i < NP2; i += 1024) {
    unsigned long long key;
    if (i < Ls) {
      const float* f = FE + (size_t)(a + i) * DH_;
      float best = -1e30f; int bj = 0;
      for (int j = 0; j < k; j++) {
        float sd = dot64(f, &cent[j][0]);
        if (sd > best) { best = sd; bj = j; }
      }
      assign[i] = (unsigned char)bj;
      unsigned int u = __float_as_uint(best);
      unsigned int ord = (u & 0x80000000u) ? ~u : (u | 0x80000000u);
      unsigned int dsc = ~ord;
      key = ((unsigned long long)bj << 45) |
            ((unsigned long long)dsc << 13) | (unsigned long long)i;
    } else {
      key = ~0ull;
    }
    keys[i] = key;
  }
  if (tid < KMAX_) cnt2[tid] = 0;
  __syncthreads();
  for (int i = tid; i < Ls; i += 1024) atomicAdd(&cnt2[assign[i]], 1);
  __syncthreads();

  for (int len2 = 2; len2 <= NP2; len2 <<= 1) {
    for (int st = len2 >> 1; st > 0; st >>= 1) {
      for (int i = tid; i < NP2; i += 1024) {
        int j = i ^ st;
        if (j > i) {
          unsigned long long x = keys[i], y = keys[j];
          bool asc = ((i & len2) == 0);
          if ((x > y) == asc) { keys[i] = y; keys[j] = x; }
        }
      }
      __syncthreads();
    }
  }
  if (tid == 0) {
    starts[0] = 0;
    for (int j = 0; j < k; j++) starts[j + 1] = starts[j] + cnt2[j];
  }
  __syncthreads();

  const int g = gidx[s];
  int cOut = 0;
  for (int j = 0; j < k; j++) {
    int cj = cnt2[j];
    if (cj <= 0) continue;
    int keep = cj < wloc ? cj : wloc;
    int slot = s * KMAX_ + cOut;
    for (int p = tid; p < keep; p += 1024) {
      int token = a + (int)(keys[starts[j] + p] & 0x1FFFull);
      cT[slot * MAXLEN_ + p] = token;
      atomicAdd(&tC[token], 1);
    }
    if (tid == 0) {
      cT[slot * MAXLEN_ + keep] = g;
      atomicAdd(&tC[g], 1);
      cL[slot] = keep + 1;
    }
    cOut++;
  }
}

// ---------------------------------------------------------------------------
// MFMA flash attention, split-bf16 inputs. Block = (cluster, head, 64-q-chunk),
// 4 waves x 16 q-rows. K/Q staged via global_load_lds (pre-swizzled source);
// V^T via ushort register transpose; Q-tile LDS reused as P buffer.
// LDS: toks 1.5K + QP 16K + KT 16K + VT 16K = 49.5 KB -> 3 blocks/CU.
// ---------------------------------------------------------------------------
__global__ __launch_bounds__(256)
void attn_kernel(const unsigned short* __restrict__ Qh, const unsigned short* __restrict__ Ql,
                 const unsigned short* __restrict__ Kh, const unsigned short* __restrict__ Kl,
                 const unsigned short* __restrict__ Vh, const unsigned short* __restrict__ Vl,
                 const int* __restrict__ cT, const int* __restrict__ cL,
                 float* __restrict__ OH) {
  const int c = blockIdx.x, h = blockIdx.y;
  const int len = cL[c];
  const int q0 = blockIdx.z * 64;
  if (len <= 0 || q0 >= len) return;

  __shared__ int toks[MAXLEN_];
  __shared__ __align__(16) unsigned short QP[8192];  // Q hi/lo tile -> P hi/lo
  __shared__ __align__(16) unsigned short KT[8192];  // K hi [0..4095], lo [4096..]
  __shared__ __align__(16) unsigned short VT[8192];  // V^T hi/lo

  const int tid = threadIdx.x, wave = tid >> 6, lane = tid & 63;
  const int lm = lane & 15, lg = lane >> 4;
  const int lr8 = lane >> 3;            // row within 8-row slab
  const int lc8 = (lane & 7) ^ lr8;     // pre-swizzled source chunk

  for (int i = tid; i < len; i += 256) toks[i] = cT[c * MAXLEN_ + i];
  __syncthreads();

  // ---- stage Q tile once (glds, source-swizzled) ----
#pragma unroll
  for (int i = 0; i < 4; i++) {
    int slab = wave * 4 + i;                     // 0..15 (0-7: hi, 8-15: lo)
    int r8 = (slab & 7) * 8;
    int row = q0 + r8 + lr8;
    int tok = toks[row < len ? row : 0];
    const unsigned short* base = (slab < 8) ? Qh : Ql;
    glds16(base + (size_t)tok * D_ + h * DH_ + lc8 * 8,
           &QP[(slab >> 3) * 4096 + r8 * 64]);
  }
  __syncthreads();

  bf16x8 qAh[2], qAl[2];
#pragma unroll
  for (int s = 0; s < 2; s++) {
    qAh[s] = *(const bf16x8*)&QP[SWZ(wave * 16 + lm, s * 32 + lg * 8)];
    qAl[s] = *(const bf16x8*)&QP[4096 + SWZ(wave * 16 + lm, s * 32 + lg * 8)];
  }

  f32x4 accO[4];
#pragma unroll
  for (int t = 0; t < 4; t++) accO[t] = (f32x4){0.f, 0.f, 0.f, 0.f};
  float mm[4] = {-INFINITY, -INFINITY, -INFINITY, -INFINITY};
  float ll[4] = {0.f, 0.f, 0.f, 0.f};

  const int ntile = (len + 63) >> 6;
  for (int mt = 0; mt < ntile; mt++) {
    __syncthreads();  // staging of this tile vs readers of previous tile
    // ---- K tile via glds (source-swizzled) ----
#pragma unroll
    for (int i = 0; i < 4; i++) {
      int slab = wave * 4 + i;
      int r8 = (slab & 7) * 8;
      int kr = mt * 64 + r8 + lr8;
      int tok = toks[kr < len ? kr : 0];
      const unsigned short* base = (slab < 8) ? Kh : Kl;
      glds16(base + (size_t)tok * D_ + h * DH_ + lc8 * 8,
             &KT[(slab >> 3) * 4096 + r8 * 64]);
    }
    // ---- V^T tile: ushort register transpose (no conversion) ----
    {
      const int dg = tid & 15, kg = tid >> 4;
      const int d0 = dg * 4;
      int kr = mt * 64 + kg * 4;
      int t0 = toks[kr + 0 < len ? kr + 0 : 0];
      int t1 = toks[kr + 1 < len ? kr + 1 : 0];
      int t2 = toks[kr + 2 < len ? kr + 2 : 0];
      int t3 = toks[kr + 3 < len ? kr + 3 : 0];
      size_t off = (size_t)h * DH_ + d0;
      u16x4 a0 = *(const u16x4*)(Vh + (size_t)t0 * D_ + off);
      u16x4 a1 = *(const u16x4*)(Vh + (size_t)t1 * D_ + off);
      u16x4 a2 = *(const u16x4*)(Vh + (size_t)t2 * D_ + off);
      u16x4 a3 = *(const u16x4*)(Vh + (size_t)t3 * D_ + off);
      u16x4 b0 = *(const u16x4*)(Vl + (size_t)t0 * D_ + off);
      u16x4 b1 = *(const u16x4*)(Vl + (size_t)t1 * D_ + off);
      u16x4 b2 = *(const u16x4*)(Vl + (size_t)t2 * D_ + off);
      u16x4 b3 = *(const u16x4*)(Vl + (size_t)t3 * D_ + off);
#pragma unroll
      for (int dd = 0; dd < 4; dd++) {
        *(uint2*)&VT[SWZ(d0 + dd, kg * 4)] =
            make_uint2(pk2(a0[dd], a1[dd]), pk2(a2[dd], a3[dd]));
        *(uint2*)&VT[4096 + SWZ(d0 + dd, kg * 4)] =
            make_uint2(pk2(b0[dd], b1[dd]), pk2(b2[dd], b3[dd]));
      }
    }
    __syncthreads();

    // ---- QK^T: 4 key-tiles x 2 k-slabs x 3 split terms ----
    f32x4 sA[4];
#pragma unroll
    for (int t = 0; t < 4; t++) sA[t] = (f32x4){0.f, 0.f, 0.f, 0.f};
#pragma unroll
    for (int t = 0; t < 4; t++) {
#pragma unroll
      for (int s = 0; s < 2; s++) {
        bf16x8 kb = *(const bf16x8*)&KT[SWZ(t * 16 + lm, s * 32 + lg * 8)];
        bf16x8 kl2 = *(const bf16x8*)&KT[4096 + SWZ(t * 16 + lm, s * 32 + lg * 8)];
        sA[t] = __builtin_amdgcn_mfma_f32_16x16x32_bf16(qAh[s], kb, sA[t], 0, 0, 0);
        sA[t] = __builtin_amdgcn_mfma_f32_16x16x32_bf16(qAl[s], kb, sA[t], 0, 0, 0);
        sA[t] = __builtin_amdgcn_mfma_f32_16x16x32_bf16(qAh[s], kl2, sA[t], 0, 0, 0);
      }
    }

    // ---- mask + online softmax ----
    float sc[4][4];
#pragma unroll
    for (int t = 0; t < 4; t++) {
      bool kvalid = (mt * 64 + t * 16 + lm) < len;
#pragma unroll
      for (int r = 0; r < 4; r++)
        sc[t][r] = kvalid ? sA[t][r] * 0.125f : -1e9f;
    }
    float mx[4], nn[4], cor[4], sum[4];
#pragma unroll
    for (int r = 0; r < 4; r++) {
      mx[r] = fmaxf(fmaxf(sc[0][r], sc[1][r]), fmaxf(sc[2][r], sc[3][r]));
      mx[r] = fmaxf(mx[r], __shfl_xor(mx[r], 1, 64));
      mx[r] = fmaxf(mx[r], __shfl_xor(mx[r], 2, 64));
      mx[r] = fmaxf(mx[r], __shfl_xor(mx[r], 4, 64));
      mx[r] = fmaxf(mx[r], __shfl_xor(mx[r], 8, 64));
      nn[r] = fmaxf(mm[r], mx[r]);
      cor[r] = __expf(mm[r] - nn[r]);
      mm[r] = nn[r];
    }
    float pp[4][4];
#pragma unroll
    for (int t = 0; t < 4; t++)
#pragma unroll
      for (int r = 0; r < 4; r++) pp[t][r] = __expf(sc[t][r] - nn[r]);
#pragma unroll
    for (int r = 0; r < 4; r++) {
      sum[r] = (pp[0][r] + pp[1][r]) + (pp[2][r] + pp[3][r]);
      sum[r] += __shfl_xor(sum[r], 1, 64);
      sum[r] += __shfl_xor(sum[r], 2, 64);
      sum[r] += __shfl_xor(sum[r], 4, 64);
      sum[r] += __shfl_xor(sum[r], 8, 64);
      ll[r] = ll[r] * cor[r] + sum[r];
    }
    // ---- P hi/lo into the (dead-Q) QP buffer, per-wave region ----
#pragma unroll
    for (int t = 0; t < 4; t++) {
#pragma unroll
      for (int r = 0; r < 4; r++) {
        accO[t][r] *= cor[r];
        int row = wave * 16 + lg * 4 + r, col = t * 16 + lm;
        unsigned short hp = bfh(pp[t][r]);
        QP[SWZ(row, col)] = hp;
        QP[4096 + SWZ(row, col)] = bfh(pp[t][r] - bff(hp));
      }
    }

    // ---- PV: 3 split terms ----
    bf16x8 pAh[2], pAl[2];
#pragma unroll
    for (int s = 0; s < 2; s++) {
      pAh[s] = *(const bf16x8*)&QP[SWZ(wave * 16 + lm, s * 32 + lg * 8)];
      pAl[s] = *(const bf16x8*)&QP[4096 + SWZ(wave * 16 + lm, s * 32 + lg * 8)];
    }
#pragma unroll
    for (int t = 0; t < 4; t++) {
#pragma unroll
      for (int s = 0; s < 2; s++) {
        bf16x8 vb = *(const bf16x8*)&VT[SWZ(t * 16 + lm, s * 32 + lg * 8)];
        bf16x8 vl2 = *(const bf16x8*)&VT[4096 + SWZ(t * 16 + lm, s * 32 + lg * 8)];
        accO[t] = __builtin_amdgcn_mfma_f32_16x16x32_bf16(pAh[s], vb, accO[t], 0, 0, 0);
        accO[t] = __builtin_amdgcn_mfma_f32_16x16x32_bf16(pAl[s], vb, accO[t], 0, 0, 0);
        accO[t] = __builtin_amdgcn_mfma_f32_16x16x32_bf16(pAh[s], vl2, accO[t], 0, 0, 0);
      }
    }
  }

  // ---- epilogue: normalize, scatter-add ----
#pragma unroll
  for (int t = 0; t < 4; t++) {
#pragma unroll
    for (int r = 0; r < 4; r++) {
      int row = q0 + wave * 16 + lg * 4 + r;
      if (row < len)
        atomicAdd(&OH[(size_t)toks[row] * D_ + h * DH_ + t * 16 + lm],
                  accO[t][r] / ll[r]);
    }
  }
}

// ---------------------------------------------------------------------------
// out_h /= clip(cnt,1), then split to bf16 hi/lo for the output GEMM
// ---------------------------------------------------------------------------
__global__ __launch_bounds__(256)
void norm_split(const float* __restrict__ OH, const int* __restrict__ cnt,
                unsigned short* __restrict__ oh, unsigned short* __restrict__ ol) {
  size_t i = (size_t)blockIdx.x * 256 + threadIdx.x;
  size_t n4 = NELEM_ / 4;
  if (i >= n4) return;
  int row = (int)((i * 4) >> 10);
  int cc = cnt[row];
  float s = 1.0f / (float)(cc > 1 ? cc : 1);
  float4 v = ((const float4*)OH)[i];
  v.x *= s; v.y *= s; v.z *= s; v.w *= s;
  unsigned short h0 = bfh(v.x), h1 = bfh(v.y), h2 = bfh(v.z), h3 = bfh(v.w);
  *(uint2*)&oh[i * 4] = make_uint2(pk2(h0, h1), pk2(h2, h3));
  *(uint2*)&ol[i * 4] =
      make_uint2(pk2(bfh(v.x - bff(h0)), bfh(v.y - bff(h1))),
                 pk2(bfh(v.z - bff(h2)), bfh(v.w - bff(h3))));
}

// ---------------------------------------------------------------------------
extern "C" void kernel_launch(void* const* d_in, const int* in_sizes, int n_in,
                              void* d_out, int out_size, void* d_ws, size_t ws_size,
                              hipStream_t stream) {
  (void)in_sizes; (void)n_in; (void)out_size; (void)ws_size;
  const float* q_in = (const float*)d_in[0];
  const float* k_in = (const float*)d_in[1];
  const float* v_in = (const float*)d_in[2];
  const int* seqlens = (const int*)d_in[3];
  const int* gidx    = (const int*)d_in[4];
  const float* Wq = (const float*)d_in[5];
  const float* Wk = (const float*)d_in[6];
  const float* Wv = (const float*)d_in[7];
  const float* Wo = (const float*)d_in[8];
  float* out = (float*)d_out;

  // workspace layout (bytes): 6*NELEM_*2 (QKV splits) + NELEM_*4 (OH, aliased
  // by input splits) + 4MB (wt splits) + feats + routing ints  ~= 145 MB
  unsigned short* Qh = (unsigned short*)d_ws;
  unsigned short* Ql = Qh + NELEM_;
  unsigned short* Kh = Ql + NELEM_;
  unsigned short* Kl = Kh + NELEM_;
  unsigned short* Vh = Kl + NELEM_;
  unsigned short* Vl = Vh + NELEM_;
  float* OH = (float*)(Vl + NELEM_);
  float* WS = OH + NELEM_;
  float* FE = WS + (1 << 20);
  float* FQ = FE + (size_t)TTOT_ * DH_;
  float* FK = FQ + (size_t)TTOT_ * DH_;
  float* Wqm = FK + (size_t)TTOT_ * DH_;
  float* Wkm = Wqm + 64 * 1024;
  int* cT = (int*)(Wkm + 64 * 1024);
  int* cL = cT + MAXCL_ * MAXLEN_;
  int* tC = cL + MAXCL_;

  unsigned short* SPh = (unsigned short*)OH;   // input splits (dead before OH)
  unsigned short* SPl = SPh + NELEM_;
  unsigned short* WSh = (unsigned short*)WS;
  unsigned short* WSl = WSh + (1 << 20);
  unsigned short* OHh = Qh;                    // OH splits (Q dead after attn)
  unsigned short* OHl = Ql;

  hipMemsetAsync(tC, 0, TTOT_ * sizeof(int), stream);

  // ---- routing features (exact f32 path) ----
  wmean<<<256, 256, 0, stream>>>(Wq, Wqm);
  wmean<<<256, 256, 0, stream>>>(Wk, Wkm);
  gemm_nt<<<dim3(TTOT_ / 64, 1), 256, 0, stream>>>(q_in, Wqm, FQ, TTOT_, 64, 1024);
  gemm_nt<<<dim3(TTOT_ / 64, 1), 256, 0, stream>>>(k_in, Wkm, FK, TTOT_, 64, 1024);
  l2comb<<<TTOT_ / 4, 256, 0, stream>>>(FQ, FK, FE);
  routing_kernel<<<S_, 1024, 0, stream>>>(FE, seqlens, gidx, cT, cL, tC);

  // ---- Q/K/V projections: split-bf16 MFMA GEMMs with split epilogue ----
  const int n4in = (int)(NELEM_ / 4);
  const int n4w = (1024 * 1024) / 4;
  dim3 gg(TTOT_ / 128, D_ / 128);

  conv_split<<<(n4w + 255) / 256, 256, 0, stream>>>(Wq, WSh, WSl, n4w);
  conv_split<<<(n4in + 255) / 256, 256, 0, stream>>>(q_in, SPh, SPl, n4in);
  gemm_bf16s_sp<<<gg, 256, 0, stream>>>(SPh, SPl, WSh, WSl, Qh, Ql, TTOT_, D_, D_);

  conv_split<<<(n4w + 255) / 256, 256, 0, stream>>>(Wk, WSh, WSl, n4w);
  conv_split<<<(n4in + 255) / 256, 256, 0, stream>>>(k_in, SPh, SPl, n4in);
  gemm_bf16s_sp<<<gg, 256, 0, stream>>>(SPh, SPl, WSh, WSl, Kh, Kl, TTOT_, D_, D_);

  conv_split<<<(n4w + 255) / 256, 256, 0, stream>>>(Wv, WSh, WSl, n4w);
  conv_split<<<(n4in + 255) / 256, 256, 0, stream>>>(v_in, SPh, SPl, n4in);
  gemm_bf16s_sp<<<gg, 256, 0, stream>>>(SPh, SPl, WSh, WSl, Vh, Vl, TTOT_, D_, D_);

  // ---- attention (OH aliases the now-dead input-split slab) ----
  hipMemsetAsync(OH, 0, NELEM_ * sizeof(float), stream);
  attn_kernel<<<dim3(MAXCL_, H_, (MAXLEN_ + 63) / 64), 256, 0, stream>>>(
      Qh, Ql, Kh, Kl, Vh, Vl, cT, cL, OH);

  // ---- normalize + split (into dead Q slab), output GEMM ----
  norm_split<<<(unsigned)((NELEM_ / 4 + 255) / 256), 256, 0, stream>>>(OH, tC, OHh, OHl);
  conv_split<<<(n4w + 255) / 256, 256, 0, stream>>>(Wo, WSh, WSl, n4w);
  gemm_bf16s<<<gg, 256, 0, stream>>>(OHh, OHl, WSh, WSl, out, TTOT_, D_, D_);
}

// Round 6
// 627.412 us; speedup vs baseline: 5.4968x; 1.3217x over previous
//
#include <hip/hip_runtime.h>
#include <math.h>

#define S_ 4
#define L_ 2048
#define D_ 1024
#define H_ 16
#define DH_ 64
#define TTOT_ 8192
#define WCL_ 384
#define KMAX_ 16
#define MAXCL_ (S_*KMAX_)
#define MAXLEN_ (WCL_+1)   // 385
#define LSCAP_ 4096
#define NELEM_ ((size_t)TTOT_*(size_t)D_)

typedef __attribute__((ext_vector_type(8))) short bf16x8;
typedef __attribute__((ext_vector_type(4))) float f32x4;
typedef __attribute__((ext_vector_type(4))) unsigned short u16x4;

// bf16 split helpers (RNE)
__device__ __forceinline__ unsigned short bfh(float x) {
  unsigned u = __float_as_uint(x);
  return (unsigned short)((u + 0x7FFFu + ((u >> 16) & 1u)) >> 16);
}
__device__ __forceinline__ float bff(unsigned short h) {
  return __uint_as_float(((unsigned)h) << 16);
}
__device__ __forceinline__ unsigned pk2(unsigned short a, unsigned short b) {
  return (unsigned)a | ((unsigned)b << 16);
}
// XOR swizzle on ushort index within [row][64] tiles (16B-chunk granularity)
#define SWZ(r, c) (((r) << 6) + ((c) ^ (((r) & 7) << 3)))

__device__ __forceinline__ void glds16(const void* g, void* l) {
  __builtin_amdgcn_global_load_lds(
      (const __attribute__((address_space(1))) unsigned int*)g,
      (__attribute__((address_space(3))) unsigned int*)l, 16, 0, 0);
}

// ---------------------------------------------------------------------------
// f32 GEMM (kept for the small, routing-exact feats GEMMs): C=A[M,K]*B[N,K]^T
// ---------------------------------------------------------------------------
__global__ __launch_bounds__(256)
void gemm_nt(const float* __restrict__ A, const float* __restrict__ B,
             float* __restrict__ C, int M, int N, int Kd) {
  __shared__ float As[16][68];
  __shared__ float Bs[16][68];
  const int tx = threadIdx.x & 15, ty = threadIdx.x >> 4;
  const int m0 = blockIdx.x * 64, n0 = blockIdx.y * 64;
  const int lr = threadIdx.x >> 2, lc = threadIdx.x & 3;
  float acc[4][4] = {};
  for (int k0 = 0; k0 < Kd; k0 += 16) {
    __syncthreads();
    float4 a4 = *(const float4*)(A + (size_t)(m0 + lr) * Kd + k0 + lc * 4);
    float4 b4 = *(const float4*)(B + (size_t)(n0 + lr) * Kd + k0 + lc * 4);
    As[lc*4+0][lr] = a4.x; As[lc*4+1][lr] = a4.y; As[lc*4+2][lr] = a4.z; As[lc*4+3][lr] = a4.w;
    Bs[lc*4+0][lr] = b4.x; Bs[lc*4+1][lr] = b4.y; Bs[lc*4+2][lr] = b4.z; Bs[lc*4+3][lr] = b4.w;
    __syncthreads();
#pragma unroll
    for (int kk = 0; kk < 16; kk++) {
      float4 av = *(const float4*)&As[kk][ty * 4];
      float4 bv = *(const float4*)&Bs[kk][tx * 4];
      float aa[4] = {av.x, av.y, av.z, av.w};
      float bb[4] = {bv.x, bv.y, bv.z, bv.w};
#pragma unroll
      for (int i = 0; i < 4; i++)
#pragma unroll
        for (int j = 0; j < 4; j++) acc[i][j] += aa[i] * bb[j];
    }
  }
#pragma unroll
  for (int i = 0; i < 4; i++)
#pragma unroll
    for (int j = 0; j < 4; j++)
      C[(size_t)(m0 + ty * 4 + i) * N + (n0 + tx * 4 + j)] = acc[i][j];
}

// ---------------------------------------------------------------------------
// Split-bf16 MFMA GEMM core: 128x128 tile, BK=64, 4 waves, glds staging.
// ---------------------------------------------------------------------------
#define GEMM_BODY                                                              \
  __shared__ __align__(16) unsigned short LA[2][128 * 64];                     \
  __shared__ __align__(16) unsigned short LB[2][128 * 64];                     \
  const int tid = threadIdx.x, wave = tid >> 6, lane = tid & 63;               \
  const int lm = lane & 15, lg = lane >> 4;                                    \
  const int m0 = blockIdx.x * 128, n0 = blockIdx.y * 128;                      \
  const int wr = wave >> 1, wc = wave & 1;                                     \
  const int lrow = lane >> 3;                                                  \
  const int lchk = (lane & 7) ^ lrow;                                          \
  f32x4 acc[4][4];                                                             \
  _Pragma("unroll") for (int i = 0; i < 4; i++)                                \
      _Pragma("unroll") for (int j = 0; j < 4; j++)                            \
          acc[i][j] = (f32x4){0.f, 0.f, 0.f, 0.f};                             \
  for (int k0 = 0; k0 < Kd; k0 += 64) {                                        \
    __syncthreads();                                                           \
    _Pragma("unroll") for (int i = 0; i < 4; i++) {                            \
      const int r = wave * 32 + i * 8;                                         \
      const size_t ga = (size_t)(m0 + r + lrow) * Kd + k0 + lchk * 8;          \
      const size_t gb = (size_t)(n0 + r + lrow) * Kd + k0 + lchk * 8;          \
      glds16(&Ah[ga], &LA[0][r * 64]);                                         \
      glds16(&Al[ga], &LA[1][r * 64]);                                         \
      glds16(&Bh[gb], &LB[0][r * 64]);                                         \
      glds16(&Bl[gb], &LB[1][r * 64]);                                         \
    }                                                                          \
    __syncthreads();                                                           \
    _Pragma("unroll") for (int s = 0; s < 2; s++) {                            \
      bf16x8 ah[4], al[4], bh[4], bl[4];                                       \
      _Pragma("unroll") for (int i = 0; i < 4; i++) {                          \
        const int ra = wr * 64 + i * 16 + lm;                                  \
        const int ca = ((s * 4 + lg) ^ (ra & 7)) * 8;                          \
        ah[i] = *(const bf16x8*)&LA[0][ra * 64 + ca];                          \
        al[i] = *(const bf16x8*)&LA[1][ra * 64 + ca];                          \
        const int rb = wc * 64 + i * 16 + lm;                                  \
        const int cb = ((s * 4 + lg) ^ (rb & 7)) * 8;                          \
        bh[i] = *(const bf16x8*)&LB[0][rb * 64 + cb];                          \
        bl[i] = *(const bf16x8*)&LB[1][rb * 64 + cb];                          \
      }                                                                        \
      _Pragma("unroll") for (int i = 0; i < 4; i++)                            \
          _Pragma("unroll") for (int j = 0; j < 4; j++) {                      \
        acc[i][j] = __builtin_amdgcn_mfma_f32_16x16x32_bf16(ah[i], bh[j], acc[i][j], 0, 0, 0); \
        acc[i][j] = __builtin_amdgcn_mfma_f32_16x16x32_bf16(al[i], bh[j], acc[i][j], 0, 0, 0); \
        acc[i][j] = __builtin_amdgcn_mfma_f32_16x16x32_bf16(ah[i], bl[j], acc[i][j], 0, 0, 0); \
      }                                                                        \
    }                                                                          \
  }

__global__ __launch_bounds__(256)
void gemm_bf16s(const unsigned short* __restrict__ Ah, const unsigned short* __restrict__ Al,
                const unsigned short* __restrict__ Bh, const unsigned short* __restrict__ Bl,
                float* __restrict__ C, int M, int N, int Kd) {
  GEMM_BODY
#pragma unroll
  for (int i = 0; i < 4; i++)
#pragma unroll
    for (int j = 0; j < 4; j++) {
      const int rowb = m0 + wr * 64 + i * 16 + lg * 4;
      const int col = n0 + wc * 64 + j * 16 + lm;
#pragma unroll
      for (int r = 0; r < 4; r++)
        C[(size_t)(rowb + r) * N + col] = acc[i][j][r];
    }
}

__global__ __launch_bounds__(256)
void gemm_bf16s_sp(const unsigned short* __restrict__ Ah, const unsigned short* __restrict__ Al,
                   const unsigned short* __restrict__ Bh, const unsigned short* __restrict__ Bl,
                   unsigned short* __restrict__ Ch, unsigned short* __restrict__ Cl,
                   int M, int N, int Kd) {
  GEMM_BODY
#pragma unroll
  for (int i = 0; i < 4; i++)
#pragma unroll
    for (int j = 0; j < 4; j++) {
      const int rowb = m0 + wr * 64 + i * 16 + lg * 4;
      const int col = n0 + wc * 64 + j * 16 + lm;
#pragma unroll
      for (int r = 0; r < 4; r++) {
        float v = acc[i][j][r];
        unsigned short hh = bfh(v);
        Ch[(size_t)(rowb + r) * N + col] = hh;
        Cl[(size_t)(rowb + r) * N + col] = bfh(v - bff(hh));
      }
    }
}

// ---------------------------------------------------------------------------
// f32 -> (hi,lo) bf16 split, vectorized
// ---------------------------------------------------------------------------
__global__ __launch_bounds__(256)
void conv_split(const float* __restrict__ src, unsigned short* __restrict__ dh,
                unsigned short* __restrict__ dl, int n4) {
  int i = blockIdx.x * 256 + threadIdx.x;
  if (i >= n4) return;
  float4 v = ((const float4*)src)[i];
  unsigned short h0 = bfh(v.x), h1 = bfh(v.y), h2 = bfh(v.z), h3 = bfh(v.w);
  *(uint2*)&dh[(size_t)i * 4] = make_uint2(pk2(h0, h1), pk2(h2, h3));
  *(uint2*)&dl[(size_t)i * 4] =
      make_uint2(pk2(bfh(v.x - bff(h0)), bfh(v.y - bff(h1))),
                 pk2(bfh(v.z - bff(h2)), bfh(v.w - bff(h3))));
}

// ---------------------------------------------------------------------------
// Wm[d][k] = (1/16) sum_h W[h*64+d][k]   (64 x 1024 output)
// ---------------------------------------------------------------------------
__global__ __launch_bounds__(256)
void wmean(const float* __restrict__ W, float* __restrict__ Wm) {
  int i = blockIdx.x * 256 + threadIdx.x;
  if (i >= 64 * 1024) return;
  int d = i >> 10, kk = i & 1023;
  float s = 0.f;
#pragma unroll
  for (int h = 0; h < 16; h++) s += W[(size_t)(h * 64 + d) * 1024 + kk];
  Wm[i] = s * (1.0f / 16.0f);
}

// ---------------------------------------------------------------------------
// FE[t] = 0.5*(l2n(FQ[t]) + l2n(FK[t]))   (one wave per token)
// ---------------------------------------------------------------------------
__global__ __launch_bounds__(256)
void l2comb(const float* __restrict__ FQ, const float* __restrict__ FK,
            float* __restrict__ FE) {
  int t = blockIdx.x * 4 + (threadIdx.x >> 6);
  int lane = threadIdx.x & 63;
  if (t >= TTOT_) return;
  float q = FQ[(size_t)t * 64 + lane], k = FK[(size_t)t * 64 + lane];
  float q2 = q * q, k2 = k * k;
#pragma unroll
  for (int m = 1; m < 64; m <<= 1) {
    q2 += __shfl_xor(q2, m, 64);
    k2 += __shfl_xor(k2, m, 64);
  }
  FE[(size_t)t * 64 + lane] =
      0.5f * (q / (sqrtf(q2) + 1e-6f) + k / (sqrtf(k2) + 1e-6f));
}

// ---------------------------------------------------------------------------
// Routing (exact replica of _route_np) — unchanged
// ---------------------------------------------------------------------------
__device__ __forceinline__ float dot64(const float* __restrict__ f,
                                       const float* __restrict__ c) {
  float s = 0.f;
#pragma unroll
  for (int c4 = 0; c4 < 16; c4++) {
    float4 fv = *(const float4*)(f + c4 * 4);
    float4 cv = *(const float4*)(c + c4 * 4);
    s += fv.x * cv.x; s += fv.y * cv.y; s += fv.z * cv.z; s += fv.w * cv.w;
  }
  return s;
}

__global__ __launch_bounds__(1024)
void routing_kernel(const float* __restrict__ FE, const int* __restrict__ seqlens,
                    const int* __restrict__ gidx, int* __restrict__ cT,
                    int* __restrict__ cL, int* __restrict__ tC) {
  __shared__ float cent[KMAX_][64];
  __shared__ float csum[KMAX_][64];
  __shared__ int cnt1[KMAX_];
  __shared__ int cnt2[KMAX_];
  __shared__ int starts[KMAX_ + 1];
  __shared__ unsigned char assign[LSCAP_];
  __shared__ unsigned long long keys[LSCAP_];

  const int s = blockIdx.x, tid = threadIdx.x;
  int a = 0;
  for (int t = 0; t < s; t++) a += seqlens[t];
  int Ls = seqlens[s];
  if (Ls > LSCAP_) Ls = LSCAP_;
  for (int cs = tid; cs < KMAX_; cs += 1024) cL[s * KMAX_ + cs] = 0;
  if (Ls <= 0) return;

  int wloc = Ls < WCL_ ? Ls : WCL_;
  if (wloc < 1) wloc = 1;
  int k = (Ls + wloc - 1) / wloc;
  if (k < 1) k = 1;
  if (k > KMAX_) k = KMAX_;

  if (tid < k * 64) {
    int j = tid >> 6, d = tid & 63;
    double step = (k > 1) ? (double)(Ls - 1) / (double)(k - 1) : 0.0;
    long ii = (long)rint(step * (double)j);
    if (ii < 0) ii = 0;
    if (ii > Ls - 1) ii = Ls - 1;
    cent[j][d] = FE[(size_t)(a + ii) * DH_ + d];
  }
  if (tid < KMAX_) cnt1[tid] = 0;
  __syncthreads();

  for (int i = tid; i < Ls; i += 1024) {
    const float* f = FE + (size_t)(a + i) * DH_;
    float best = -1e30f; int bj = 0;
    for (int j = 0; j < k; j++) {
      float sd = dot64(f, &cent[j][0]);
      if (sd > best) { best = sd; bj = j; }
    }
    assign[i] = (unsigned char)bj;
  }
  __syncthreads();
  for (int i = tid; i < Ls; i += 1024) atomicAdd(&cnt1[assign[i]], 1);
  __syncthreads();
  if (tid < 64) {
    int d = tid;
    for (int j = 0; j < k; j++) csum[j][d] = 0.f;
    for (int i = 0; i < Ls; i++)
      csum[assign[i]][d] += FE[(size_t)(a + i) * DH_ + d];
  }
  __syncthreads();
  if (tid < k * 64) {
    int j = tid >> 6, d = tid & 63;
    float v = csum[j][d] / fmaxf((float)cnt1[j], 1.0f);
    float sq = v * v;
#pragma unroll
    for (int m = 1; m < 64; m <<= 1) sq += __shfl_xor(sq, m, 64);
    cent[j][d] = v / (sqrtf(sq) + 1e-6f);
  }
  __syncthreads();

  int NP2 = 1;
  while (NP2 < Ls) NP2 <<= 1;
  for (int i = tid; i < NP2; i += 1024) {
    unsigned long long key;
    if (i < Ls) {
      const float* f = FE + (size_t)(a + i) * DH_;
      float best = -1e30f; int bj = 0;
      for (int j = 0; j < k; j++) {
        float sd = dot64(f, &cent[j][0]);
        if (sd > best) { best = sd; bj = j; }
      }
      assign[i] = (unsigned char)bj;
      unsigned int u = __float_as_uint(best);
      unsigned int ord = (u & 0x80000000u) ? ~u : (u | 0x80000000u);
      unsigned int dsc = ~ord;
      key = ((unsigned long long)bj << 45) |
            ((unsigned long long)dsc << 13) | (unsigned long long)i;
    } else {
      key = ~0ull;
    }
    keys[i] = key;
  }
  if (tid < KMAX_) cnt2[tid] = 0;
  __syncthreads();
  for (int i = tid; i < Ls; i += 1024) atomicAdd(&cnt2[assign[i]], 1);
  __syncthreads();

  for (int len2 = 2; len2 <= NP2; len2 <<= 1) {
    for (int st = len2 >> 1; st > 0; st >>= 1) {
      for (int i = tid; i < NP2; i += 1024) {
        int j = i ^ st;
        if (j > i) {
          unsigned long long x = keys[i], y = keys[j];
          bool asc = ((i & len2) == 0);
          if ((x > y) == asc) { keys[i] = y; keys[j] = x; }
        }
      }
      __syncthreads();
    }
  }
  if (tid == 0) {
    starts[0] = 0;
    for (int j = 0; j < k; j++) starts[j + 1] = starts[j] + cnt2[j];
  }
  __syncthreads();

  const int g = gidx[s];
  int cOut = 0;
  for (int j = 0; j < k; j++) {
    int cj = cnt2[j];
    if (cj <= 0) continue;
    int keep = cj < wloc ? cj : wloc;
    int slot = s * KMAX_ + cOut;
    for (int p = tid; p < keep; p += 1024) {
      int token = a + (int)(keys[starts[j] + p] & 0x1FFFull);
      cT[slot * MAXLEN_ + p] = token;
      atomicAdd(&tC[token], 1);
    }
    if (tid == 0) {
      cT[slot * MAXLEN_ + keep] = g;
      atomicAdd(&tC[g], 1);
      cL[slot] = keep + 1;
    }
    cOut++;
  }
}

// ---------------------------------------------------------------------------
// MFMA flash attention v3: async reg-staged K/V (issue-early, write-late),
// grid = (qchunk, head, cluster) for gather L2/L3 locality, setprio on MFMA.
// Block = 4 waves x 16 q-rows. LDS 49.5 KB -> 3 blocks/CU.
// ---------------------------------------------------------------------------
__global__ __launch_bounds__(256)
void attn_kernel(const unsigned short* __restrict__ Qh, const unsigned short* __restrict__ Ql,
                 const unsigned short* __restrict__ Kh, const unsigned short* __restrict__ Kl,
                 const unsigned short* __restrict__ Vh, const unsigned short* __restrict__ Vl,
                 const int* __restrict__ cT, const int* __restrict__ cL,
                 float* __restrict__ OH) {
  const int qc = blockIdx.x, h = blockIdx.y, c = blockIdx.z;
  const int len = cL[c];
  const int q0 = qc * 64;
  if (len <= 0 || q0 >= len) return;

  __shared__ int toks[MAXLEN_];
  __shared__ __align__(16) unsigned short QP[8192];  // Q hi/lo tile -> P hi/lo
  __shared__ __align__(16) unsigned short KT[8192];  // K hi [0..4095], lo [4096..]
  __shared__ __align__(16) unsigned short VT[8192];  // V^T hi/lo

  const int tid = threadIdx.x, wave = tid >> 6, lane = tid & 63;
  const int lm = lane & 15, lg = lane >> 4;
  const int lr8 = lane >> 3;            // row within 8-row slab (Q glds)
  const int lc8 = (lane & 7) ^ lr8;     // pre-swizzled source chunk (Q glds)

  // K staging map: 4 threads/row, each 2 adjacent 8-ushort chunks per half
  const int krow = tid >> 2;
  const int kc = (tid & 3) * 16;        // ushort offset of 2-chunk segment
  // V staging map: 16 threads/dim-group, 4 keys each
  const int dg = tid & 15, kg = tid >> 4;
  const int vd0 = dg * 4;

  for (int i = tid; i < len; i += 256) toks[i] = cT[c * MAXLEN_ + i];
  __syncthreads();

  // staging registers (issue-early, write-late)
  uint4 ka0, ka1, kb0, kb1;
  u16x4 va0, va1, va2, va3, vb0, vb1, vb2, vb3;

#define KV_LOAD(mt_) do {                                                      \
    int kr_ = (mt_) * 64 + krow;                                               \
    int tk_ = toks[kr_ < len ? kr_ : 0];                                       \
    const unsigned short* kph = Kh + (size_t)tk_ * D_ + h * DH_ + kc;          \
    const unsigned short* kpl = Kl + (size_t)tk_ * D_ + h * DH_ + kc;          \
    ka0 = *(const uint4*)(kph);  ka1 = *(const uint4*)(kph + 8);               \
    kb0 = *(const uint4*)(kpl);  kb1 = *(const uint4*)(kpl + 8);               \
    int vr_ = (mt_) * 64 + kg * 4;                                             \
    int t0_ = toks[vr_ + 0 < len ? vr_ + 0 : 0];                               \
    int t1_ = toks[vr_ + 1 < len ? vr_ + 1 : 0];                               \
    int t2_ = toks[vr_ + 2 < len ? vr_ + 2 : 0];                               \
    int t3_ = toks[vr_ + 3 < len ? vr_ + 3 : 0];                               \
    size_t off_ = (size_t)h * DH_ + vd0;                                       \
    va0 = *(const u16x4*)(Vh + (size_t)t0_ * D_ + off_);                       \
    va1 = *(const u16x4*)(Vh + (size_t)t1_ * D_ + off_);                       \
    va2 = *(const u16x4*)(Vh + (size_t)t2_ * D_ + off_);                       \
    va3 = *(const u16x4*)(Vh + (size_t)t3_ * D_ + off_);                       \
    vb0 = *(const u16x4*)(Vl + (size_t)t0_ * D_ + off_);                       \
    vb1 = *(const u16x4*)(Vl + (size_t)t1_ * D_ + off_);                       \
    vb2 = *(const u16x4*)(Vl + (size_t)t2_ * D_ + off_);                       \
    vb3 = *(const u16x4*)(Vl + (size_t)t3_ * D_ + off_);                       \
  } while (0)

#define KV_WRITE() do {                                                        \
    *(uint4*)&KT[SWZ(krow, kc)] = ka0;                                         \
    *(uint4*)&KT[SWZ(krow, kc + 8)] = ka1;                                     \
    *(uint4*)&KT[4096 + SWZ(krow, kc)] = kb0;                                  \
    *(uint4*)&KT[4096 + SWZ(krow, kc + 8)] = kb1;                              \
    _Pragma("unroll") for (int dd = 0; dd < 4; dd++) {                         \
      *(uint2*)&VT[SWZ(vd0 + dd, kg * 4)] =                                    \
          make_uint2(pk2(va0[dd], va1[dd]), pk2(va2[dd], va3[dd]));            \
      *(uint2*)&VT[4096 + SWZ(vd0 + dd, kg * 4)] =                             \
          make_uint2(pk2(vb0[dd], vb1[dd]), pk2(vb2[dd], vb3[dd]));            \
    }                                                                          \
  } while (0)

  // ---- stage Q tile once (glds, source-swizzled) + prologue K/V loads ----
#pragma unroll
  for (int i = 0; i < 4; i++) {
    int slab = wave * 4 + i;                     // 0..15 (0-7: hi, 8-15: lo)
    int r8 = (slab & 7) * 8;
    int row = q0 + r8 + lr8;
    int tok = toks[row < len ? row : 0];
    const unsigned short* base = (slab < 8) ? Qh : Ql;
    glds16(base + (size_t)tok * D_ + h * DH_ + lc8 * 8,
           &QP[(slab >> 3) * 4096 + r8 * 64]);
  }
  KV_LOAD(0);
  __syncthreads();

  bf16x8 qAh[2], qAl[2];
#pragma unroll
  for (int s = 0; s < 2; s++) {
    qAh[s] = *(const bf16x8*)&QP[SWZ(wave * 16 + lm, s * 32 + lg * 8)];
    qAl[s] = *(const bf16x8*)&QP[4096 + SWZ(wave * 16 + lm, s * 32 + lg * 8)];
  }

  f32x4 accO[4];
#pragma unroll
  for (int t = 0; t < 4; t++) accO[t] = (f32x4){0.f, 0.f, 0.f, 0.f};
  float mm[4] = {-INFINITY, -INFINITY, -INFINITY, -INFINITY};
  float ll[4] = {0.f, 0.f, 0.f, 0.f};

  const int ntile = (len + 63) >> 6;
  for (int mt = 0; mt < ntile; mt++) {
    __syncthreads();  // all waves done reading previous tile
    KV_WRITE();       // compiler waits the in-flight global loads here
    __syncthreads();
    if (mt + 1 < ntile) KV_LOAD(mt + 1);   // hide next gather under compute

    // ---- QK^T: 4 key-tiles x 2 k-slabs x 3 split terms ----
    f32x4 sA[4];
#pragma unroll
    for (int t = 0; t < 4; t++) sA[t] = (f32x4){0.f, 0.f, 0.f, 0.f};
    __builtin_amdgcn_s_setprio(1);
#pragma unroll
    for (int t = 0; t < 4; t++) {
#pragma unroll
      for (int s = 0; s < 2; s++) {
        bf16x8 kb = *(const bf16x8*)&KT[SWZ(t * 16 + lm, s * 32 + lg * 8)];
        bf16x8 kl2 = *(const bf16x8*)&KT[4096 + SWZ(t * 16 + lm, s * 32 + lg * 8)];
        sA[t] = __builtin_amdgcn_mfma_f32_16x16x32_bf16(qAh[s], kb, sA[t], 0, 0, 0);
        sA[t] = __builtin_amdgcn_mfma_f32_16x16x32_bf16(qAl[s], kb, sA[t], 0, 0, 0);
        sA[t] = __builtin_amdgcn_mfma_f32_16x16x32_bf16(qAh[s], kl2, sA[t], 0, 0, 0);
      }
    }
    __builtin_amdgcn_s_setprio(0);

    // ---- mask + online softmax ----
    float sc[4][4];
#pragma unroll
    for (int t = 0; t < 4; t++) {
      bool kvalid = (mt * 64 + t * 16 + lm) < len;
#pragma unroll
      for (int r = 0; r < 4; r++)
        sc[t][r] = kvalid ? sA[t][r] * 0.125f : -1e9f;
    }
    float mx[4], nn[4], cor[4], sum[4];
#pragma unroll
    for (int r = 0; r < 4; r++) {
      mx[r] = fmaxf(fmaxf(sc[0][r], sc[1][r]), fmaxf(sc[2][r], sc[3][r]));
      mx[r] = fmaxf(mx[r], __shfl_xor(mx[r], 1, 64));
      mx[r] = fmaxf(mx[r], __shfl_xor(mx[r], 2, 64));
      mx[r] = fmaxf(mx[r], __shfl_xor(mx[r], 4, 64));
      mx[r] = fmaxf(mx[r], __shfl_xor(mx[r], 8, 64));
      nn[r] = fmaxf(mm[r], mx[r]);
      cor[r] = __expf(mm[r] - nn[r]);
      mm[r] = nn[r];
    }
    float pp[4][4];
#pragma unroll
    for (int t = 0; t < 4; t++)
#pragma unroll
      for (int r = 0; r < 4; r++) pp[t][r] = __expf(sc[t][r] - nn[r]);
#pragma unroll
    for (int r = 0; r < 4; r++) {
      sum[r] = (pp[0][r] + pp[1][r]) + (pp[2][r] + pp[3][r]);
      sum[r] += __shfl_xor(sum[r], 1, 64);
      sum[r] += __shfl_xor(sum[r], 2, 64);
      sum[r] += __shfl_xor(sum[r], 4, 64);
      sum[r] += __shfl_xor(sum[r], 8, 64);
      ll[r] = ll[r] * cor[r] + sum[r];
    }
    // ---- P hi/lo into the (dead-Q) QP buffer, per-wave region ----
#pragma unroll
    for (int t = 0; t < 4; t++) {
#pragma unroll
      for (int r = 0; r < 4; r++) {
        accO[t][r] *= cor[r];
        int row = wave * 16 + lg * 4 + r, col = t * 16 + lm;
        unsigned short hp = bfh(pp[t][r]);
        QP[SWZ(row, col)] = hp;
        QP[4096 + SWZ(row, col)] = bfh(pp[t][r] - bff(hp));
      }
    }

    // ---- PV: 3 split terms ----
    bf16x8 pAh[2], pAl[2];
#pragma unroll
    for (int s = 0; s < 2; s++) {
      pAh[s] = *(const bf16x8*)&QP[SWZ(wave * 16 + lm, s * 32 + lg * 8)];
      pAl[s] = *(const bf16x8*)&QP[4096 + SWZ(wave * 16 + lm, s * 32 + lg * 8)];
    }
    __builtin_amdgcn_s_setprio(1);
#pragma unroll
    for (int t = 0; t < 4; t++) {
#pragma unroll
      for (int s = 0; s < 2; s++) {
        bf16x8 vb = *(const bf16x8*)&VT[SWZ(t * 16 + lm, s * 32 + lg * 8)];
        bf16x8 vl2 = *(const bf16x8*)&VT[4096 + SWZ(t * 16 + lm, s * 32 + lg * 8)];
        accO[t] = __builtin_amdgcn_mfma_f32_16x16x32_bf16(pAh[s], vb, accO[t], 0, 0, 0);
        accO[t] = __builtin_amdgcn_mfma_f32_16x16x32_bf16(pAl[s], vb, accO[t], 0, 0, 0);
        accO[t] = __builtin_amdgcn_mfma_f32_16x16x32_bf16(pAh[s], vl2, accO[t], 0, 0, 0);
      }
    }
    __builtin_amdgcn_s_setprio(0);
  }
#undef KV_LOAD
#undef KV_WRITE

  // ---- epilogue: normalize, scatter-add ----
#pragma unroll
  for (int t = 0; t < 4; t++) {
#pragma unroll
    for (int r = 0; r < 4; r++) {
      int row = q0 + wave * 16 + lg * 4 + r;
      if (row < len)
        atomicAdd(&OH[(size_t)toks[row] * D_ + h * DH_ + t * 16 + lm],
                  accO[t][r] / ll[r]);
    }
  }
}

// ---------------------------------------------------------------------------
// out_h /= clip(cnt,1), then split to bf16 hi/lo for the output GEMM
// ---------------------------------------------------------------------------
__global__ __launch_bounds__(256)
void norm_split(const float* __restrict__ OH, const int* __restrict__ cnt,
                unsigned short* __restrict__ oh, unsigned short* __restrict__ ol) {
  size_t i = (size_t)blockIdx.x * 256 + threadIdx.x;
  size_t n4 = NELEM_ / 4;
  if (i >= n4) return;
  int row = (int)((i * 4) >> 10);
  int cc = cnt[row];
  float s = 1.0f / (float)(cc > 1 ? cc : 1);
  float4 v = ((const float4*)OH)[i];
  v.x *= s; v.y *= s; v.z *= s; v.w *= s;
  unsigned short h0 = bfh(v.x), h1 = bfh(v.y), h2 = bfh(v.z), h3 = bfh(v.w);
  *(uint2*)&oh[i * 4] = make_uint2(pk2(h0, h1), pk2(h2, h3));
  *(uint2*)&ol[i * 4] =
      make_uint2(pk2(bfh(v.x - bff(h0)), bfh(v.y - bff(h1))),
                 pk2(bfh(v.z - bff(h2)), bfh(v.w - bff(h3))));
}

// ---------------------------------------------------------------------------
extern "C" void kernel_launch(void* const* d_in, const int* in_sizes, int n_in,
                              void* d_out, int out_size, void* d_ws, size_t ws_size,
                              hipStream_t stream) {
  (void)in_sizes; (void)n_in; (void)out_size; (void)ws_size;
  const float* q_in = (const float*)d_in[0];
  const float* k_in = (const float*)d_in[1];
  const float* v_in = (const float*)d_in[2];
  const int* seqlens = (const int*)d_in[3];
  const int* gidx    = (const int*)d_in[4];
  const float* Wq = (const float*)d_in[5];
  const float* Wk = (const float*)d_in[6];
  const float* Wv = (const float*)d_in[7];
  const float* Wo = (const float*)d_in[8];
  float* out = (float*)d_out;

  unsigned short* Qh = (unsigned short*)d_ws;
  unsigned short* Ql = Qh + NELEM_;
  unsigned short* Kh = Ql + NELEM_;
  unsigned short* Kl = Kh + NELEM_;
  unsigned short* Vh = Kl + NELEM_;
  unsigned short* Vl = Vh + NELEM_;
  float* OH = (float*)(Vl + NELEM_);
  float* WS = OH + NELEM_;
  float* FE = WS + (1 << 20);
  float* FQ = FE + (size_t)TTOT_ * DH_;
  float* FK = FQ + (size_t)TTOT_ * DH_;
  float* Wqm = FK + (size_t)TTOT_ * DH_;
  float* Wkm = Wqm + 64 * 1024;
  int* cT = (int*)(Wkm + 64 * 1024);
  int* cL = cT + MAXCL_ * MAXLEN_;
  int* tC = cL + MAXCL_;

  unsigned short* SPh = (unsigned short*)OH;   // input splits (dead before OH)
  unsigned short* SPl = SPh + NELEM_;
  unsigned short* WSh = (unsigned short*)WS;
  unsigned short* WSl = WSh + (1 << 20);
  unsigned short* OHh = Qh;                    // OH splits (Q dead after attn)
  unsigned short* OHl = Ql;

  hipMemsetAsync(tC, 0, TTOT_ * sizeof(int), stream);

  // ---- routing features (exact f32 path) ----
  wmean<<<256, 256, 0, stream>>>(Wq, Wqm);
  wmean<<<256, 256, 0, stream>>>(Wk, Wkm);
  gemm_nt<<<dim3(TTOT_ / 64, 1), 256, 0, stream>>>(q_in, Wqm, FQ, TTOT_, 64, 1024);
  gemm_nt<<<dim3(TTOT_ / 64, 1), 256, 0, stream>>>(k_in, Wkm, FK, TTOT_, 64, 1024);
  l2comb<<<TTOT_ / 4, 256, 0, stream>>>(FQ, FK, FE);
  routing_kernel<<<S_, 1024, 0, stream>>>(FE, seqlens, gidx, cT, cL, tC);

  // ---- Q/K/V projections: split-bf16 MFMA GEMMs with split epilogue ----
  const int n4in = (int)(NELEM_ / 4);
  const int n4w = (1024 * 1024) / 4;
  dim3 gg(TTOT_ / 128, D_ / 128);

  conv_split<<<(n4w + 255) / 256, 256, 0, stream>>>(Wq, WSh, WSl, n4w);
  conv_split<<<(n4in + 255) / 256, 256, 0, stream>>>(q_in, SPh, SPl, n4in);
  gemm_bf16s_sp<<<gg, 256, 0, stream>>>(SPh, SPl, WSh, WSl, Qh, Ql, TTOT_, D_, D_);

  conv_split<<<(n4w + 255) / 256, 256, 0, stream>>>(Wk, WSh, WSl, n4w);
  conv_split<<<(n4in + 255) / 256, 256, 0, stream>>>(k_in, SPh, SPl, n4in);
  gemm_bf16s_sp<<<gg, 256, 0, stream>>>(SPh, SPl, WSh, WSl, Kh, Kl, TTOT_, D_, D_);

  conv_split<<<(n4w + 255) / 256, 256, 0, stream>>>(Wv, WSh, WSl, n4w);
  conv_split<<<(n4in + 255) / 256, 256, 0, stream>>>(v_in, SPh, SPl, n4in);
  gemm_bf16s_sp<<<gg, 256, 0, stream>>>(SPh, SPl, WSh, WSl, Vh, Vl, TTOT_, D_, D_);

  // ---- attention (OH aliases the now-dead input-split slab) ----
  hipMemsetAsync(OH, 0, NELEM_ * sizeof(float), stream);
  attn_kernel<<<dim3((MAXLEN_ + 63) / 64, H_, MAXCL_), 256, 0, stream>>>(
      Qh, Ql, Kh, Kl, Vh, Vl, cT, cL, OH);

  // ---- normalize + split (into dead Q slab), output GEMM ----
  norm_split<<<(unsigned)((NELEM_ / 4 + 255) / 256), 256, 0, stream>>>(OH, tC, OHh, OHl);
  conv_split<<<(n4w + 255) / 256, 256, 0, stream>>>(Wo, WSh, WSl, n4w);
  gemm_bf16s<<<gg, 256, 0, stream>>>(OHh, OHl, WSh, WSl, out, TTOT_, D_, D_);
}

// Round 7
// 544.440 us; speedup vs baseline: 6.3345x; 1.1524x over previous
//
#include <hip/hip_runtime.h>
#include <math.h>

#define S_ 4
#define L_ 2048
#define D_ 1024
#define H_ 16
#define DH_ 64
#define TTOT_ 8192
#define WCL_ 384
#define KMAX_ 16
#define MAXCL_ (S_*KMAX_)
#define MAXLEN_ (WCL_+1)   // 385
#define LSCAP_ 4096
#define NELEM_ ((size_t)TTOT_*(size_t)D_)

typedef __attribute__((ext_vector_type(8))) short bf16x8;
typedef __attribute__((ext_vector_type(4))) float f32x4;
typedef __attribute__((ext_vector_type(4))) unsigned short u16x4;

// bf16 split helpers (RNE)
__device__ __forceinline__ unsigned short bfh(float x) {
  unsigned u = __float_as_uint(x);
  return (unsigned short)((u + 0x7FFFu + ((u >> 16) & 1u)) >> 16);
}
__device__ __forceinline__ float bff(unsigned short h) {
  return __uint_as_float(((unsigned)h) << 16);
}
__device__ __forceinline__ unsigned pk2(unsigned short a, unsigned short b) {
  return (unsigned)a | ((unsigned)b << 16);
}
// XOR swizzle on ushort index within [row][64] tiles (16B-chunk granularity)
#define SWZ(r, c) (((r) << 6) + ((c) ^ (((r) & 7) << 3)))

__device__ __forceinline__ void glds16(const void* g, void* l) {
  __builtin_amdgcn_global_load_lds(
      (const __attribute__((address_space(1))) unsigned int*)g,
      (__attribute__((address_space(3))) unsigned int*)l, 16, 0, 0);
}

// ---------------------------------------------------------------------------
// Fused feats GEMM: C[M,64] = A[M,1024] * B[64,1024]^T for (q,k) via grid.y
// ---------------------------------------------------------------------------
__global__ __launch_bounds__(256)
void gemm_feats(const float* __restrict__ Aq, const float* __restrict__ Ak,
                const float* __restrict__ Bq, const float* __restrict__ Bk,
                float* __restrict__ Cq, float* __restrict__ Ck) {
  const float* __restrict__ A = blockIdx.y ? Ak : Aq;
  const float* __restrict__ B = blockIdx.y ? Bk : Bq;
  float* __restrict__ C = blockIdx.y ? Ck : Cq;
  const int Kd = 1024, N = 64;
  __shared__ float As[16][68];
  __shared__ float Bs[16][68];
  const int tx = threadIdx.x & 15, ty = threadIdx.x >> 4;
  const int m0 = blockIdx.x * 64;
  const int lr = threadIdx.x >> 2, lc = threadIdx.x & 3;
  float acc[4][4] = {};
  for (int k0 = 0; k0 < Kd; k0 += 16) {
    __syncthreads();
    float4 a4 = *(const float4*)(A + (size_t)(m0 + lr) * Kd + k0 + lc * 4);
    float4 b4 = *(const float4*)(B + (size_t)lr * Kd + k0 + lc * 4);
    As[lc*4+0][lr] = a4.x; As[lc*4+1][lr] = a4.y; As[lc*4+2][lr] = a4.z; As[lc*4+3][lr] = a4.w;
    Bs[lc*4+0][lr] = b4.x; Bs[lc*4+1][lr] = b4.y; Bs[lc*4+2][lr] = b4.z; Bs[lc*4+3][lr] = b4.w;
    __syncthreads();
#pragma unroll
    for (int kk = 0; kk < 16; kk++) {
      float4 av = *(const float4*)&As[kk][ty * 4];
      float4 bv = *(const float4*)&Bs[kk][tx * 4];
      float aa[4] = {av.x, av.y, av.z, av.w};
      float bb[4] = {bv.x, bv.y, bv.z, bv.w};
#pragma unroll
      for (int i = 0; i < 4; i++)
#pragma unroll
        for (int j = 0; j < 4; j++) acc[i][j] += aa[i] * bb[j];
    }
  }
#pragma unroll
  for (int i = 0; i < 4; i++)
#pragma unroll
    for (int j = 0; j < 4; j++)
      C[(size_t)(m0 + ty * 4 + i) * N + (tx * 4 + j)] = acc[i][j];
}

// ---------------------------------------------------------------------------
// Split-bf16 MFMA GEMM core: 128x128 tile, BK=64, 4 waves, glds staging.
// ---------------------------------------------------------------------------
#define GEMM_BODY                                                              \
  __shared__ __align__(16) unsigned short LA[2][128 * 64];                     \
  __shared__ __align__(16) unsigned short LB[2][128 * 64];                     \
  const int tid = threadIdx.x, wave = tid >> 6, lane = tid & 63;               \
  const int lm = lane & 15, lg = lane >> 4;                                    \
  const int m0 = blockIdx.x * 128, n0 = blockIdx.y * 128;                      \
  const int wr = wave >> 1, wc = wave & 1;                                     \
  const int lrow = lane >> 3;                                                  \
  const int lchk = (lane & 7) ^ lrow;                                          \
  f32x4 acc[4][4];                                                             \
  _Pragma("unroll") for (int i = 0; i < 4; i++)                                \
      _Pragma("unroll") for (int j = 0; j < 4; j++)                            \
          acc[i][j] = (f32x4){0.f, 0.f, 0.f, 0.f};                             \
  for (int k0 = 0; k0 < Kd; k0 += 64) {                                        \
    __syncthreads();                                                           \
    _Pragma("unroll") for (int i = 0; i < 4; i++) {                            \
      const int r = wave * 32 + i * 8;                                         \
      const size_t ga = (size_t)(m0 + r + lrow) * Kd + k0 + lchk * 8;          \
      const size_t gb = (size_t)(n0 + r + lrow) * Kd + k0 + lchk * 8;          \
      glds16(&Ah[ga], &LA[0][r * 64]);                                         \
      glds16(&Al[ga], &LA[1][r * 64]);                                         \
      glds16(&Bh[gb], &LB[0][r * 64]);                                         \
      glds16(&Bl[gb], &LB[1][r * 64]);                                         \
    }                                                                          \
    __syncthreads();                                                           \
    _Pragma("unroll") for (int s = 0; s < 2; s++) {                            \
      bf16x8 ah[4], al[4], bh[4], bl[4];                                       \
      _Pragma("unroll") for (int i = 0; i < 4; i++) {                          \
        const int ra = wr * 64 + i * 16 + lm;                                  \
        const int ca = ((s * 4 + lg) ^ (ra & 7)) * 8;                          \
        ah[i] = *(const bf16x8*)&LA[0][ra * 64 + ca];                          \
        al[i] = *(const bf16x8*)&LA[1][ra * 64 + ca];                          \
        const int rb = wc * 64 + i * 16 + lm;                                  \
        const int cb = ((s * 4 + lg) ^ (rb & 7)) * 8;                          \
        bh[i] = *(const bf16x8*)&LB[0][rb * 64 + cb];                          \
        bl[i] = *(const bf16x8*)&LB[1][rb * 64 + cb];                          \
      }                                                                        \
      _Pragma("unroll") for (int i = 0; i < 4; i++)                            \
          _Pragma("unroll") for (int j = 0; j < 4; j++) {                      \
        acc[i][j] = __builtin_amdgcn_mfma_f32_16x16x32_bf16(ah[i], bh[j], acc[i][j], 0, 0, 0); \
        acc[i][j] = __builtin_amdgcn_mfma_f32_16x16x32_bf16(al[i], bh[j], acc[i][j], 0, 0, 0); \
        acc[i][j] = __builtin_amdgcn_mfma_f32_16x16x32_bf16(ah[i], bl[j], acc[i][j], 0, 0, 0); \
      }                                                                        \
    }                                                                          \
  }

__global__ __launch_bounds__(256)
void gemm_bf16s(const unsigned short* __restrict__ Ah, const unsigned short* __restrict__ Al,
                const unsigned short* __restrict__ Bh, const unsigned short* __restrict__ Bl,
                float* __restrict__ C, int M, int N, int Kd) {
  GEMM_BODY
#pragma unroll
  for (int i = 0; i < 4; i++)
#pragma unroll
    for (int j = 0; j < 4; j++) {
      const int rowb = m0 + wr * 64 + i * 16 + lg * 4;
      const int col = n0 + wc * 64 + j * 16 + lm;
#pragma unroll
      for (int r = 0; r < 4; r++)
        C[(size_t)(rowb + r) * N + col] = acc[i][j][r];
    }
}

__global__ __launch_bounds__(256)
void gemm_bf16s_sp(const unsigned short* __restrict__ Ah, const unsigned short* __restrict__ Al,
                   const unsigned short* __restrict__ Bh, const unsigned short* __restrict__ Bl,
                   unsigned short* __restrict__ Ch, unsigned short* __restrict__ Cl,
                   int M, int N, int Kd) {
  GEMM_BODY
#pragma unroll
  for (int i = 0; i < 4; i++)
#pragma unroll
    for (int j = 0; j < 4; j++) {
      const int rowb = m0 + wr * 64 + i * 16 + lg * 4;
      const int col = n0 + wc * 64 + j * 16 + lm;
#pragma unroll
      for (int r = 0; r < 4; r++) {
        float v = acc[i][j][r];
        unsigned short hh = bfh(v);
        Ch[(size_t)(rowb + r) * N + col] = hh;
        Cl[(size_t)(rowb + r) * N + col] = bfh(v - bff(hh));
      }
    }
}

// ---------------------------------------------------------------------------
// f32 -> (hi,lo) bf16 split, vectorized
// ---------------------------------------------------------------------------
__global__ __launch_bounds__(256)
void conv_split(const float* __restrict__ src, unsigned short* __restrict__ dh,
                unsigned short* __restrict__ dl, int n4) {
  int i = blockIdx.x * 256 + threadIdx.x;
  if (i >= n4) return;
  float4 v = ((const float4*)src)[i];
  unsigned short h0 = bfh(v.x), h1 = bfh(v.y), h2 = bfh(v.z), h3 = bfh(v.w);
  *(uint2*)&dh[(size_t)i * 4] = make_uint2(pk2(h0, h1), pk2(h2, h3));
  *(uint2*)&dl[(size_t)i * 4] =
      make_uint2(pk2(bfh(v.x - bff(h0)), bfh(v.y - bff(h1))),
                 pk2(bfh(v.z - bff(h2)), bfh(v.w - bff(h3))));
}

// ---------------------------------------------------------------------------
// Fused Wm[d][k] = (1/16) sum_h W[h*64+d][k] for both Wq and Wk (grid.y)
// ---------------------------------------------------------------------------
__global__ __launch_bounds__(256)
void wmean2(const float* __restrict__ Wq, const float* __restrict__ Wk,
            float* __restrict__ Wqm, float* __restrict__ Wkm) {
  const float* __restrict__ W = blockIdx.y ? Wk : Wq;
  float* __restrict__ Wm = blockIdx.y ? Wkm : Wqm;
  int i = blockIdx.x * 256 + threadIdx.x;
  if (i >= 64 * 1024) return;
  int d = i >> 10, kk = i & 1023;
  float s = 0.f;
#pragma unroll
  for (int h = 0; h < 16; h++) s += W[(size_t)(h * 64 + d) * 1024 + kk];
  Wm[i] = s * (1.0f / 16.0f);
}

// ---------------------------------------------------------------------------
// FE[t] = 0.5*(l2n(FQ[t]) + l2n(FK[t]))   (one wave per token)
// ---------------------------------------------------------------------------
__global__ __launch_bounds__(256)
void l2comb(const float* __restrict__ FQ, const float* __restrict__ FK,
            float* __restrict__ FE) {
  int t = blockIdx.x * 4 + (threadIdx.x >> 6);
  int lane = threadIdx.x & 63;
  if (t >= TTOT_) return;
  float q = FQ[(size_t)t * 64 + lane], k = FK[(size_t)t * 64 + lane];
  float q2 = q * q, k2 = k * k;
#pragma unroll
  for (int m = 1; m < 64; m <<= 1) {
    q2 += __shfl_xor(q2, m, 64);
    k2 += __shfl_xor(k2, m, 64);
  }
  FE[(size_t)t * 64 + lane] =
      0.5f * (q / (sqrtf(q2) + 1e-6f) + k / (sqrtf(k2) + 1e-6f));
}

// ---------------------------------------------------------------------------
// Routing (exact replica of _route_np). Centroid accumulation parallelized
// per (cluster, dim) with predicated adds — bit-exact vs np.add.at order.
// ---------------------------------------------------------------------------
__device__ __forceinline__ float dot64(const float* __restrict__ f,
                                       const float* __restrict__ c) {
  float s = 0.f;
#pragma unroll
  for (int c4 = 0; c4 < 16; c4++) {
    float4 fv = *(const float4*)(f + c4 * 4);
    float4 cv = *(const float4*)(c + c4 * 4);
    s += fv.x * cv.x; s += fv.y * cv.y; s += fv.z * cv.z; s += fv.w * cv.w;
  }
  return s;
}

__global__ __launch_bounds__(1024)
void routing_kernel(const float* __restrict__ FE, const int* __restrict__ seqlens,
                    const int* __restrict__ gidx, int* __restrict__ cT,
                    int* __restrict__ cL, int* __restrict__ tC) {
  __shared__ float cent[KMAX_][64];
  __shared__ int cnt1[KMAX_];
  __shared__ int cnt2[KMAX_];
  __shared__ int starts[KMAX_ + 1];
  __shared__ unsigned char assign[LSCAP_];
  __shared__ unsigned long long keys[LSCAP_];

  const int s = blockIdx.x, tid = threadIdx.x;
  int a = 0;
  for (int t = 0; t < s; t++) a += seqlens[t];
  int Ls = seqlens[s];
  if (Ls > LSCAP_) Ls = LSCAP_;
  for (int cs = tid; cs < KMAX_; cs += 1024) cL[s * KMAX_ + cs] = 0;
  if (Ls <= 0) return;

  int wloc = Ls < WCL_ ? Ls : WCL_;
  if (wloc < 1) wloc = 1;
  int k = (Ls + wloc - 1) / wloc;
  if (k < 1) k = 1;
  if (k > KMAX_) k = KMAX_;

  if (tid < k * 64) {
    int j = tid >> 6, d = tid & 63;
    double step = (k > 1) ? (double)(Ls - 1) / (double)(k - 1) : 0.0;
    long ii = (long)rint(step * (double)j);
    if (ii < 0) ii = 0;
    if (ii > Ls - 1) ii = Ls - 1;
    cent[j][d] = FE[(size_t)(a + ii) * DH_ + d];
  }
  if (tid < KMAX_) cnt1[tid] = 0;
  __syncthreads();

  for (int i = tid; i < Ls; i += 1024) {
    const float* f = FE + (size_t)(a + i) * DH_;
    float best = -1e30f; int bj = 0;
    for (int j = 0; j < k; j++) {
      float sd = dot64(f, &cent[j][0]);
      if (sd > best) { best = sd; bj = j; }
    }
    assign[i] = (unsigned char)bj;
  }
  __syncthreads();
  for (int i = tid; i < Ls; i += 1024) atomicAdd(&cnt1[assign[i]], 1);
  __syncthreads();
  // exact np.add.at: each (j,d) sums its subsequence in ascending-i order.
  // Predicated add of +0.0 is an exact FP identity here (sums start at +0.0;
  // exact cancellation yields +0.0 in RNE), so this is bit-identical to np.
  float csum_acc = 0.f;
  if (tid < k * 64) {
    int j = tid >> 6, d = tid & 63;
    for (int i = 0; i < Ls; i++) {
      float v = FE[(size_t)(a + i) * DH_ + d];
      csum_acc += (assign[i] == (unsigned char)j) ? v : 0.0f;
    }
  }
  __syncthreads();
  if (tid < k * 64) {
    int j = tid >> 6;
    float v = csum_acc / fmaxf((float)cnt1[j], 1.0f);
    float sq = v * v;
#pragma unroll
    for (int m = 1; m < 64; m <<= 1) sq += __shfl_xor(sq, m, 64);
    cent[j][tid & 63] = v / (sqrtf(sq) + 1e-6f);
  }
  __syncthreads();

  int NP2 = 1;
  while (NP2 < Ls) NP2 <<= 1;
  for (int i = tid; i < NP2; i += 1024) {
    unsigned long long key;
    if (i < Ls) {
      const float* f = FE + (size_t)(a + i) * DH_;
      float best = -1e30f; int bj = 0;
      for (int j = 0; j < k; j++) {
        float sd = dot64(f, &cent[j][0]);
        if (sd > best) { best = sd; bj = j; }
      }
      assign[i] = (unsigned char)bj;
      unsigned int u = __float_as_uint(best);
      unsigned int ord = (u & 0x80000000u) ? ~u : (u | 0x80000000u);
      unsigned int dsc = ~ord;
      key = ((unsigned long long)bj << 45) |
            ((unsigned long long)dsc << 13) | (unsigned long long)i;
    } else {
      key = ~0ull;
    }
    keys[i] = key;
  }
  if (tid < KMAX_) cnt2[tid] = 0;
  __syncthreads();
  for (int i = tid; i < Ls; i += 1024) atomicAdd(&cnt2[assign[i]], 1);
  __syncthreads();

  for (int len2 = 2; len2 <= NP2; len2 <<= 1) {
    for (int st = len2 >> 1; st > 0; st >>= 1) {
      for (int i = tid; i < NP2; i += 1024) {
        int j = i ^ st;
        if (j > i) {
          unsigned long long x = keys[i], y = keys[j];
          bool asc = ((i & len2) == 0);
          if ((x > y) == asc) { keys[i] = y; keys[j] = x; }
        }
      }
      __syncthreads();
    }
  }
  if (tid == 0) {
    starts[0] = 0;
    for (int j = 0; j < k; j++) starts[j + 1] = starts[j] + cnt2[j];
  }
  __syncthreads();

  const int g = gidx[s];
  int cOut = 0;
  for (int j = 0; j < k; j++) {
    int cj = cnt2[j];
    if (cj <= 0) continue;
    int keep = cj < wloc ? cj : wloc;
    int slot = s * KMAX_ + cOut;
    for (int p = tid; p < keep; p += 1024) {
      int token = a + (int)(keys[starts[j] + p] & 0x1FFFull);
      cT[slot * MAXLEN_ + p] = token;
      atomicAdd(&tC[token], 1);
    }
    if (tid == 0) {
      cT[slot * MAXLEN_ + keep] = g;
      atomicAdd(&tC[g], 1);
      cL[slot] = keep + 1;
    }
    cOut++;
  }
}

// ---------------------------------------------------------------------------
// MFMA flash attention v3 (unchanged from R6): async reg-staged K/V,
// grid = (qchunk, head, cluster), setprio on MFMA. 49.5 KB LDS.
// ---------------------------------------------------------------------------
__global__ __launch_bounds__(256)
void attn_kernel(const unsigned short* __restrict__ Qh, const unsigned short* __restrict__ Ql,
                 const unsigned short* __restrict__ Kh, const unsigned short* __restrict__ Kl,
                 const unsigned short* __restrict__ Vh, const unsigned short* __restrict__ Vl,
                 const int* __restrict__ cT, const int* __restrict__ cL,
                 float* __restrict__ OH) {
  const int qc = blockIdx.x, h = blockIdx.y, c = blockIdx.z;
  const int len = cL[c];
  const int q0 = qc * 64;
  if (len <= 0 || q0 >= len) return;

  __shared__ int toks[MAXLEN_];
  __shared__ __align__(16) unsigned short QP[8192];  // Q hi/lo tile -> P hi/lo
  __shared__ __align__(16) unsigned short KT[8192];  // K hi [0..4095], lo [4096..]
  __shared__ __align__(16) unsigned short VT[8192];  // V^T hi/lo

  const int tid = threadIdx.x, wave = tid >> 6, lane = tid & 63;
  const int lm = lane & 15, lg = lane >> 4;
  const int lr8 = lane >> 3;            // row within 8-row slab (Q glds)
  const int lc8 = (lane & 7) ^ lr8;     // pre-swizzled source chunk (Q glds)

  const int krow = tid >> 2;
  const int kc = (tid & 3) * 16;
  const int dg = tid & 15, kg = tid >> 4;
  const int vd0 = dg * 4;

  for (int i = tid; i < len; i += 256) toks[i] = cT[c * MAXLEN_ + i];
  __syncthreads();

  uint4 ka0, ka1, kb0, kb1;
  u16x4 va0, va1, va2, va3, vb0, vb1, vb2, vb3;

#define KV_LOAD(mt_) do {                                                      \
    int kr_ = (mt_) * 64 + krow;                                               \
    int tk_ = toks[kr_ < len ? kr_ : 0];                                       \
    const unsigned short* kph = Kh + (size_t)tk_ * D_ + h * DH_ + kc;          \
    const unsigned short* kpl = Kl + (size_t)tk_ * D_ + h * DH_ + kc;          \
    ka0 = *(const uint4*)(kph);  ka1 = *(const uint4*)(kph + 8);               \
    kb0 = *(const uint4*)(kpl);  kb1 = *(const uint4*)(kpl + 8);               \
    int vr_ = (mt_) * 64 + kg * 4;                                             \
    int t0_ = toks[vr_ + 0 < len ? vr_ + 0 : 0];                               \
    int t1_ = toks[vr_ + 1 < len ? vr_ + 1 : 0];                               \
    int t2_ = toks[vr_ + 2 < len ? vr_ + 2 : 0];                               \
    int t3_ = toks[vr_ + 3 < len ? vr_ + 3 : 0];                               \
    size_t off_ = (size_t)h * DH_ + vd0;                                       \
    va0 = *(const u16x4*)(Vh + (size_t)t0_ * D_ + off_);                       \
    va1 = *(const u16x4*)(Vh + (size_t)t1_ * D_ + off_);                       \
    va2 = *(const u16x4*)(Vh + (size_t)t2_ * D_ + off_);                       \
    va3 = *(const u16x4*)(Vh + (size_t)t3_ * D_ + off_);                       \
    vb0 = *(const u16x4*)(Vl + (size_t)t0_ * D_ + off_);                       \
    vb1 = *(const u16x4*)(Vl + (size_t)t1_ * D_ + off_);                       \
    vb2 = *(const u16x4*)(Vl + (size_t)t2_ * D_ + off_);                       \
    vb3 = *(const u16x4*)(Vl + (size_t)t3_ * D_ + off_);                       \
  } while (0)

#define KV_WRITE() do {                                                        \
    *(uint4*)&KT[SWZ(krow, kc)] = ka0;                                         \
    *(uint4*)&KT[SWZ(krow, kc + 8)] = ka1;                                     \
    *(uint4*)&KT[4096 + SWZ(krow, kc)] = kb0;                                  \
    *(uint4*)&KT[4096 + SWZ(krow, kc + 8)] = kb1;                              \
    _Pragma("unroll") for (int dd = 0; dd < 4; dd++) {                         \
      *(uint2*)&VT[SWZ(vd0 + dd, kg * 4)] =                                    \
          make_uint2(pk2(va0[dd], va1[dd]), pk2(va2[dd], va3[dd]));            \
      *(uint2*)&VT[4096 + SWZ(vd0 + dd, kg * 4)] =                             \
          make_uint2(pk2(vb0[dd], vb1[dd]), pk2(vb2[dd], vb3[dd]));            \
    }                                                                          \
  } while (0)

#pragma unroll
  for (int i = 0; i < 4; i++) {
    int slab = wave * 4 + i;
    int r8 = (slab & 7) * 8;
    int row = q0 + r8 + lr8;
    int tok = toks[row < len ? row : 0];
    const unsigned short* base = (slab < 8) ? Qh : Ql;
    glds16(base + (size_t)tok * D_ + h * DH_ + lc8 * 8,
           &QP[(slab >> 3) * 4096 + r8 * 64]);
  }
  KV_LOAD(0);
  __syncthreads();

  bf16x8 qAh[2], qAl[2];
#pragma unroll
  for (int s = 0; s < 2; s++) {
    qAh[s] = *(const bf16x8*)&QP[SWZ(wave * 16 + lm, s * 32 + lg * 8)];
    qAl[s] = *(const bf16x8*)&QP[4096 + SWZ(wave * 16 + lm, s * 32 + lg * 8)];
  }

  f32x4 accO[4];
#pragma unroll
  for (int t = 0; t < 4; t++) accO[t] = (f32x4){0.f, 0.f, 0.f, 0.f};
  float mm[4] = {-INFINITY, -INFINITY, -INFINITY, -INFINITY};
  float ll[4] = {0.f, 0.f, 0.f, 0.f};

  const int ntile = (len + 63) >> 6;
  for (int mt = 0; mt < ntile; mt++) {
    __syncthreads();
    KV_WRITE();
    __syncthreads();
    if (mt + 1 < ntile) KV_LOAD(mt + 1);

    f32x4 sA[4];
#pragma unroll
    for (int t = 0; t < 4; t++) sA[t] = (f32x4){0.f, 0.f, 0.f, 0.f};
    __builtin_amdgcn_s_setprio(1);
#pragma unroll
    for (int t = 0; t < 4; t++) {
#pragma unroll
      for (int s = 0; s < 2; s++) {
        bf16x8 kb = *(const bf16x8*)&KT[SWZ(t * 16 + lm, s * 32 + lg * 8)];
        bf16x8 kl2 = *(const bf16x8*)&KT[4096 + SWZ(t * 16 + lm, s * 32 + lg * 8)];
        sA[t] = __builtin_amdgcn_mfma_f32_16x16x32_bf16(qAh[s], kb, sA[t], 0, 0, 0);
        sA[t] = __builtin_amdgcn_mfma_f32_16x16x32_bf16(qAl[s], kb, sA[t], 0, 0, 0);
        sA[t] = __builtin_amdgcn_mfma_f32_16x16x32_bf16(qAh[s], kl2, sA[t], 0, 0, 0);
      }
    }
    __builtin_amdgcn_s_setprio(0);

    float sc[4][4];
#pragma unroll
    for (int t = 0; t < 4; t++) {
      bool kvalid = (mt * 64 + t * 16 + lm) < len;
#pragma unroll
      for (int r = 0; r < 4; r++)
        sc[t][r] = kvalid ? sA[t][r] * 0.125f : -1e9f;
    }
    float mx[4], nn[4], cor[4], sum[4];
#pragma unroll
    for (int r = 0; r < 4; r++) {
      mx[r] = fmaxf(fmaxf(sc[0][r], sc[1][r]), fmaxf(sc[2][r], sc[3][r]));
      mx[r] = fmaxf(mx[r], __shfl_xor(mx[r], 1, 64));
      mx[r] = fmaxf(mx[r], __shfl_xor(mx[r], 2, 64));
      mx[r] = fmaxf(mx[r], __shfl_xor(mx[r], 4, 64));
      mx[r] = fmaxf(mx[r], __shfl_xor(mx[r], 8, 64));
      nn[r] = fmaxf(mm[r], mx[r]);
      cor[r] = __expf(mm[r] - nn[r]);
      mm[r] = nn[r];
    }
    float pp[4][4];
#pragma unroll
    for (int t = 0; t < 4; t++)
#pragma unroll
      for (int r = 0; r < 4; r++) pp[t][r] = __expf(sc[t][r] - nn[r]);
#pragma unroll
    for (int r = 0; r < 4; r++) {
      sum[r] = (pp[0][r] + pp[1][r]) + (pp[2][r] + pp[3][r]);
      sum[r] += __shfl_xor(sum[r], 1, 64);
      sum[r] += __shfl_xor(sum[r], 2, 64);
      sum[r] += __shfl_xor(sum[r], 4, 64);
      sum[r] += __shfl_xor(sum[r], 8, 64);
      ll[r] = ll[r] * cor[r] + sum[r];
    }
#pragma unroll
    for (int t = 0; t < 4; t++) {
#pragma unroll
      for (int r = 0; r < 4; r++) {
        accO[t][r] *= cor[r];
        int row = wave * 16 + lg * 4 + r, col = t * 16 + lm;
        unsigned short hp = bfh(pp[t][r]);
        QP[SWZ(row, col)] = hp;
        QP[4096 + SWZ(row, col)] = bfh(pp[t][r] - bff(hp));
      }
    }

    bf16x8 pAh[2], pAl[2];
#pragma unroll
    for (int s = 0; s < 2; s++) {
      pAh[s] = *(const bf16x8*)&QP[SWZ(wave * 16 + lm, s * 32 + lg * 8)];
      pAl[s] = *(const bf16x8*)&QP[4096 + SWZ(wave * 16 + lm, s * 32 + lg * 8)];
    }
    __builtin_amdgcn_s_setprio(1);
#pragma unroll
    for (int t = 0; t < 4; t++) {
#pragma unroll
      for (int s = 0; s < 2; s++) {
        bf16x8 vb = *(const bf16x8*)&VT[SWZ(t * 16 + lm, s * 32 + lg * 8)];
        bf16x8 vl2 = *(const bf16x8*)&VT[4096 + SWZ(t * 16 + lm, s * 32 + lg * 8)];
        accO[t] = __builtin_amdgcn_mfma_f32_16x16x32_bf16(pAh[s], vb, accO[t], 0, 0, 0);
        accO[t] = __builtin_amdgcn_mfma_f32_16x16x32_bf16(pAl[s], vb, accO[t], 0, 0, 0);
        accO[t] = __builtin_amdgcn_mfma_f32_16x16x32_bf16(pAh[s], vl2, accO[t], 0, 0, 0);
      }
    }
    __builtin_amdgcn_s_setprio(0);
  }
#undef KV_LOAD
#undef KV_WRITE

#pragma unroll
  for (int t = 0; t < 4; t++) {
#pragma unroll
    for (int r = 0; r < 4; r++) {
      int row = q0 + wave * 16 + lg * 4 + r;
      if (row < len)
        atomicAdd(&OH[(size_t)toks[row] * D_ + h * DH_ + t * 16 + lm],
                  accO[t][r] / ll[r]);
    }
  }
}

// ---------------------------------------------------------------------------
// out_h /= clip(cnt,1), then split to bf16 hi/lo for the output GEMM
// ---------------------------------------------------------------------------
__global__ __launch_bounds__(256)
void norm_split(const float* __restrict__ OH, const int* __restrict__ cnt,
                unsigned short* __restrict__ oh, unsigned short* __restrict__ ol) {
  size_t i = (size_t)blockIdx.x * 256 + threadIdx.x;
  size_t n4 = NELEM_ / 4;
  if (i >= n4) return;
  int row = (int)((i * 4) >> 10);
  int cc = cnt[row];
  float s = 1.0f / (float)(cc > 1 ? cc : 1);
  float4 v = ((const float4*)OH)[i];
  v.x *= s; v.y *= s; v.z *= s; v.w *= s;
  unsigned short h0 = bfh(v.x), h1 = bfh(v.y), h2 = bfh(v.z), h3 = bfh(v.w);
  *(uint2*)&oh[i * 4] = make_uint2(pk2(h0, h1), pk2(h2, h3));
  *(uint2*)&ol[i * 4] =
      make_uint2(pk2(bfh(v.x - bff(h0)), bfh(v.y - bff(h1))),
                 pk2(bfh(v.z - bff(h2)), bfh(v.w - bff(h3))));
}

// ---------------------------------------------------------------------------
extern "C" void kernel_launch(void* const* d_in, const int* in_sizes, int n_in,
                              void* d_out, int out_size, void* d_ws, size_t ws_size,
                              hipStream_t stream) {
  (void)in_sizes; (void)n_in; (void)out_size; (void)ws_size;
  const float* q_in = (const float*)d_in[0];
  const float* k_in = (const float*)d_in[1];
  const float* v_in = (const float*)d_in[2];
  const int* seqlens = (const int*)d_in[3];
  const int* gidx    = (const int*)d_in[4];
  const float* Wq = (const float*)d_in[5];
  const float* Wk = (const float*)d_in[6];
  const float* Wv = (const float*)d_in[7];
  const float* Wo = (const float*)d_in[8];
  float* out = (float*)d_out;

  unsigned short* Qh = (unsigned short*)d_ws;
  unsigned short* Ql = Qh + NELEM_;
  unsigned short* Kh = Ql + NELEM_;
  unsigned short* Kl = Kh + NELEM_;
  unsigned short* Vh = Kl + NELEM_;
  unsigned short* Vl = Vh + NELEM_;
  float* OH = (float*)(Vl + NELEM_);
  float* WS = OH + NELEM_;
  float* FE = WS + (1 << 20);
  float* FQ = FE + (size_t)TTOT_ * DH_;
  float* FK = FQ + (size_t)TTOT_ * DH_;
  float* Wqm = FK + (size_t)TTOT_ * DH_;
  float* Wkm = Wqm + 64 * 1024;
  int* cT = (int*)(Wkm + 64 * 1024);
  int* cL = cT + MAXCL_ * MAXLEN_;
  int* tC = cL + MAXCL_;

  unsigned short* SPh = (unsigned short*)OH;   // input splits (dead before OH)
  unsigned short* SPl = SPh + NELEM_;
  unsigned short* WSh = (unsigned short*)WS;
  unsigned short* WSl = WSh + (1 << 20);
  unsigned short* OHh = Qh;                    // OH splits (Q dead after attn)
  unsigned short* OHl = Ql;

  hipMemsetAsync(tC, 0, TTOT_ * sizeof(int), stream);

  // ---- routing features (exact f32 path) ----
  wmean2<<<dim3(256, 2), 256, 0, stream>>>(Wq, Wk, Wqm, Wkm);
  gemm_feats<<<dim3(TTOT_ / 64, 2), 256, 0, stream>>>(q_in, k_in, Wqm, Wkm, FQ, FK);
  l2comb<<<TTOT_ / 4, 256, 0, stream>>>(FQ, FK, FE);
  routing_kernel<<<S_, 1024, 0, stream>>>(FE, seqlens, gidx, cT, cL, tC);

  // ---- Q/K/V projections: split-bf16 MFMA GEMMs with split epilogue ----
  const int n4in = (int)(NELEM_ / 4);
  const int n4w = (1024 * 1024) / 4;
  dim3 gg(TTOT_ / 128, D_ / 128);

  conv_split<<<(n4w + 255) / 256, 256, 0, stream>>>(Wq, WSh, WSl, n4w);
  conv_split<<<(n4in + 255) / 256, 256, 0, stream>>>(q_in, SPh, SPl, n4in);
  gemm_bf16s_sp<<<gg, 256, 0, stream>>>(SPh, SPl, WSh, WSl, Qh, Ql, TTOT_, D_, D_);

  conv_split<<<(n4w + 255) / 256, 256, 0, stream>>>(Wk, WSh, WSl, n4w);
  conv_split<<<(n4in + 255) / 256, 256, 0, stream>>>(k_in, SPh, SPl, n4in);
  gemm_bf16s_sp<<<gg, 256, 0, stream>>>(SPh, SPl, WSh, WSl, Kh, Kl, TTOT_, D_, D_);

  conv_split<<<(n4w + 255) / 256, 256, 0, stream>>>(Wv, WSh, WSl, n4w);
  conv_split<<<(n4in + 255) / 256, 256, 0, stream>>>(v_in, SPh, SPl, n4in);
  gemm_bf16s_sp<<<gg, 256, 0, stream>>>(SPh, SPl, WSh, WSl, Vh, Vl, TTOT_, D_, D_);

  // ---- attention (OH aliases the now-dead input-split slab) ----
  hipMemsetAsync(OH, 0, NELEM_ * sizeof(float), stream);
  attn_kernel<<<dim3((MAXLEN_ + 63) / 64, H_, MAXCL_), 256, 0, stream>>>(
      Qh, Ql, Kh, Kl, Vh, Vl, cT, cL, OH);

  // ---- normalize + split (into dead Q slab), output GEMM ----
  norm_split<<<(unsigned)((NELEM_ / 4 + 255) / 256), 256, 0, stream>>>(OH, tC, OHh, OHl);
  conv_split<<<(n4w + 255) / 256, 256, 0, stream>>>(Wo, WSh, WSl, n4w);
  gemm_bf16s<<<gg, 256, 0, stream>>>(OHh, OHl, WSh, WSl, out, TTOT_, D_, D_);
}

// Round 8
// 532.440 us; speedup vs baseline: 6.4773x; 1.0225x over previous
//
#include <hip/hip_runtime.h>
#include <math.h>

#define S_ 4
#define L_ 2048
#define D_ 1024
#define H_ 16
#define DH_ 64
#define TTOT_ 8192
#define WCL_ 384
#define KMAX_ 16
#define MAXCL_ (S_*KMAX_)
#define MAXLEN_ (WCL_+1)   // 385
#define LSCAP_ 4096
#define NELEM_ ((size_t)TTOT_*(size_t)D_)

typedef __attribute__((ext_vector_type(8))) short bf16x8;
typedef __attribute__((ext_vector_type(4))) float f32x4;
typedef __attribute__((ext_vector_type(4))) unsigned short u16x4;

// bf16 split helpers (RNE)
__device__ __forceinline__ unsigned short bfh(float x) {
  unsigned u = __float_as_uint(x);
  return (unsigned short)((u + 0x7FFFu + ((u >> 16) & 1u)) >> 16);
}
__device__ __forceinline__ float bff(unsigned short h) {
  return __uint_as_float(((unsigned)h) << 16);
}
__device__ __forceinline__ unsigned pk2(unsigned short a, unsigned short b) {
  return (unsigned)a | ((unsigned)b << 16);
}
// XOR swizzle on ushort index within [row][64] tiles (16B-chunk granularity)
#define SWZ(r, c) (((r) << 6) + ((c) ^ (((r) & 7) << 3)))

__device__ __forceinline__ void glds16(const void* g, void* l) {
  __builtin_amdgcn_global_load_lds(
      (const __attribute__((address_space(1))) unsigned int*)g,
      (__attribute__((address_space(3))) unsigned int*)l, 16, 0, 0);
}

// ---------------------------------------------------------------------------
// Fused feats GEMM: C[M,64] = A[M,1024] * B[64,1024]^T for (q,k) via grid.y
// ---------------------------------------------------------------------------
__global__ __launch_bounds__(256)
void gemm_feats(const float* __restrict__ Aq, const float* __restrict__ Ak,
                const float* __restrict__ Bq, const float* __restrict__ Bk,
                float* __restrict__ Cq, float* __restrict__ Ck) {
  const float* __restrict__ A = blockIdx.y ? Ak : Aq;
  const float* __restrict__ B = blockIdx.y ? Bk : Bq;
  float* __restrict__ C = blockIdx.y ? Ck : Cq;
  const int Kd = 1024, N = 64;
  __shared__ float As[16][68];
  __shared__ float Bs[16][68];
  const int tx = threadIdx.x & 15, ty = threadIdx.x >> 4;
  const int m0 = blockIdx.x * 64;
  const int lr = threadIdx.x >> 2, lc = threadIdx.x & 3;
  float acc[4][4] = {};
  for (int k0 = 0; k0 < Kd; k0 += 16) {
    __syncthreads();
    float4 a4 = *(const float4*)(A + (size_t)(m0 + lr) * Kd + k0 + lc * 4);
    float4 b4 = *(const float4*)(B + (size_t)lr * Kd + k0 + lc * 4);
    As[lc*4+0][lr] = a4.x; As[lc*4+1][lr] = a4.y; As[lc*4+2][lr] = a4.z; As[lc*4+3][lr] = a4.w;
    Bs[lc*4+0][lr] = b4.x; Bs[lc*4+1][lr] = b4.y; Bs[lc*4+2][lr] = b4.z; Bs[lc*4+3][lr] = b4.w;
    __syncthreads();
#pragma unroll
    for (int kk = 0; kk < 16; kk++) {
      float4 av = *(const float4*)&As[kk][ty * 4];
      float4 bv = *(const float4*)&Bs[kk][tx * 4];
      float aa[4] = {av.x, av.y, av.z, av.w};
      float bb[4] = {bv.x, bv.y, bv.z, bv.w};
#pragma unroll
      for (int i = 0; i < 4; i++)
#pragma unroll
        for (int j = 0; j < 4; j++) acc[i][j] += aa[i] * bb[j];
    }
  }
#pragma unroll
  for (int i = 0; i < 4; i++)
#pragma unroll
    for (int j = 0; j < 4; j++)
      C[(size_t)(m0 + ty * 4 + i) * N + (tx * 4 + j)] = acc[i][j];
}

// ---------------------------------------------------------------------------
// Split-bf16 MFMA GEMM core: 128x128 tile, BK=64, 4 waves, glds staging.
// ---------------------------------------------------------------------------
#define GEMM_BODY                                                              \
  __shared__ __align__(16) unsigned short LA[2][128 * 64];                     \
  __shared__ __align__(16) unsigned short LB[2][128 * 64];                     \
  const int tid = threadIdx.x, wave = tid >> 6, lane = tid & 63;               \
  const int lm = lane & 15, lg = lane >> 4;                                    \
  const int m0 = blockIdx.x * 128, n0 = blockIdx.y * 128;                      \
  const int wr = wave >> 1, wc = wave & 1;                                     \
  const int lrow = lane >> 3;                                                  \
  const int lchk = (lane & 7) ^ lrow;                                          \
  f32x4 acc[4][4];                                                             \
  _Pragma("unroll") for (int i = 0; i < 4; i++)                                \
      _Pragma("unroll") for (int j = 0; j < 4; j++)                            \
          acc[i][j] = (f32x4){0.f, 0.f, 0.f, 0.f};                             \
  for (int k0 = 0; k0 < Kd; k0 += 64) {                                        \
    __syncthreads();                                                           \
    _Pragma("unroll") for (int i = 0; i < 4; i++) {                            \
      const int r = wave * 32 + i * 8;                                         \
      const size_t ga = (size_t)(m0 + r + lrow) * Kd + k0 + lchk * 8;          \
      const size_t gb = (size_t)(n0 + r + lrow) * Kd + k0 + lchk * 8;          \
      glds16(&Ah[ga], &LA[0][r * 64]);                                         \
      glds16(&Al[ga], &LA[1][r * 64]);                                         \
      glds16(&Bh[gb], &LB[0][r * 64]);                                         \
      glds16(&Bl[gb], &LB[1][r * 64]);                                         \
    }                                                                          \
    __syncthreads();                                                           \
    _Pragma("unroll") for (int s = 0; s < 2; s++) {                            \
      bf16x8 ah[4], al[4], bh[4], bl[4];                                       \
      _Pragma("unroll") for (int i = 0; i < 4; i++) {                          \
        const int ra = wr * 64 + i * 16 + lm;                                  \
        const int ca = ((s * 4 + lg) ^ (ra & 7)) * 8;                          \
        ah[i] = *(const bf16x8*)&LA[0][ra * 64 + ca];                          \
        al[i] = *(const bf16x8*)&LA[1][ra * 64 + ca];                          \
        const int rb = wc * 64 + i * 16 + lm;                                  \
        const int cb = ((s * 4 + lg) ^ (rb & 7)) * 8;                          \
        bh[i] = *(const bf16x8*)&LB[0][rb * 64 + cb];                          \
        bl[i] = *(const bf16x8*)&LB[1][rb * 64 + cb];                          \
      }                                                                        \
      _Pragma("unroll") for (int i = 0; i < 4; i++)                            \
          _Pragma("unroll") for (int j = 0; j < 4; j++) {                      \
        acc[i][j] = __builtin_amdgcn_mfma_f32_16x16x32_bf16(ah[i], bh[j], acc[i][j], 0, 0, 0); \
        acc[i][j] = __builtin_amdgcn_mfma_f32_16x16x32_bf16(al[i], bh[j], acc[i][j], 0, 0, 0); \
        acc[i][j] = __builtin_amdgcn_mfma_f32_16x16x32_bf16(ah[i], bl[j], acc[i][j], 0, 0, 0); \
      }                                                                        \
    }                                                                          \
  }

__global__ __launch_bounds__(256)
void gemm_bf16s(const unsigned short* __restrict__ Ah, const unsigned short* __restrict__ Al,
                const unsigned short* __restrict__ Bh, const unsigned short* __restrict__ Bl,
                float* __restrict__ C, int M, int N, int Kd) {
  GEMM_BODY
#pragma unroll
  for (int i = 0; i < 4; i++)
#pragma unroll
    for (int j = 0; j < 4; j++) {
      const int rowb = m0 + wr * 64 + i * 16 + lg * 4;
      const int col = n0 + wc * 64 + j * 16 + lm;
#pragma unroll
      for (int r = 0; r < 4; r++)
        C[(size_t)(rowb + r) * N + col] = acc[i][j][r];
    }
}

__global__ __launch_bounds__(256)
void gemm_bf16s_sp(const unsigned short* __restrict__ Ah, const unsigned short* __restrict__ Al,
                   const unsigned short* __restrict__ Bh, const unsigned short* __restrict__ Bl,
                   unsigned short* __restrict__ Ch, unsigned short* __restrict__ Cl,
                   int M, int N, int Kd) {
  GEMM_BODY
#pragma unroll
  for (int i = 0; i < 4; i++)
#pragma unroll
    for (int j = 0; j < 4; j++) {
      const int rowb = m0 + wr * 64 + i * 16 + lg * 4;
      const int col = n0 + wc * 64 + j * 16 + lm;
#pragma unroll
      for (int r = 0; r < 4; r++) {
        float v = acc[i][j][r];
        unsigned short hh = bfh(v);
        Ch[(size_t)(rowb + r) * N + col] = hh;
        Cl[(size_t)(rowb + r) * N + col] = bfh(v - bff(hh));
      }
    }
}

// ---------------------------------------------------------------------------
// f32 -> (hi,lo) bf16 split, vectorized
// ---------------------------------------------------------------------------
__global__ __launch_bounds__(256)
void conv_split(const float* __restrict__ src, unsigned short* __restrict__ dh,
                unsigned short* __restrict__ dl, int n4) {
  int i = blockIdx.x * 256 + threadIdx.x;
  if (i >= n4) return;
  float4 v = ((const float4*)src)[i];
  unsigned short h0 = bfh(v.x), h1 = bfh(v.y), h2 = bfh(v.z), h3 = bfh(v.w);
  *(uint2*)&dh[(size_t)i * 4] = make_uint2(pk2(h0, h1), pk2(h2, h3));
  *(uint2*)&dl[(size_t)i * 4] =
      make_uint2(pk2(bfh(v.x - bff(h0)), bfh(v.y - bff(h1))),
                 pk2(bfh(v.z - bff(h2)), bfh(v.w - bff(h3))));
}

// ---------------------------------------------------------------------------
// Fused Wm[d][k] = (1/16) sum_h W[h*64+d][k] for both Wq and Wk (grid.y)
// ---------------------------------------------------------------------------
__global__ __launch_bounds__(256)
void wmean2(const float* __restrict__ Wq, const float* __restrict__ Wk,
            float* __restrict__ Wqm, float* __restrict__ Wkm) {
  const float* __restrict__ W = blockIdx.y ? Wk : Wq;
  float* __restrict__ Wm = blockIdx.y ? Wkm : Wqm;
  int i = blockIdx.x * 256 + threadIdx.x;
  if (i >= 64 * 1024) return;
  int d = i >> 10, kk = i & 1023;
  float s = 0.f;
#pragma unroll
  for (int h = 0; h < 16; h++) s += W[(size_t)(h * 64 + d) * 1024 + kk];
  Wm[i] = s * (1.0f / 16.0f);
}

// ---------------------------------------------------------------------------
// FE[t] = 0.5*(l2n(FQ[t]) + l2n(FK[t]))   (one wave per token)
// ---------------------------------------------------------------------------
__global__ __launch_bounds__(256)
void l2comb(const float* __restrict__ FQ, const float* __restrict__ FK,
            float* __restrict__ FE) {
  int t = blockIdx.x * 4 + (threadIdx.x >> 6);
  int lane = threadIdx.x & 63;
  if (t >= TTOT_) return;
  float q = FQ[(size_t)t * 64 + lane], k = FK[(size_t)t * 64 + lane];
  float q2 = q * q, k2 = k * k;
#pragma unroll
  for (int m = 1; m < 64; m <<= 1) {
    q2 += __shfl_xor(q2, m, 64);
    k2 += __shfl_xor(k2, m, 64);
  }
  FE[(size_t)t * 64 + lane] =
      0.5f * (q / (sqrtf(q2) + 1e-6f) + k / (sqrtf(k2) + 1e-6f));
}

// ---------------------------------------------------------------------------
// Routing (replica of _route_np; same decision stream). Assignment dots use
// register-hoisted features (same FP add order); centroid accumulation is
// LDS-chunk staged, ascending-i order per (cluster,dim) — bit-identical to
// np.add.at.
// ---------------------------------------------------------------------------
__global__ __launch_bounds__(1024)
void routing_kernel(const float* __restrict__ FE, const int* __restrict__ seqlens,
                    const int* __restrict__ gidx, int* __restrict__ cT,
                    int* __restrict__ cL, int* __restrict__ tC) {
  __shared__ float cent[KMAX_][64];
  __shared__ float chunk[128][64];
  __shared__ int cnt1[KMAX_];
  __shared__ int cnt2[KMAX_];
  __shared__ int starts[KMAX_ + 1];
  __shared__ unsigned char assign[LSCAP_];
  __shared__ unsigned long long keys[LSCAP_];

  const int s = blockIdx.x, tid = threadIdx.x;
  int a = 0;
  for (int t = 0; t < s; t++) a += seqlens[t];
  int Ls = seqlens[s];
  if (Ls > LSCAP_) Ls = LSCAP_;
  for (int cs = tid; cs < KMAX_; cs += 1024) cL[s * KMAX_ + cs] = 0;
  if (Ls <= 0) return;

  int wloc = Ls < WCL_ ? Ls : WCL_;
  if (wloc < 1) wloc = 1;
  int k = (Ls + wloc - 1) / wloc;
  if (k < 1) k = 1;
  if (k > KMAX_) k = KMAX_;

  if (tid < k * 64) {
    int j = tid >> 6, d = tid & 63;
    double step = (k > 1) ? (double)(Ls - 1) / (double)(k - 1) : 0.0;
    long ii = (long)rint(step * (double)j);
    if (ii < 0) ii = 0;
    if (ii > Ls - 1) ii = Ls - 1;
    cent[j][d] = FE[(size_t)(a + ii) * DH_ + d];
  }
  if (tid < KMAX_) cnt1[tid] = 0;
  __syncthreads();

  // ---- assignment pass 1 (hoisted f, same add order as dot64) ----
  for (int i = tid; i < Ls; i += 1024) {
    const float4* f4 = (const float4*)(FE + (size_t)(a + i) * DH_);
    float4 fr[16];
#pragma unroll
    for (int c4 = 0; c4 < 16; c4++) fr[c4] = f4[c4];
    float best = -1e30f; int bj = 0;
    for (int j = 0; j < k; j++) {
      float sd = 0.f;
#pragma unroll
      for (int c4 = 0; c4 < 16; c4++) {
        float4 cv = *(const float4*)&cent[j][c4 * 4];
        sd += fr[c4].x * cv.x; sd += fr[c4].y * cv.y;
        sd += fr[c4].z * cv.z; sd += fr[c4].w * cv.w;
      }
      if (sd > best) { best = sd; bj = j; }
    }
    assign[i] = (unsigned char)bj;
  }
  __syncthreads();
  for (int i = tid; i < Ls; i += 1024) atomicAdd(&cnt1[assign[i]], 1);
  __syncthreads();

  // ---- exact np.add.at centroid accumulation, LDS-chunk staged ----
  float csum_acc = 0.f;
  const int jj = tid >> 6, dd = tid & 63;
  for (int base = 0; base < Ls; base += 128) {
    int nrows = Ls - base; if (nrows > 128) nrows = 128;
    __syncthreads();
    for (int e = tid; e < nrows * 16; e += 1024) {
      int rr = e >> 4, cc = e & 15;
      *(float4*)&chunk[rr][cc * 4] =
          *(const float4*)(FE + (size_t)(a + base + rr) * DH_ + cc * 4);
    }
    __syncthreads();
    if (jj < k) {
      for (int i = 0; i < nrows; i++) {
        float v = chunk[i][dd];
        csum_acc += (assign[base + i] == (unsigned char)jj) ? v : 0.0f;
      }
    }
  }
  __syncthreads();
  if (tid < k * 64) {
    float v = csum_acc / fmaxf((float)cnt1[jj], 1.0f);
    float sq = v * v;
#pragma unroll
    for (int m = 1; m < 64; m <<= 1) sq += __shfl_xor(sq, m, 64);
    cent[jj][dd] = v / (sqrtf(sq) + 1e-6f);
  }
  __syncthreads();

  // ---- assignment pass 2 + sort keys (hoisted f) ----
  int NP2 = 1;
  while (NP2 < Ls) NP2 <<= 1;
  for (int i = tid; i < NP2; i += 1024) {
    unsigned long long key;
    if (i < Ls) {
      const float4* f4 = (const float4*)(FE + (size_t)(a + i) * DH_);
      float4 fr[16];
#pragma unroll
      for (int c4 = 0; c4 < 16; c4++) fr[c4] = f4[c4];
      float best = -1e30f; int bj = 0;
      for (int j = 0; j < k; j++) {
        float sd = 0.f;
#pragma unroll
        for (int c4 = 0; c4 < 16; c4++) {
          float4 cv = *(const float4*)&cent[j][c4 * 4];
          sd += fr[c4].x * cv.x; sd += fr[c4].y * cv.y;
          sd += fr[c4].z * cv.z; sd += fr[c4].w * cv.w;
        }
        if (sd > best) { best = sd; bj = j; }
      }
      assign[i] = (unsigned char)bj;
      unsigned int u = __float_as_uint(best);
      unsigned int ord = (u & 0x80000000u) ? ~u : (u | 0x80000000u);
      unsigned int dsc = ~ord;
      key = ((unsigned long long)bj << 45) |
            ((unsigned long long)dsc << 13) | (unsigned long long)i;
    } else {
      key = ~0ull;
    }
    keys[i] = key;
  }
  if (tid < KMAX_) cnt2[tid] = 0;
  __syncthreads();
  for (int i = tid; i < Ls; i += 1024) atomicAdd(&cnt2[assign[i]], 1);
  __syncthreads();

  for (int len2 = 2; len2 <= NP2; len2 <<= 1) {
    for (int st = len2 >> 1; st > 0; st >>= 1) {
      for (int i = tid; i < NP2; i += 1024) {
        int j = i ^ st;
        if (j > i) {
          unsigned long long x = keys[i], y = keys[j];
          bool asc = ((i & len2) == 0);
          if ((x > y) == asc) { keys[i] = y; keys[j] = x; }
        }
      }
      __syncthreads();
    }
  }
  if (tid == 0) {
    starts[0] = 0;
    for (int j = 0; j < k; j++) starts[j + 1] = starts[j] + cnt2[j];
  }
  __syncthreads();

  const int g = gidx[s];
  int cOut = 0;
  for (int j = 0; j < k; j++) {
    int cj = cnt2[j];
    if (cj <= 0) continue;
    int keep = cj < wloc ? cj : wloc;
    int slot = s * KMAX_ + cOut;
    for (int p = tid; p < keep; p += 1024) {
      int token = a + (int)(keys[starts[j] + p] & 0x1FFFull);
      cT[slot * MAXLEN_ + p] = token;
      atomicAdd(&tC[token], 1);
    }
    if (tid == 0) {
      cT[slot * MAXLEN_ + keep] = g;
      atomicAdd(&tC[g], 1);
      cL[slot] = keep + 1;
    }
    cOut++;
  }
}

// ---------------------------------------------------------------------------
// MFMA flash attention v3 (unchanged): async reg-staged K/V,
// grid = (qchunk, head, cluster), setprio on MFMA. 49.5 KB LDS.
// ---------------------------------------------------------------------------
__global__ __launch_bounds__(256)
void attn_kernel(const unsigned short* __restrict__ Qh, const unsigned short* __restrict__ Ql,
                 const unsigned short* __restrict__ Kh, const unsigned short* __restrict__ Kl,
                 const unsigned short* __restrict__ Vh, const unsigned short* __restrict__ Vl,
                 const int* __restrict__ cT, const int* __restrict__ cL,
                 float* __restrict__ OH) {
  const int qc = blockIdx.x, h = blockIdx.y, c = blockIdx.z;
  const int len = cL[c];
  const int q0 = qc * 64;
  if (len <= 0 || q0 >= len) return;

  __shared__ int toks[MAXLEN_];
  __shared__ __align__(16) unsigned short QP[8192];  // Q hi/lo tile -> P hi/lo
  __shared__ __align__(16) unsigned short KT[8192];  // K hi [0..4095], lo [4096..]
  __shared__ __align__(16) unsigned short VT[8192];  // V^T hi/lo

  const int tid = threadIdx.x, wave = tid >> 6, lane = tid & 63;
  const int lm = lane & 15, lg = lane >> 4;
  const int lr8 = lane >> 3;            // row within 8-row slab (Q glds)
  const int lc8 = (lane & 7) ^ lr8;     // pre-swizzled source chunk (Q glds)

  const int krow = tid >> 2;
  const int kc = (tid & 3) * 16;
  const int dg = tid & 15, kg = tid >> 4;
  const int vd0 = dg * 4;

  for (int i = tid; i < len; i += 256) toks[i] = cT[c * MAXLEN_ + i];
  __syncthreads();

  uint4 ka0, ka1, kb0, kb1;
  u16x4 va0, va1, va2, va3, vb0, vb1, vb2, vb3;

#define KV_LOAD(mt_) do {                                                      \
    int kr_ = (mt_) * 64 + krow;                                               \
    int tk_ = toks[kr_ < len ? kr_ : 0];                                       \
    const unsigned short* kph = Kh + (size_t)tk_ * D_ + h * DH_ + kc;          \
    const unsigned short* kpl = Kl + (size_t)tk_ * D_ + h * DH_ + kc;          \
    ka0 = *(const uint4*)(kph);  ka1 = *(const uint4*)(kph + 8);               \
    kb0 = *(const uint4*)(kpl);  kb1 = *(const uint4*)(kpl + 8);               \
    int vr_ = (mt_) * 64 + kg * 4;                                             \
    int t0_ = toks[vr_ + 0 < len ? vr_ + 0 : 0];                               \
    int t1_ = toks[vr_ + 1 < len ? vr_ + 1 : 0];                               \
    int t2_ = toks[vr_ + 2 < len ? vr_ + 2 : 0];                               \
    int t3_ = toks[vr_ + 3 < len ? vr_ + 3 : 0];                               \
    size_t off_ = (size_t)h * DH_ + vd0;                                       \
    va0 = *(const u16x4*)(Vh + (size_t)t0_ * D_ + off_);                       \
    va1 = *(const u16x4*)(Vh + (size_t)t1_ * D_ + off_);                       \
    va2 = *(const u16x4*)(Vh + (size_t)t2_ * D_ + off_);                       \
    va3 = *(const u16x4*)(Vh + (size_t)t3_ * D_ + off_);                       \
    vb0 = *(const u16x4*)(Vl + (size_t)t0_ * D_ + off_);                       \
    vb1 = *(const u16x4*)(Vl + (size_t)t1_ * D_ + off_);                       \
    vb2 = *(const u16x4*)(Vl + (size_t)t2_ * D_ + off_);                       \
    vb3 = *(const u16x4*)(Vl + (size_t)t3_ * D_ + off_);                       \
  } while (0)

#define KV_WRITE() do {                                                        \
    *(uint4*)&KT[SWZ(krow, kc)] = ka0;                                         \
    *(uint4*)&KT[SWZ(krow, kc + 8)] = ka1;                                     \
    *(uint4*)&KT[4096 + SWZ(krow, kc)] = kb0;                                  \
    *(uint4*)&KT[4096 + SWZ(krow, kc + 8)] = kb1;                              \
    _Pragma("unroll") for (int dd = 0; dd < 4; dd++) {                         \
      *(uint2*)&VT[SWZ(vd0 + dd, kg * 4)] =                                    \
          make_uint2(pk2(va0[dd], va1[dd]), pk2(va2[dd], va3[dd]));            \
      *(uint2*)&VT[4096 + SWZ(vd0 + dd, kg * 4)] =                             \
          make_uint2(pk2(vb0[dd], vb1[dd]), pk2(vb2[dd], vb3[dd]));            \
    }                                                                          \
  } while (0)

#pragma unroll
  for (int i = 0; i < 4; i++) {
    int slab = wave * 4 + i;
    int r8 = (slab & 7) * 8;
    int row = q0 + r8 + lr8;
    int tok = toks[row < len ? row : 0];
    const unsigned short* base = (slab < 8) ? Qh : Ql;
    glds16(base + (size_t)tok * D_ + h * DH_ + lc8 * 8,
           &QP[(slab >> 3) * 4096 + r8 * 64]);
  }
  KV_LOAD(0);
  __syncthreads();

  bf16x8 qAh[2], qAl[2];
#pragma unroll
  for (int s = 0; s < 2; s++) {
    qAh[s] = *(const bf16x8*)&QP[SWZ(wave * 16 + lm, s * 32 + lg * 8)];
    qAl[s] = *(const bf16x8*)&QP[4096 + SWZ(wave * 16 + lm, s * 32 + lg * 8)];
  }

  f32x4 accO[4];
#pragma unroll
  for (int t = 0; t < 4; t++) accO[t] = (f32x4){0.f, 0.f, 0.f, 0.f};
  float mm[4] = {-INFINITY, -INFINITY, -INFINITY, -INFINITY};
  float ll[4] = {0.f, 0.f, 0.f, 0.f};

  const int ntile = (len + 63) >> 6;
  for (int mt = 0; mt < ntile; mt++) {
    __syncthreads();
    KV_WRITE();
    __syncthreads();
    if (mt + 1 < ntile) KV_LOAD(mt + 1);

    f32x4 sA[4];
#pragma unroll
    for (int t = 0; t < 4; t++) sA[t] = (f32x4){0.f, 0.f, 0.f, 0.f};
    __builtin_amdgcn_s_setprio(1);
#pragma unroll
    for (int t = 0; t < 4; t++) {
#pragma unroll
      for (int s = 0; s < 2; s++) {
        bf16x8 kb = *(const bf16x8*)&KT[SWZ(t * 16 + lm, s * 32 + lg * 8)];
        bf16x8 kl2 = *(const bf16x8*)&KT[4096 + SWZ(t * 16 + lm, s * 32 + lg * 8)];
        sA[t] = __builtin_amdgcn_mfma_f32_16x16x32_bf16(qAh[s], kb, sA[t], 0, 0, 0);
        sA[t] = __builtin_amdgcn_mfma_f32_16x16x32_bf16(qAl[s], kb, sA[t], 0, 0, 0);
        sA[t] = __builtin_amdgcn_mfma_f32_16x16x32_bf16(qAh[s], kl2, sA[t], 0, 0, 0);
      }
    }
    __builtin_amdgcn_s_setprio(0);

    float sc[4][4];
#pragma unroll
    for (int t = 0; t < 4; t++) {
      bool kvalid = (mt * 64 + t * 16 + lm) < len;
#pragma unroll
      for (int r = 0; r < 4; r++)
        sc[t][r] = kvalid ? sA[t][r] * 0.125f : -1e9f;
    }
    float mx[4], nn[4], cor[4], sum[4];
#pragma unroll
    for (int r = 0; r < 4; r++) {
      mx[r] = fmaxf(fmaxf(sc[0][r], sc[1][r]), fmaxf(sc[2][r], sc[3][r]));
      mx[r] = fmaxf(mx[r], __shfl_xor(mx[r], 1, 64));
      mx[r] = fmaxf(mx[r], __shfl_xor(mx[r], 2, 64));
      mx[r] = fmaxf(mx[r], __shfl_xor(mx[r], 4, 64));
      mx[r] = fmaxf(mx[r], __shfl_xor(mx[r], 8, 64));
      nn[r] = fmaxf(mm[r], mx[r]);
      cor[r] = __expf(mm[r] - nn[r]);
      mm[r] = nn[r];
    }
    float pp[4][4];
#pragma unroll
    for (int t = 0; t < 4; t++)
#pragma unroll
      for (int r = 0; r < 4; r++) pp[t][r] = __expf(sc[t][r] - nn[r]);
#pragma unroll
    for (int r = 0; r < 4; r++) {
      sum[r] = (pp[0][r] + pp[1][r]) + (pp[2][r] + pp[3][r]);
      sum[r] += __shfl_xor(sum[r], 1, 64);
      sum[r] += __shfl_xor(sum[r], 2, 64);
      sum[r] += __shfl_xor(sum[r], 4, 64);
      sum[r] += __shfl_xor(sum[r], 8, 64);
      ll[r] = ll[r] * cor[r] + sum[r];
    }
#pragma unroll
    for (int t = 0; t < 4; t++) {
#pragma unroll
      for (int r = 0; r < 4; r++) {
        accO[t][r] *= cor[r];
        int row = wave * 16 + lg * 4 + r, col = t * 16 + lm;
        unsigned short hp = bfh(pp[t][r]);
        QP[SWZ(row, col)] = hp;
        QP[4096 + SWZ(row, col)] = bfh(pp[t][r] - bff(hp));
      }
    }

    bf16x8 pAh[2], pAl[2];
#pragma unroll
    for (int s = 0; s < 2; s++) {
      pAh[s] = *(const bf16x8*)&QP[SWZ(wave * 16 + lm, s * 32 + lg * 8)];
      pAl[s] = *(const bf16x8*)&QP[4096 + SWZ(wave * 16 + lm, s * 32 + lg * 8)];
    }
    __builtin_amdgcn_s_setprio(1);
#pragma unroll
    for (int t = 0; t < 4; t++) {
#pragma unroll
      for (int s = 0; s < 2; s++) {
        bf16x8 vb = *(const bf16x8*)&VT[SWZ(t * 16 + lm, s * 32 + lg * 8)];
        bf16x8 vl2 = *(const bf16x8*)&VT[4096 + SWZ(t * 16 + lm, s * 32 + lg * 8)];
        accO[t] = __builtin_amdgcn_mfma_f32_16x16x32_bf16(pAh[s], vb, accO[t], 0, 0, 0);
        accO[t] = __builtin_amdgcn_mfma_f32_16x16x32_bf16(pAl[s], vb, accO[t], 0, 0, 0);
        accO[t] = __builtin_amdgcn_mfma_f32_16x16x32_bf16(pAh[s], vl2, accO[t], 0, 0, 0);
      }
    }
    __builtin_amdgcn_s_setprio(0);
  }
#undef KV_LOAD
#undef KV_WRITE

#pragma unroll
  for (int t = 0; t < 4; t++) {
#pragma unroll
    for (int r = 0; r < 4; r++) {
      int row = q0 + wave * 16 + lg * 4 + r;
      if (row < len)
        atomicAdd(&OH[(size_t)toks[row] * D_ + h * DH_ + t * 16 + lm],
                  accO[t][r] / ll[r]);
    }
  }
}

// ---------------------------------------------------------------------------
// out_h /= clip(cnt,1), then split to bf16 hi/lo for the output GEMM
// ---------------------------------------------------------------------------
__global__ __launch_bounds__(256)
void norm_split(const float* __restrict__ OH, const int* __restrict__ cnt,
                unsigned short* __restrict__ oh, unsigned short* __restrict__ ol) {
  size_t i = (size_t)blockIdx.x * 256 + threadIdx.x;
  size_t n4 = NELEM_ / 4;
  if (i >= n4) return;
  int row = (int)((i * 4) >> 10);
  int cc = cnt[row];
  float s = 1.0f / (float)(cc > 1 ? cc : 1);
  float4 v = ((const float4*)OH)[i];
  v.x *= s; v.y *= s; v.z *= s; v.w *= s;
  unsigned short h0 = bfh(v.x), h1 = bfh(v.y), h2 = bfh(v.z), h3 = bfh(v.w);
  *(uint2*)&oh[i * 4] = make_uint2(pk2(h0, h1), pk2(h2, h3));
  *(uint2*)&ol[i * 4] =
      make_uint2(pk2(bfh(v.x - bff(h0)), bfh(v.y - bff(h1))),
                 pk2(bfh(v.z - bff(h2)), bfh(v.w - bff(h3))));
}

// ---------------------------------------------------------------------------
extern "C" void kernel_launch(void* const* d_in, const int* in_sizes, int n_in,
                              void* d_out, int out_size, void* d_ws, size_t ws_size,
                              hipStream_t stream) {
  (void)in_sizes; (void)n_in; (void)out_size; (void)ws_size;
  const float* q_in = (const float*)d_in[0];
  const float* k_in = (const float*)d_in[1];
  const float* v_in = (const float*)d_in[2];
  const int* seqlens = (const int*)d_in[3];
  const int* gidx    = (const int*)d_in[4];
  const float* Wq = (const float*)d_in[5];
  const float* Wk = (const float*)d_in[6];
  const float* Wv = (const float*)d_in[7];
  const float* Wo = (const float*)d_in[8];
  float* out = (float*)d_out;

  unsigned short* Qh = (unsigned short*)d_ws;
  unsigned short* Ql = Qh + NELEM_;
  unsigned short* Kh = Ql + NELEM_;
  unsigned short* Kl = Kh + NELEM_;
  unsigned short* Vh = Kl + NELEM_;
  unsigned short* Vl = Vh + NELEM_;
  float* OH = (float*)(Vl + NELEM_);
  float* WS = OH + NELEM_;
  float* FE = WS + (1 << 20);
  float* FQ = FE + (size_t)TTOT_ * DH_;
  float* FK = FQ + (size_t)TTOT_ * DH_;
  float* Wqm = FK + (size_t)TTOT_ * DH_;
  float* Wkm = Wqm + 64 * 1024;
  int* cT = (int*)(Wkm + 64 * 1024);
  int* cL = cT + MAXCL_ * MAXLEN_;
  int* tC = cL + MAXCL_;

  unsigned short* SPh = (unsigned short*)OH;   // input splits (dead before OH)
  unsigned short* SPl = SPh + NELEM_;
  unsigned short* WSh = (unsigned short*)WS;
  unsigned short* WSl = WSh + (1 << 20);
  unsigned short* OHh = Qh;                    // OH splits (Q dead after attn)
  unsigned short* OHl = Ql;

  hipMemsetAsync(tC, 0, TTOT_ * sizeof(int), stream);

  // ---- routing features (exact f32 path) ----
  wmean2<<<dim3(256, 2), 256, 0, stream>>>(Wq, Wk, Wqm, Wkm);
  gemm_feats<<<dim3(TTOT_ / 64, 2), 256, 0, stream>>>(q_in, k_in, Wqm, Wkm, FQ, FK);
  l2comb<<<TTOT_ / 4, 256, 0, stream>>>(FQ, FK, FE);
  routing_kernel<<<S_, 1024, 0, stream>>>(FE, seqlens, gidx, cT, cL, tC);

  // ---- Q/K/V projections: split-bf16 MFMA GEMMs with split epilogue ----
  const int n4in = (int)(NELEM_ / 4);
  const int n4w = (1024 * 1024) / 4;
  dim3 gg(TTOT_ / 128, D_ / 128);

  conv_split<<<(n4w + 255) / 256, 256, 0, stream>>>(Wq, WSh, WSl, n4w);
  conv_split<<<(n4in + 255) / 256, 256, 0, stream>>>(q_in, SPh, SPl, n4in);
  gemm_bf16s_sp<<<gg, 256, 0, stream>>>(SPh, SPl, WSh, WSl, Qh, Ql, TTOT_, D_, D_);

  conv_split<<<(n4w + 255) / 256, 256, 0, stream>>>(Wk, WSh, WSl, n4w);
  conv_split<<<(n4in + 255) / 256, 256, 0, stream>>>(k_in, SPh, SPl, n4in);
  gemm_bf16s_sp<<<gg, 256, 0, stream>>>(SPh, SPl, WSh, WSl, Kh, Kl, TTOT_, D_, D_);

  conv_split<<<(n4w + 255) / 256, 256, 0, stream>>>(Wv, WSh, WSl, n4w);
  conv_split<<<(n4in + 255) / 256, 256, 0, stream>>>(v_in, SPh, SPl, n4in);
  gemm_bf16s_sp<<<gg, 256, 0, stream>>>(SPh, SPl, WSh, WSl, Vh, Vl, TTOT_, D_, D_);

  // ---- attention (OH aliases the now-dead input-split slab) ----
  hipMemsetAsync(OH, 0, NELEM_ * sizeof(float), stream);
  attn_kernel<<<dim3((MAXLEN_ + 63) / 64, H_, MAXCL_), 256, 0, stream>>>(
      Qh, Ql, Kh, Kl, Vh, Vl, cT, cL, OH);

  // ---- normalize + split (into dead Q slab), output GEMM ----
  norm_split<<<(unsigned)((NELEM_ / 4 + 255) / 256), 256, 0, stream>>>(OH, tC, OHh, OHl);
  conv_split<<<(n4w + 255) / 256, 256, 0, stream>>>(Wo, WSh, WSl, n4w);
  gemm_bf16s<<<gg, 256, 0, stream>>>(OHh, OHl, WSh, WSl, out, TTOT_, D_, D_);
}

// Round 9
// 522.798 us; speedup vs baseline: 6.5968x; 1.0184x over previous
//
#include <hip/hip_runtime.h>
#include <math.h>

#define S_ 4
#define L_ 2048
#define D_ 1024
#define H_ 16
#define DH_ 64
#define TTOT_ 8192
#define WCL_ 384
#define KMAX_ 16
#define MAXCL_ (S_*KMAX_)
#define MAXLEN_ (WCL_+1)   // 385
#define LSCAP_ 4096
#define NELEM_ ((size_t)TTOT_*(size_t)D_)

typedef __attribute__((ext_vector_type(8))) short bf16x8;
typedef __attribute__((ext_vector_type(4))) float f32x4;
typedef __attribute__((ext_vector_type(4))) unsigned short u16x4;

// bf16 split helpers (RNE)
__device__ __forceinline__ unsigned short bfh(float x) {
  unsigned u = __float_as_uint(x);
  return (unsigned short)((u + 0x7FFFu + ((u >> 16) & 1u)) >> 16);
}
__device__ __forceinline__ float bff(unsigned short h) {
  return __uint_as_float(((unsigned)h) << 16);
}
__device__ __forceinline__ unsigned pk2(unsigned short a, unsigned short b) {
  return (unsigned)a | ((unsigned)b << 16);
}
// XOR swizzle on ushort index within [row][64] tiles (16B-chunk granularity)
#define SWZ(r, c) (((r) << 6) + ((c) ^ (((r) & 7) << 3)))

__device__ __forceinline__ void glds16(const void* g, void* l) {
  __builtin_amdgcn_global_load_lds(
      (const __attribute__((address_space(1))) unsigned int*)g,
      (__attribute__((address_space(3))) unsigned int*)l, 16, 0, 0);
}

// ---------------------------------------------------------------------------
// Fused feats GEMM: C[M,64] = A[M,1024] * B[64,1024]^T for (q,k) via grid.y
// ---------------------------------------------------------------------------
__global__ __launch_bounds__(256)
void gemm_feats(const float* __restrict__ Aq, const float* __restrict__ Ak,
                const float* __restrict__ Bq, const float* __restrict__ Bk,
                float* __restrict__ Cq, float* __restrict__ Ck) {
  const float* __restrict__ A = blockIdx.y ? Ak : Aq;
  const float* __restrict__ B = blockIdx.y ? Bk : Bq;
  float* __restrict__ C = blockIdx.y ? Ck : Cq;
  const int Kd = 1024, N = 64;
  __shared__ float As[16][68];
  __shared__ float Bs[16][68];
  const int tx = threadIdx.x & 15, ty = threadIdx.x >> 4;
  const int m0 = blockIdx.x * 64;
  const int lr = threadIdx.x >> 2, lc = threadIdx.x & 3;
  float acc[4][4] = {};
  for (int k0 = 0; k0 < Kd; k0 += 16) {
    __syncthreads();
    float4 a4 = *(const float4*)(A + (size_t)(m0 + lr) * Kd + k0 + lc * 4);
    float4 b4 = *(const float4*)(B + (size_t)lr * Kd + k0 + lc * 4);
    As[lc*4+0][lr] = a4.x; As[lc*4+1][lr] = a4.y; As[lc*4+2][lr] = a4.z; As[lc*4+3][lr] = a4.w;
    Bs[lc*4+0][lr] = b4.x; Bs[lc*4+1][lr] = b4.y; Bs[lc*4+2][lr] = b4.z; Bs[lc*4+3][lr] = b4.w;
    __syncthreads();
#pragma unroll
    for (int kk = 0; kk < 16; kk++) {
      float4 av = *(const float4*)&As[kk][ty * 4];
      float4 bv = *(const float4*)&Bs[kk][tx * 4];
      float aa[4] = {av.x, av.y, av.z, av.w};
      float bb[4] = {bv.x, bv.y, bv.z, bv.w};
#pragma unroll
      for (int i = 0; i < 4; i++)
#pragma unroll
        for (int j = 0; j < 4; j++) acc[i][j] += aa[i] * bb[j];
    }
  }
#pragma unroll
  for (int i = 0; i < 4; i++)
#pragma unroll
    for (int j = 0; j < 4; j++)
      C[(size_t)(m0 + ty * 4 + i) * N + (tx * 4 + j)] = acc[i][j];
}

// ---------------------------------------------------------------------------
// Split-bf16 MFMA GEMM core: 128x128 tile, BK=64, 4 waves, glds staging.
// ---------------------------------------------------------------------------
#define GEMM_BODY                                                              \
  __shared__ __align__(16) unsigned short LA[2][128 * 64];                     \
  __shared__ __align__(16) unsigned short LB[2][128 * 64];                     \
  const int tid = threadIdx.x, wave = tid >> 6, lane = tid & 63;               \
  const int lm = lane & 15, lg = lane >> 4;                                    \
  const int m0 = blockIdx.x * 128, n0 = blockIdx.y * 128;                      \
  const int wr = wave >> 1, wc = wave & 1;                                     \
  const int lrow = lane >> 3;                                                  \
  const int lchk = (lane & 7) ^ lrow;                                          \
  f32x4 acc[4][4];                                                             \
  _Pragma("unroll") for (int i = 0; i < 4; i++)                                \
      _Pragma("unroll") for (int j = 0; j < 4; j++)                            \
          acc[i][j] = (f32x4){0.f, 0.f, 0.f, 0.f};                             \
  for (int k0 = 0; k0 < Kd; k0 += 64) {                                        \
    __syncthreads();                                                           \
    _Pragma("unroll") for (int i = 0; i < 4; i++) {                            \
      const int r = wave * 32 + i * 8;                                         \
      const size_t ga = (size_t)(m0 + r + lrow) * Kd + k0 + lchk * 8;          \
      const size_t gb = (size_t)(n0 + r + lrow) * Kd + k0 + lchk * 8;          \
      glds16(&Ah[ga], &LA[0][r * 64]);                                         \
      glds16(&Al[ga], &LA[1][r * 64]);                                         \
      glds16(&Bh[gb], &LB[0][r * 64]);                                         \
      glds16(&Bl[gb], &LB[1][r * 64]);                                         \
    }                                                                          \
    __syncthreads();                                                           \
    _Pragma("unroll") for (int s = 0; s < 2; s++) {                            \
      bf16x8 ah[4], al[4], bh[4], bl[4];                                       \
      _Pragma("unroll") for (int i = 0; i < 4; i++) {                          \
        const int ra = wr * 64 + i * 16 + lm;                                  \
        const int ca = ((s * 4 + lg) ^ (ra & 7)) * 8;                          \
        ah[i] = *(const bf16x8*)&LA[0][ra * 64 + ca];                          \
        al[i] = *(const bf16x8*)&LA[1][ra * 64 + ca];                          \
        const int rb = wc * 64 + i * 16 + lm;                                  \
        const int cb = ((s * 4 + lg) ^ (rb & 7)) * 8;                          \
        bh[i] = *(const bf16x8*)&LB[0][rb * 64 + cb];                          \
        bl[i] = *(const bf16x8*)&LB[1][rb * 64 + cb];                          \
      }                                                                        \
      _Pragma("unroll") for (int i = 0; i < 4; i++)                            \
          _Pragma("unroll") for (int j = 0; j < 4; j++) {                      \
        acc[i][j] = __builtin_amdgcn_mfma_f32_16x16x32_bf16(ah[i], bh[j], acc[i][j], 0, 0, 0); \
        acc[i][j] = __builtin_amdgcn_mfma_f32_16x16x32_bf16(al[i], bh[j], acc[i][j], 0, 0, 0); \
        acc[i][j] = __builtin_amdgcn_mfma_f32_16x16x32_bf16(ah[i], bl[j], acc[i][j], 0, 0, 0); \
      }                                                                        \
    }                                                                          \
  }

__global__ __launch_bounds__(256)
void gemm_bf16s(const unsigned short* __restrict__ Ah, const unsigned short* __restrict__ Al,
                const unsigned short* __restrict__ Bh, const unsigned short* __restrict__ Bl,
                float* __restrict__ C, int M, int N, int Kd) {
  GEMM_BODY
#pragma unroll
  for (int i = 0; i < 4; i++)
#pragma unroll
    for (int j = 0; j < 4; j++) {
      const int rowb = m0 + wr * 64 + i * 16 + lg * 4;
      const int col = n0 + wc * 64 + j * 16 + lm;
#pragma unroll
      for (int r = 0; r < 4; r++)
        C[(size_t)(rowb + r) * N + col] = acc[i][j][r];
    }
}

__global__ __launch_bounds__(256)
void gemm_bf16s_sp(const unsigned short* __restrict__ Ah, const unsigned short* __restrict__ Al,
                   const unsigned short* __restrict__ Bh, const unsigned short* __restrict__ Bl,
                   unsigned short* __restrict__ Ch, unsigned short* __restrict__ Cl,
                   int M, int N, int Kd) {
  GEMM_BODY
#pragma unroll
  for (int i = 0; i < 4; i++)
#pragma unroll
    for (int j = 0; j < 4; j++) {
      const int rowb = m0 + wr * 64 + i * 16 + lg * 4;
      const int col = n0 + wc * 64 + j * 16 + lm;
#pragma unroll
      for (int r = 0; r < 4; r++) {
        float v = acc[i][j][r];
        unsigned short hh = bfh(v);
        Ch[(size_t)(rowb + r) * N + col] = hh;
        Cl[(size_t)(rowb + r) * N + col] = bfh(v - bff(hh));
      }
    }
}

// ---------------------------------------------------------------------------
// f32 -> (hi,lo) bf16 split, vectorized
// ---------------------------------------------------------------------------
__global__ __launch_bounds__(256)
void conv_split(const float* __restrict__ src, unsigned short* __restrict__ dh,
                unsigned short* __restrict__ dl, int n4) {
  int i = blockIdx.x * 256 + threadIdx.x;
  if (i >= n4) return;
  float4 v = ((const float4*)src)[i];
  unsigned short h0 = bfh(v.x), h1 = bfh(v.y), h2 = bfh(v.z), h3 = bfh(v.w);
  *(uint2*)&dh[(size_t)i * 4] = make_uint2(pk2(h0, h1), pk2(h2, h3));
  *(uint2*)&dl[(size_t)i * 4] =
      make_uint2(pk2(bfh(v.x - bff(h0)), bfh(v.y - bff(h1))),
                 pk2(bfh(v.z - bff(h2)), bfh(v.w - bff(h3))));
}

// ---------------------------------------------------------------------------
// Fused Wm[d][k] = (1/16) sum_h W[h*64+d][k] for both Wq and Wk (grid.y)
// ---------------------------------------------------------------------------
__global__ __launch_bounds__(256)
void wmean2(const float* __restrict__ Wq, const float* __restrict__ Wk,
            float* __restrict__ Wqm, float* __restrict__ Wkm) {
  const float* __restrict__ W = blockIdx.y ? Wk : Wq;
  float* __restrict__ Wm = blockIdx.y ? Wkm : Wqm;
  int i = blockIdx.x * 256 + threadIdx.x;
  if (i >= 64 * 1024) return;
  int d = i >> 10, kk = i & 1023;
  float s = 0.f;
#pragma unroll
  for (int h = 0; h < 16; h++) s += W[(size_t)(h * 64 + d) * 1024 + kk];
  Wm[i] = s * (1.0f / 16.0f);
}

// ---------------------------------------------------------------------------
// FE[t] = 0.5*(l2n(FQ[t]) + l2n(FK[t]))   (one wave per token)
// ---------------------------------------------------------------------------
__global__ __launch_bounds__(256)
void l2comb(const float* __restrict__ FQ, const float* __restrict__ FK,
            float* __restrict__ FE) {
  int t = blockIdx.x * 4 + (threadIdx.x >> 6);
  int lane = threadIdx.x & 63;
  if (t >= TTOT_) return;
  float q = FQ[(size_t)t * 64 + lane], k = FK[(size_t)t * 64 + lane];
  float q2 = q * q, k2 = k * k;
#pragma unroll
  for (int m = 1; m < 64; m <<= 1) {
    q2 += __shfl_xor(q2, m, 64);
    k2 += __shfl_xor(k2, m, 64);
  }
  FE[(size_t)t * 64 + lane] =
      0.5f * (q / (sqrtf(q2) + 1e-6f) + k / (sqrtf(k2) + 1e-6f));
}

// ---------------------------------------------------------------------------
// Routing (replica of _route_np; same decision stream). Assignment dots use
// register-hoisted features; centroid accumulation LDS-chunk staged,
// ascending-i order per (cluster,dim) — bit-identical to np.add.at.
// ---------------------------------------------------------------------------
__global__ __launch_bounds__(1024)
void routing_kernel(const float* __restrict__ FE, const int* __restrict__ seqlens,
                    const int* __restrict__ gidx, int* __restrict__ cT,
                    int* __restrict__ cL, int* __restrict__ tC) {
  __shared__ float cent[KMAX_][64];
  __shared__ float chunk[128][64];
  __shared__ int cnt1[KMAX_];
  __shared__ int cnt2[KMAX_];
  __shared__ int starts[KMAX_ + 1];
  __shared__ unsigned char assign[LSCAP_];
  __shared__ unsigned long long keys[LSCAP_];

  const int s = blockIdx.x, tid = threadIdx.x;
  int a = 0;
  for (int t = 0; t < s; t++) a += seqlens[t];
  int Ls = seqlens[s];
  if (Ls > LSCAP_) Ls = LSCAP_;
  for (int cs = tid; cs < KMAX_; cs += 1024) cL[s * KMAX_ + cs] = 0;
  if (Ls <= 0) return;

  int wloc = Ls < WCL_ ? Ls : WCL_;
  if (wloc < 1) wloc = 1;
  int k = (Ls + wloc - 1) / wloc;
  if (k < 1) k = 1;
  if (k > KMAX_) k = KMAX_;

  if (tid < k * 64) {
    int j = tid >> 6, d = tid & 63;
    double step = (k > 1) ? (double)(Ls - 1) / (double)(k - 1) : 0.0;
    long ii = (long)rint(step * (double)j);
    if (ii < 0) ii = 0;
    if (ii > Ls - 1) ii = Ls - 1;
    cent[j][d] = FE[(size_t)(a + ii) * DH_ + d];
  }
  if (tid < KMAX_) cnt1[tid] = 0;
  __syncthreads();

  // ---- assignment pass 1 (hoisted f, same add order as dot64) ----
  for (int i = tid; i < Ls; i += 1024) {
    const float4* f4 = (const float4*)(FE + (size_t)(a + i) * DH_);
    float4 fr[16];
#pragma unroll
    for (int c4 = 0; c4 < 16; c4++) fr[c4] = f4[c4];
    float best = -1e30f; int bj = 0;
    for (int j = 0; j < k; j++) {
      float sd = 0.f;
#pragma unroll
      for (int c4 = 0; c4 < 16; c4++) {
        float4 cv = *(const float4*)&cent[j][c4 * 4];
        sd += fr[c4].x * cv.x; sd += fr[c4].y * cv.y;
        sd += fr[c4].z * cv.z; sd += fr[c4].w * cv.w;
      }
      if (sd > best) { best = sd; bj = j; }
    }
    assign[i] = (unsigned char)bj;
  }
  __syncthreads();
  for (int i = tid; i < Ls; i += 1024) atomicAdd(&cnt1[assign[i]], 1);
  __syncthreads();

  // ---- exact np.add.at centroid accumulation, LDS-chunk staged ----
  float csum_acc = 0.f;
  const int jj = tid >> 6, dd = tid & 63;
  for (int base = 0; base < Ls; base += 128) {
    int nrows = Ls - base; if (nrows > 128) nrows = 128;
    __syncthreads();
    for (int e = tid; e < nrows * 16; e += 1024) {
      int rr = e >> 4, cc = e & 15;
      *(float4*)&chunk[rr][cc * 4] =
          *(const float4*)(FE + (size_t)(a + base + rr) * DH_ + cc * 4);
    }
    __syncthreads();
    if (jj < k) {
      for (int i = 0; i < nrows; i++) {
        float v = chunk[i][dd];
        csum_acc += (assign[base + i] == (unsigned char)jj) ? v : 0.0f;
      }
    }
  }
  __syncthreads();
  if (tid < k * 64) {
    float v = csum_acc / fmaxf((float)cnt1[jj], 1.0f);
    float sq = v * v;
#pragma unroll
    for (int m = 1; m < 64; m <<= 1) sq += __shfl_xor(sq, m, 64);
    cent[jj][dd] = v / (sqrtf(sq) + 1e-6f);
  }
  __syncthreads();

  // ---- assignment pass 2 + sort keys (hoisted f) ----
  int NP2 = 1;
  while (NP2 < Ls) NP2 <<= 1;
  for (int i = tid; i < NP2; i += 1024) {
    unsigned long long key;
    if (i < Ls) {
      const float4* f4 = (const float4*)(FE + (size_t)(a + i) * DH_);
      float4 fr[16];
#pragma unroll
      for (int c4 = 0; c4 < 16; c4++) fr[c4] = f4[c4];
      float best = -1e30f; int bj = 0;
      for (int j = 0; j < k; j++) {
        float sd = 0.f;
#pragma unroll
        for (int c4 = 0; c4 < 16; c4++) {
          float4 cv = *(const float4*)&cent[j][c4 * 4];
          sd += fr[c4].x * cv.x; sd += fr[c4].y * cv.y;
          sd += fr[c4].z * cv.z; sd += fr[c4].w * cv.w;
        }
        if (sd > best) { best = sd; bj = j; }
      }
      assign[i] = (unsigned char)bj;
      unsigned int u = __float_as_uint(best);
      unsigned int ord = (u & 0x80000000u) ? ~u : (u | 0x80000000u);
      unsigned int dsc = ~ord;
      key = ((unsigned long long)bj << 45) |
            ((unsigned long long)dsc << 13) | (unsigned long long)i;
    } else {
      key = ~0ull;
    }
    keys[i] = key;
  }
  if (tid < KMAX_) cnt2[tid] = 0;
  __syncthreads();
  for (int i = tid; i < Ls; i += 1024) atomicAdd(&cnt2[assign[i]], 1);
  __syncthreads();

  for (int len2 = 2; len2 <= NP2; len2 <<= 1) {
    for (int st = len2 >> 1; st > 0; st >>= 1) {
      for (int i = tid; i < NP2; i += 1024) {
        int j = i ^ st;
        if (j > i) {
          unsigned long long x = keys[i], y = keys[j];
          bool asc = ((i & len2) == 0);
          if ((x > y) == asc) { keys[i] = y; keys[j] = x; }
        }
      }
      __syncthreads();
    }
  }
  if (tid == 0) {
    starts[0] = 0;
    for (int j = 0; j < k; j++) starts[j + 1] = starts[j] + cnt2[j];
  }
  __syncthreads();

  const int g = gidx[s];
  int cOut = 0;
  for (int j = 0; j < k; j++) {
    int cj = cnt2[j];
    if (cj <= 0) continue;
    int keep = cj < wloc ? cj : wloc;
    int slot = s * KMAX_ + cOut;
    for (int p = tid; p < keep; p += 1024) {
      int token = a + (int)(keys[starts[j] + p] & 0x1FFFull);
      cT[slot * MAXLEN_ + p] = token;
      atomicAdd(&tC[token], 1);
    }
    if (tid == 0) {
      cT[slot * MAXLEN_ + keep] = g;
      atomicAdd(&tC[g], 1);
      cL[slot] = keep + 1;
    }
    cOut++;
  }
}

// ---------------------------------------------------------------------------
// MFMA flash attention v4: XCD-grouped 1D grid (the 7 q-chunks of each
// (head,cluster) group map to the SAME XCD under round-robin dispatch so
// the K/V gather set stays in that XCD's L2), async reg-staged K/V,
// setprio on MFMA, P in plain bf16 (peak=1.0 exact; residual ≲1e-3).
// ---------------------------------------------------------------------------
__global__ __launch_bounds__(256)
void attn_kernel(const unsigned short* __restrict__ Qh, const unsigned short* __restrict__ Ql,
                 const unsigned short* __restrict__ Kh, const unsigned short* __restrict__ Kl,
                 const unsigned short* __restrict__ Vh, const unsigned short* __restrict__ Vl,
                 const int* __restrict__ cT, const int* __restrict__ cL,
                 float* __restrict__ OH) {
  // flat = 7*(16*64) blocks; decode so group g (h,c) has all 7 qc on one XCD:
  // block b -> XCD b%8 (round-robin); choose work s.t. g%8 == b%8.
  const int flat = blockIdx.x;
  const int xcd = flat & 7;
  const int i8 = flat >> 3;              // 0..895
  const int qc = i8 % 7;
  const int g = xcd + 8 * (i8 / 7);      // 0..1023, g%8==xcd
  const int h = g & 15, c = g >> 4;

  const int len = cL[c];
  const int q0 = qc * 64;
  if (len <= 0 || q0 >= len) return;

  __shared__ int toks[MAXLEN_];
  __shared__ __align__(16) unsigned short QP[8192];  // Q hi/lo tile -> P hi
  __shared__ __align__(16) unsigned short KT[8192];  // K hi [0..4095], lo [4096..]
  __shared__ __align__(16) unsigned short VT[8192];  // V^T hi/lo

  const int tid = threadIdx.x, wave = tid >> 6, lane = tid & 63;
  const int lm = lane & 15, lg = lane >> 4;
  const int lr8 = lane >> 3;            // row within 8-row slab (Q glds)
  const int lc8 = (lane & 7) ^ lr8;     // pre-swizzled source chunk (Q glds)

  const int krow = tid >> 2;
  const int kc = (tid & 3) * 16;
  const int dg = tid & 15, kg = tid >> 4;
  const int vd0 = dg * 4;

  for (int i = tid; i < len; i += 256) toks[i] = cT[c * MAXLEN_ + i];
  __syncthreads();

  uint4 ka0, ka1, kb0, kb1;
  u16x4 va0, va1, va2, va3, vb0, vb1, vb2, vb3;

#define KV_LOAD(mt_) do {                                                      \
    int kr_ = (mt_) * 64 + krow;                                               \
    int tk_ = toks[kr_ < len ? kr_ : 0];                                       \
    const unsigned short* kph = Kh + (size_t)tk_ * D_ + h * DH_ + kc;          \
    const unsigned short* kpl = Kl + (size_t)tk_ * D_ + h * DH_ + kc;          \
    ka0 = *(const uint4*)(kph);  ka1 = *(const uint4*)(kph + 8);               \
    kb0 = *(const uint4*)(kpl);  kb1 = *(const uint4*)(kpl + 8);               \
    int vr_ = (mt_) * 64 + kg * 4;                                             \
    int t0_ = toks[vr_ + 0 < len ? vr_ + 0 : 0];                               \
    int t1_ = toks[vr_ + 1 < len ? vr_ + 1 : 0];                               \
    int t2_ = toks[vr_ + 2 < len ? vr_ + 2 : 0];                               \
    int t3_ = toks[vr_ + 3 < len ? vr_ + 3 : 0];                               \
    size_t off_ = (size_t)h * DH_ + vd0;                                       \
    va0 = *(const u16x4*)(Vh + (size_t)t0_ * D_ + off_);                       \
    va1 = *(const u16x4*)(Vh + (size_t)t1_ * D_ + off_);                       \
    va2 = *(const u16x4*)(Vh + (size_t)t2_ * D_ + off_);                       \
    va3 = *(const u16x4*)(Vh + (size_t)t3_ * D_ + off_);                       \
    vb0 = *(const u16x4*)(Vl + (size_t)t0_ * D_ + off_);                       \
    vb1 = *(const u16x4*)(Vl + (size_t)t1_ * D_ + off_);                       \
    vb2 = *(const u16x4*)(Vl + (size_t)t2_ * D_ + off_);                       \
    vb3 = *(const u16x4*)(Vl + (size_t)t3_ * D_ + off_);                       \
  } while (0)

#define KV_WRITE() do {                                                        \
    *(uint4*)&KT[SWZ(krow, kc)] = ka0;                                         \
    *(uint4*)&KT[SWZ(krow, kc + 8)] = ka1;                                     \
    *(uint4*)&KT[4096 + SWZ(krow, kc)] = kb0;                                  \
    *(uint4*)&KT[4096 + SWZ(krow, kc + 8)] = kb1;                              \
    _Pragma("unroll") for (int dd = 0; dd < 4; dd++) {                         \
      *(uint2*)&VT[SWZ(vd0 + dd, kg * 4)] =                                    \
          make_uint2(pk2(va0[dd], va1[dd]), pk2(va2[dd], va3[dd]));            \
      *(uint2*)&VT[4096 + SWZ(vd0 + dd, kg * 4)] =                             \
          make_uint2(pk2(vb0[dd], vb1[dd]), pk2(vb2[dd], vb3[dd]));            \
    }                                                                          \
  } while (0)

#pragma unroll
  for (int i = 0; i < 4; i++) {
    int slab = wave * 4 + i;
    int r8 = (slab & 7) * 8;
    int row = q0 + r8 + lr8;
    int tok = toks[row < len ? row : 0];
    const unsigned short* base = (slab < 8) ? Qh : Ql;
    glds16(base + (size_t)tok * D_ + h * DH_ + lc8 * 8,
           &QP[(slab >> 3) * 4096 + r8 * 64]);
  }
  KV_LOAD(0);
  __syncthreads();

  bf16x8 qAh[2], qAl[2];
#pragma unroll
  for (int s = 0; s < 2; s++) {
    qAh[s] = *(const bf16x8*)&QP[SWZ(wave * 16 + lm, s * 32 + lg * 8)];
    qAl[s] = *(const bf16x8*)&QP[4096 + SWZ(wave * 16 + lm, s * 32 + lg * 8)];
  }

  f32x4 accO[4];
#pragma unroll
  for (int t = 0; t < 4; t++) accO[t] = (f32x4){0.f, 0.f, 0.f, 0.f};
  float mm[4] = {-INFINITY, -INFINITY, -INFINITY, -INFINITY};
  float ll[4] = {0.f, 0.f, 0.f, 0.f};

  const int ntile = (len + 63) >> 6;
  for (int mt = 0; mt < ntile; mt++) {
    __syncthreads();
    KV_WRITE();
    __syncthreads();
    if (mt + 1 < ntile) KV_LOAD(mt + 1);

    f32x4 sA[4];
#pragma unroll
    for (int t = 0; t < 4; t++) sA[t] = (f32x4){0.f, 0.f, 0.f, 0.f};
    __builtin_amdgcn_s_setprio(1);
#pragma unroll
    for (int t = 0; t < 4; t++) {
#pragma unroll
      for (int s = 0; s < 2; s++) {
        bf16x8 kb = *(const bf16x8*)&KT[SWZ(t * 16 + lm, s * 32 + lg * 8)];
        bf16x8 kl2 = *(const bf16x8*)&KT[4096 + SWZ(t * 16 + lm, s * 32 + lg * 8)];
        sA[t] = __builtin_amdgcn_mfma_f32_16x16x32_bf16(qAh[s], kb, sA[t], 0, 0, 0);
        sA[t] = __builtin_amdgcn_mfma_f32_16x16x32_bf16(qAl[s], kb, sA[t], 0, 0, 0);
        sA[t] = __builtin_amdgcn_mfma_f32_16x16x32_bf16(qAh[s], kl2, sA[t], 0, 0, 0);
      }
    }
    __builtin_amdgcn_s_setprio(0);

    float sc[4][4];
#pragma unroll
    for (int t = 0; t < 4; t++) {
      bool kvalid = (mt * 64 + t * 16 + lm) < len;
#pragma unroll
      for (int r = 0; r < 4; r++)
        sc[t][r] = kvalid ? sA[t][r] * 0.125f : -1e9f;
    }
    float mx[4], nn[4], cor[4], sum[4];
#pragma unroll
    for (int r = 0; r < 4; r++) {
      mx[r] = fmaxf(fmaxf(sc[0][r], sc[1][r]), fmaxf(sc[2][r], sc[3][r]));
      mx[r] = fmaxf(mx[r], __shfl_xor(mx[r], 1, 64));
      mx[r] = fmaxf(mx[r], __shfl_xor(mx[r], 2, 64));
      mx[r] = fmaxf(mx[r], __shfl_xor(mx[r], 4, 64));
      mx[r] = fmaxf(mx[r], __shfl_xor(mx[r], 8, 64));
      nn[r] = fmaxf(mm[r], mx[r]);
      cor[r] = __expf(mm[r] - nn[r]);
      mm[r] = nn[r];
    }
    float pp[4][4];
#pragma unroll
    for (int t = 0; t < 4; t++)
#pragma unroll
      for (int r = 0; r < 4; r++) pp[t][r] = __expf(sc[t][r] - nn[r]);
#pragma unroll
    for (int r = 0; r < 4; r++) {
      sum[r] = (pp[0][r] + pp[1][r]) + (pp[2][r] + pp[3][r]);
      sum[r] += __shfl_xor(sum[r], 1, 64);
      sum[r] += __shfl_xor(sum[r], 2, 64);
      sum[r] += __shfl_xor(sum[r], 4, 64);
      sum[r] += __shfl_xor(sum[r], 8, 64);
      ll[r] = ll[r] * cor[r] + sum[r];
    }
    // ---- P hi only into the (dead-Q) QP buffer ----
#pragma unroll
    for (int t = 0; t < 4; t++) {
#pragma unroll
      for (int r = 0; r < 4; r++) {
        accO[t][r] *= cor[r];
        int row = wave * 16 + lg * 4 + r, col = t * 16 + lm;
        QP[SWZ(row, col)] = bfh(pp[t][r]);
      }
    }

    // ---- PV: 2 terms (Ph*Vh + Ph*Vl) ----
    bf16x8 pAh[2];
#pragma unroll
    for (int s = 0; s < 2; s++)
      pAh[s] = *(const bf16x8*)&QP[SWZ(wave * 16 + lm, s * 32 + lg * 8)];
    __builtin_amdgcn_s_setprio(1);
#pragma unroll
    for (int t = 0; t < 4; t++) {
#pragma unroll
      for (int s = 0; s < 2; s++) {
        bf16x8 vb = *(const bf16x8*)&VT[SWZ(t * 16 + lm, s * 32 + lg * 8)];
        bf16x8 vl2 = *(const bf16x8*)&VT[4096 + SWZ(t * 16 + lm, s * 32 + lg * 8)];
        accO[t] = __builtin_amdgcn_mfma_f32_16x16x32_bf16(pAh[s], vb, accO[t], 0, 0, 0);
        accO[t] = __builtin_amdgcn_mfma_f32_16x16x32_bf16(pAh[s], vl2, accO[t], 0, 0, 0);
      }
    }
    __builtin_amdgcn_s_setprio(0);
  }
#undef KV_LOAD
#undef KV_WRITE

#pragma unroll
  for (int t = 0; t < 4; t++) {
#pragma unroll
    for (int r = 0; r < 4; r++) {
      int row = q0 + wave * 16 + lg * 4 + r;
      if (row < len)
        atomicAdd(&OH[(size_t)toks[row] * D_ + h * DH_ + t * 16 + lm],
                  accO[t][r] / ll[r]);
    }
  }
}

// ---------------------------------------------------------------------------
// out_h /= clip(cnt,1), then split to bf16 hi/lo for the output GEMM
// ---------------------------------------------------------------------------
__global__ __launch_bounds__(256)
void norm_split(const float* __restrict__ OH, const int* __restrict__ cnt,
                unsigned short* __restrict__ oh, unsigned short* __restrict__ ol) {
  size_t i = (size_t)blockIdx.x * 256 + threadIdx.x;
  size_t n4 = NELEM_ / 4;
  if (i >= n4) return;
  int row = (int)((i * 4) >> 10);
  int cc = cnt[row];
  float s = 1.0f / (float)(cc > 1 ? cc : 1);
  float4 v = ((const float4*)OH)[i];
  v.x *= s; v.y *= s; v.z *= s; v.w *= s;
  unsigned short h0 = bfh(v.x), h1 = bfh(v.y), h2 = bfh(v.z), h3 = bfh(v.w);
  *(uint2*)&oh[i * 4] = make_uint2(pk2(h0, h1), pk2(h2, h3));
  *(uint2*)&ol[i * 4] =
      make_uint2(pk2(bfh(v.x - bff(h0)), bfh(v.y - bff(h1))),
                 pk2(bfh(v.z - bff(h2)), bfh(v.w - bff(h3))));
}

// ---------------------------------------------------------------------------
extern "C" void kernel_launch(void* const* d_in, const int* in_sizes, int n_in,
                              void* d_out, int out_size, void* d_ws, size_t ws_size,
                              hipStream_t stream) {
  (void)in_sizes; (void)n_in; (void)out_size; (void)ws_size;
  const float* q_in = (const float*)d_in[0];
  const float* k_in = (const float*)d_in[1];
  const float* v_in = (const float*)d_in[2];
  const int* seqlens = (const int*)d_in[3];
  const int* gidx    = (const int*)d_in[4];
  const float* Wq = (const float*)d_in[5];
  const float* Wk = (const float*)d_in[6];
  const float* Wv = (const float*)d_in[7];
  const float* Wo = (const float*)d_in[8];
  float* out = (float*)d_out;

  unsigned short* Qh = (unsigned short*)d_ws;
  unsigned short* Ql = Qh + NELEM_;
  unsigned short* Kh = Ql + NELEM_;
  unsigned short* Kl = Kh + NELEM_;
  unsigned short* Vh = Kl + NELEM_;
  unsigned short* Vl = Vh + NELEM_;
  float* OH = (float*)(Vl + NELEM_);
  float* WS = OH + NELEM_;
  float* FE = WS + (1 << 20);
  float* FQ = FE + (size_t)TTOT_ * DH_;
  float* FK = FQ + (size_t)TTOT_ * DH_;
  float* Wqm = FK + (size_t)TTOT_ * DH_;
  float* Wkm = Wqm + 64 * 1024;
  int* cT = (int*)(Wkm + 64 * 1024);
  int* cL = cT + MAXCL_ * MAXLEN_;
  int* tC = cL + MAXCL_;

  unsigned short* SPh = (unsigned short*)OH;   // input splits (dead before OH)
  unsigned short* SPl = SPh + NELEM_;
  unsigned short* WSh = (unsigned short*)WS;
  unsigned short* WSl = WSh + (1 << 20);
  unsigned short* OHh = Qh;                    // OH splits (Q dead after attn)
  unsigned short* OHl = Ql;

  hipMemsetAsync(tC, 0, TTOT_ * sizeof(int), stream);

  // ---- routing features (exact f32 path) ----
  wmean2<<<dim3(256, 2), 256, 0, stream>>>(Wq, Wk, Wqm, Wkm);
  gemm_feats<<<dim3(TTOT_ / 64, 2), 256, 0, stream>>>(q_in, k_in, Wqm, Wkm, FQ, FK);
  l2comb<<<TTOT_ / 4, 256, 0, stream>>>(FQ, FK, FE);
  routing_kernel<<<S_, 1024, 0, stream>>>(FE, seqlens, gidx, cT, cL, tC);

  // ---- Q/K/V projections: split-bf16 MFMA GEMMs with split epilogue ----
  const int n4in = (int)(NELEM_ / 4);
  const int n4w = (1024 * 1024) / 4;
  dim3 gg(TTOT_ / 128, D_ / 128);

  conv_split<<<(n4w + 255) / 256, 256, 0, stream>>>(Wq, WSh, WSl, n4w);
  conv_split<<<(n4in + 255) / 256, 256, 0, stream>>>(q_in, SPh, SPl, n4in);
  gemm_bf16s_sp<<<gg, 256, 0, stream>>>(SPh, SPl, WSh, WSl, Qh, Ql, TTOT_, D_, D_);

  conv_split<<<(n4w + 255) / 256, 256, 0, stream>>>(Wk, WSh, WSl, n4w);
  conv_split<<<(n4in + 255) / 256, 256, 0, stream>>>(k_in, SPh, SPl, n4in);
  gemm_bf16s_sp<<<gg, 256, 0, stream>>>(SPh, SPl, WSh, WSl, Kh, Kl, TTOT_, D_, D_);

  conv_split<<<(n4w + 255) / 256, 256, 0, stream>>>(Wv, WSh, WSl, n4w);
  conv_split<<<(n4in + 255) / 256, 256, 0, stream>>>(v_in, SPh, SPl, n4in);
  gemm_bf16s_sp<<<gg, 256, 0, stream>>>(SPh, SPl, WSh, WSl, Vh, Vl, TTOT_, D_, D_);

  // ---- attention (OH aliases the now-dead input-split slab) ----
  hipMemsetAsync(OH, 0, NELEM_ * sizeof(float), stream);
  attn_kernel<<<7 * H_ * MAXCL_, 256, 0, stream>>>(
      Qh, Ql, Kh, Kl, Vh, Vl, cT, cL, OH);

  // ---- normalize + split (into dead Q slab), output GEMM ----
  norm_split<<<(unsigned)((NELEM_ / 4 + 255) / 256), 256, 0, stream>>>(OH, tC, OHh, OHl);
  conv_split<<<(n4w + 255) / 256, 256, 0, stream>>>(Wo, WSh, WSl, n4w);
  gemm_bf16s<<<gg, 256, 0, stream>>>(OHh, OHl, WSh, WSl, out, TTOT_, D_, D_);
}